// Round 8
// baseline (8127.430 us; speedup 1.0000x reference)
//
#include <hip/hip_runtime.h>
#include <hip/hip_bf16.h>

typedef __hip_bfloat16 bf16;
typedef __attribute__((ext_vector_type(8))) short short8;
typedef __attribute__((ext_vector_type(4))) float floatx4;
typedef unsigned short ush;

#define HH 128
#define WW 128
#define HW 16384

__device__ __forceinline__ float b2f(bf16 v){ return __bfloat162float(v); }
__device__ __forceinline__ float bfu2f(ush u){
  union{unsigned int i; float f;} c; c.i = ((unsigned int)u)<<16; return c.f;
}
__device__ __forceinline__ ush f2bfu(float f){
  bf16 h = __float2bfloat16(f);
  return *(ush*)&h;
}

// ---------- dtype detector: flag=1.0 if x is bf16, 0.0 if f32
__global__ void detect_dtype(const ush* __restrict__ x, float* __restrict__ flag){
  __shared__ int bad;
  if (threadIdx.x==0) bad = 0;
  __syncthreads();
  for (int j=threadIdx.x; j<4096; j+=256){
    float f = bfu2f(x[j]);
    if (!(fabsf(f) < 1e4f)) atomicOr(&bad, 1);
  }
  __syncthreads();
  if (threadIdx.x==0) flag[0] = bad ? 0.f : 1.f;
}

// ---------- input convert: src (bf16 or f32 per flag) -> f32
__global__ void convert_in(const void* __restrict__ src, float* __restrict__ dst, int n,
                           const float* __restrict__ flag){
  int i = blockIdx.x*256 + threadIdx.x;
  if (i >= n) return;
  float v = (flag[0] > 0.5f) ? b2f(((const bf16*)src)[i]) : ((const float*)src)[i];
  dst[i] = v;
}

// ---------- weight transpose: src f32 [Co][CiK] -> dst f32 [CiK][Co]
__global__ void transpose_w(const float* __restrict__ src, float* __restrict__ dst, int Co, int CiK){
  int tid = blockIdx.x*256 + threadIdx.x;
  if (tid >= Co*CiK) return;
  int co = tid / CiK, r = tid - co*CiK;
  dst[(long)r*Co + co] = src[tid];
}

// ---------- weight pack v2: f32 [Cout][Cin][3][3] -> bf16 fragment-order
// per ocb: [j=t*2+ch (18)][lk (4)][n (4)][lx (16)][c (8)]
__global__ void pack_w2(const float* __restrict__ src, ush* __restrict__ dst,
                        int Cout, int Cin, int kh, int nOcB){
  int idx = blockIdx.x*256 + threadIdx.x;
  int total = nOcB*36864;
  if (idx >= total) return;
  int ocb = idx / 36864; int r = idx - ocb*36864;
  int c  = r & 7;
  int lx = (r>>3) & 15;
  int n  = (r>>7) & 3;
  int lk = (r>>9) & 3;
  int j  = r>>11;            // 0..17
  int t = j>>1, ch = j&1;
  int oc = n*16+lx;
  int k = ch*32 + lk*8 + c;
  int ocg = ocb*64 + oc, icg = kh*64 + k;
  float v = (ocg < Cout && icg < Cin) ? src[((long)ocg*Cin + icg)*9 + t] : 0.f;
  dst[idx] = f2bfu(v);
}

// ---------- DCN weight pack: f32 [64 oc][64 ic][9] -> bf16 [8 g][64 oc][96]
__global__ void pack_dcn_w(const float* __restrict__ src, ush* __restrict__ dst){
  int idx = blockIdx.x*256 + threadIdx.x;
  if (idx >= 49152) return;
  int g = idx / 6144; int r = idx - g*6144;
  int oc = r / 96; int k = r - oc*96;
  float v = 0.f;
  if (k < 72){
    int tap = k >> 3, c = k & 7;
    v = src[((long)oc*64 + g*8 + c)*9 + tap];
  }
  dst[idx] = f2bfu(v);
}

// ---------- conv_init: x f32 [20][HW] -> feat NHWC hi/lo bf16 [20][HW][64], relu
// LDS-staged coalesced writes (pitch 66 ush to avoid bank conflicts)
__global__ __launch_bounds__(256) void conv_init_kernel(const float* __restrict__ x,
    const float* __restrict__ wT, const float* __restrict__ bias,
    ush* __restrict__ fh, ush* __restrict__ fl){
  __shared__ ush L[256*66];
  int tid = threadIdx.x;
  int tx = tid & 15, ty = tid >> 4;
  int gx = blockIdx.x*16+tx, gy = blockIdx.y*16+ty;
  int n = blockIdx.z;
  const float* xp = x + (long)n*HW;
  float v[9];
  #pragma unroll
  for (int dy=0;dy<3;dy++)
    #pragma unroll
    for (int dx=0;dx<3;dx++){
      int yy = gy+dy-1, xx = gx+dx-1;
      bool ok = (yy>=0)&&(yy<HH)&&(xx>=0)&&(xx<WW);
      v[dy*3+dx] = ok ? xp[yy*WW+xx] : 0.f;
    }
  float acc[64];
  #pragma unroll 1
  for (int oc=0; oc<64; oc++){
    float a = bias[oc];
    #pragma unroll
    for (int k=0;k<9;k++) a = fmaf(v[k], wT[k*64+oc], a);
    acc[oc] = fmaxf(a, 0.f);
  }
  #pragma unroll 1
  for (int pass=0; pass<2; pass++){
    #pragma unroll 1
    for (int oc=0; oc<64; oc++){
      float a = acc[oc];
      ush h = f2bfu(a);
      L[tid*66+oc] = pass ? f2bfu(a - bfu2f(h)) : h;
    }
    __syncthreads();
    ush* dst = pass ? fl : fh;
    for (int j=tid; j<2048; j+=256){
      int c8 = j&7, pidx = j>>3;
      int row = pidx>>4, col = pidx&15;
      long addr = ((long)n*HW + (blockIdx.y*16+row)*WW + blockIdx.x*16+col)*64 + c8*8;
      *(short8*)(dst+addr) = *(const short8*)(L + pidx*66 + c8*8);
    }
    __syncthreads();
  }
}

// ---------- MFMA implicit-GEMM 3x3 SAME conv (NPL planes). B direct from global.
template<int NPL, int MINW>
__global__ __launch_bounds__(256, MINW) void conv_mfma(
    const ush* __restrict__ in_hi, const ush* __restrict__ in_lo, long in_ps,
    const ush* __restrict__ wpack,
    const float* __restrict__ bias, int has_bias,
    const ush* __restrict__ add_hi, const ush* __restrict__ add_lo,
    long add_ps, int add_cs,
    ush* __restrict__ out_hi, ush* __restrict__ out_lo,
    long out_ps, int out_cs,
    float* __restrict__ out_pf, int pf_C,
    int Cout, int nOcB, int relu)
{
  __shared__ ush A[NPL*11520];
  int tid = threadIdx.x;
  int z = blockIdx.z; int img = z / nOcB; int ocb = z - img*nOcB;
  int x0 = blockIdx.x*16 - 1, y0 = blockIdx.y*8 - 1;
  int w = tid>>6, l = tid&63, lx = l&15, lk = l>>4;
  const ush* wfrag = wpack + (long)ocb*36864 + lk*4*128 + lx*8;
  const ush* ih = in_hi + (long)img*in_ps*64;
  const ush* il = in_lo + (long)img*in_ps*64;
  #pragma unroll
  for (int p=0;p<NPL;p++){
    const ush* src = p ? il : ih;
    ush* dstp = A + p*11520;
    for (int j=tid; j<1440; j+=256){
      int pidx = j>>3, c8 = j&7;
      int row = pidx/18, col = pidx - row*18;
      int yy = y0+row, xx = x0+col;
      uint4 v = make_uint4(0u,0u,0u,0u);
      if ((unsigned)yy < 128u && (unsigned)xx < 128u)
        v = *(const uint4*)(src + ((long)(yy*WW+xx))*64 + c8*8);
      *(uint4*)(dstp + pidx*64 + ((c8 ^ (pidx&7))<<3)) = v;
    }
  }
  floatx4 acc[2][4];
  #pragma unroll
  for (int mt=0;mt<2;mt++)
    #pragma unroll
    for (int n=0;n<4;n++) acc[mt][n] = (floatx4){0.f,0.f,0.f,0.f};
  short8 bf[2][4];
  #pragma unroll
  for (int n=0;n<4;n++)
    bf[0][n] = *(const short8*)(wfrag + (0*16 + n)*128);
  __syncthreads();
  #pragma unroll
  for (int j=0;j<18;j++){
    int t = j>>1, ch = j&1;
    if (j<17){
      #pragma unroll
      for (int n=0;n<4;n++)
        bf[(j+1)&1][n] = *(const short8*)(wfrag + ((j+1)*16 + n)*128);
    }
    int ky = t/3, kx = t - ky*3;
    int jc = ch*4 + lk;
    #pragma unroll
    for (int mt=0; mt<2; mt++){
      int pidx = (w*2+mt+ky)*18 + lx + kx;
      #pragma unroll
      for (int p=0;p<NPL;p++){
        short8 af = *(const short8*)(A + p*11520 + pidx*64 + ((jc ^ (pidx&7))<<3));
        #pragma unroll
        for (int n=0;n<4;n++)
          acc[mt][n] = __builtin_amdgcn_mfma_f32_16x16x32_bf16(af, bf[j&1][n], acc[mt][n], 0,0,0);
      }
    }
  }
  int ybase = blockIdx.y*8 + w*2;
  int xbase = blockIdx.x*16 + lk*4;
  #pragma unroll
  for (int mt=0;mt<2;mt++){
    int y = ybase + mt;
    #pragma unroll
    for (int n=0;n<4;n++){
      int ocg = ocb*64 + n*16 + lx;
      if (ocg < Cout){
        float bv = has_bias ? bias[ocg] : 0.f;
        #pragma unroll
        for (int r=0;r<4;r++){
          int xg = xbase + r;
          float v = acc[mt][n][r] + bv;
          if (add_hi){
            long ap = ((long)img*add_ps + y*WW + xg)*add_cs + ocg;
            v += bfu2f(add_hi[ap]) + bfu2f(add_lo[ap]);
          }
          if (relu) v = fmaxf(v, 0.f);
          if (out_pf){
            out_pf[((long)img*pf_C + ocg)*HW + y*WW + xg] = v;
          } else {
            long pp = (long)img*out_ps + y*WW + xg;
            ush h = f2bfu(v);
            out_hi[pp*out_cs + ocg] = h;
            if (out_lo) out_lo[pp*out_cs + ocg] = f2bfu(v - bfu2f(h));
          }
        }
      }
    }
  }
}

// ---------- MFMA modulated deformable conv; samples NHWC hi/lo directly
__global__ __launch_bounds__(256) void dcn_mfma(
    const ush* __restrict__ xh, const ush* __restrict__ xl, long x_ps,
    const float* __restrict__ om,
    const ush* __restrict__ wpk,
    const float* __restrict__ bias,
    ush* __restrict__ out_hi, ush* __restrict__ out_lo)
{
  __shared__ ush Ah[128*104];
  __shared__ ush Al[128*104];
  __shared__ ush Bt[64*104];
  int tid = threadIdx.x;
  int gy = blockIdx.x, img = blockIdx.y;
  {
    short8 z = {0,0,0,0,0,0,0,0};
    for (int j=tid; j<384; j+=256){
      int px = j/3, c = j - px*3;
      *(short8*)(Ah + px*104 + 72 + c*8) = z;
      *(short8*)(Al + px*104 + 72 + c*8) = z;
    }
  }
  int w = tid>>6, l = tid&63, lx = l&15, lk = l>>4;
  int px_s = tid & 127, hf = tid >> 7;
  const float* omb = om + (long)img*216*HW + gy*WW + px_s;
  const ush* xhb = xh + (long)img*x_ps*64;
  const ush* xlb = xl + (long)img*x_ps*64;
  floatx4 acc[2][4];
  #pragma unroll
  for (int mt=0;mt<2;mt++)
    #pragma unroll
    for (int n=0;n<4;n++) acc[mt][n] = (floatx4){0.f,0.f,0.f,0.f};

  #pragma unroll 1
  for (int g=0; g<8; g++){
    __syncthreads();
    const ush* wsrc = wpk + g*6144;
    for (int j=tid; j<768; j+=256){
      int oc = j/12, kc = j - oc*12;
      *(short8*)(Bt + oc*104 + kc*8) = *(const short8*)(wsrc + oc*96 + kc*8);
    }
    int t0 = hf ? 5 : 0, t1 = hf ? 9 : 5;
    #pragma unroll 1
    for (int t=t0; t<t1; t++){
      int ch = g*9+t;
      float dy = omb[(long)ch*HW];
      float dx = omb[(long)(72+ch)*HW];
      float mv = omb[(long)(144+ch)*HW];
      float m = 1.f/(1.f+__expf(-mv));
      float py = (float)gy + (float)(t/3 - 1) + dy;
      float pxf = (float)px_s + (float)(t%3 - 1) + dx;
      float fy = floorf(py), fx = floorf(pxf);
      int y0 = (int)fy, x0 = (int)fx;
      float wy = py - fy, wx = pxf - fx;
      bool y0v = (y0>=0 && y0<HH), y1v = (y0+1>=0 && y0+1<HH);
      bool x0v = (x0>=0 && x0<WW), x1v = (x0+1>=0 && x0+1<WW);
      float w00 = (1.f-wy)*(1.f-wx)*m * ((y0v&&x0v)?1.f:0.f);
      float w01 = (1.f-wy)*wx*m      * ((y0v&&x1v)?1.f:0.f);
      float w10 = wy*(1.f-wx)*m      * ((y1v&&x0v)?1.f:0.f);
      float w11 = wy*wx*m            * ((y1v&&x1v)?1.f:0.f);
      int y0c = min(max(y0,0),HH-1), y1c = min(max(y0+1,0),HH-1);
      int x0c = min(max(x0,0),WW-1), x1c = min(max(x0+1,0),WW-1);
      long a00 = ((long)(y0c*WW+x0c))*64 + g*8, a01 = ((long)(y0c*WW+x1c))*64 + g*8;
      long a10 = ((long)(y1c*WW+x0c))*64 + g*8, a11 = ((long)(y1c*WW+x1c))*64 + g*8;
      short8 h00 = *(const short8*)(xhb+a00), l00 = *(const short8*)(xlb+a00);
      short8 h01 = *(const short8*)(xhb+a01), l01 = *(const short8*)(xlb+a01);
      short8 h10 = *(const short8*)(xhb+a10), l10 = *(const short8*)(xlb+a10);
      short8 h11 = *(const short8*)(xhb+a11), l11 = *(const short8*)(xlb+a11);
      short8 vh, vl;
      #pragma unroll
      for (int c=0;c<8;c++){
        float s00 = bfu2f((ush)h00[c]) + bfu2f((ush)l00[c]);
        float s01 = bfu2f((ush)h01[c]) + bfu2f((ush)l01[c]);
        float s10 = bfu2f((ush)h10[c]) + bfu2f((ush)l10[c]);
        float s11 = bfu2f((ush)h11[c]) + bfu2f((ush)l11[c]);
        float val = w00*s00 + w01*s01 + w10*s10 + w11*s11;
        ush h = f2bfu(val);
        vh[c] = (short)h;
        vl[c] = (short)f2bfu(val - bfu2f(h));
      }
      *(short8*)(Ah + px_s*104 + t*8) = vh;
      *(short8*)(Al + px_s*104 + t*8) = vl;
    }
    __syncthreads();
    #pragma unroll
    for (int ks=0; ks<3; ks++){
      short8 bfg[4];
      #pragma unroll
      for (int n=0;n<4;n++)
        bfg[n] = *(const short8*)(Bt + (n*16+lx)*104 + ks*32 + lk*8);
      #pragma unroll
      for (int mt=0; mt<2; mt++){
        int px = (w*2+mt)*16 + lx;
        short8 ah = *(const short8*)(Ah + px*104 + ks*32 + lk*8);
        short8 al = *(const short8*)(Al + px*104 + ks*32 + lk*8);
        #pragma unroll
        for (int n=0;n<4;n++){
          acc[mt][n] = __builtin_amdgcn_mfma_f32_16x16x32_bf16(ah, bfg[n], acc[mt][n], 0,0,0);
          acc[mt][n] = __builtin_amdgcn_mfma_f32_16x16x32_bf16(al, bfg[n], acc[mt][n], 0,0,0);
        }
      }
    }
  }
  long base = ((long)img*HW + gy*WW)*64;
  #pragma unroll
  for (int mt=0;mt<2;mt++){
    #pragma unroll
    for (int n=0;n<4;n++){
      int oc = n*16 + lx;
      float bv = bias[oc];
      #pragma unroll
      for (int r=0;r<4;r++){
        int pxl = (w*2+mt)*16 + lk*4 + r;
        float v = acc[mt][n][r] + bv;
        ush h = f2bfu(v);
        out_hi[base + (long)pxl*64 + oc] = h;
        out_lo[base + (long)pxl*64 + oc] = f2bfu(v - bfu2f(h));
      }
    }
  }
}

// ---------- reconstruction conv: channel-split + LDS reduce
// block 256 = 32 px x 8 ch-chunks; grid (4, 128, 4)
__global__ __launch_bounds__(256) void rec_kernel(
    const ush* __restrict__ fh, const ush* __restrict__ fl,
    const float* __restrict__ wT, const float* __restrict__ bias,
    void* __restrict__ out, int ni, const float* __restrict__ flag){
  __shared__ float red[256];
  int tid = threadIdx.x;
  int p = tid & 31, q = tid >> 5;
  int gx = blockIdx.x*32 + p;
  int gy = blockIdx.y;
  int b = blockIdx.z;
  float acc = 0.f;
  #pragma unroll
  for (int t=0;t<9;t++){
    int yy = gy + t/3 - 1, xx = gx + t%3 - 1;
    if (yy<0||yy>=HH||xx<0||xx>=WW) continue;
    long base = ((long)b*HW + yy*WW + xx)*64 + q*8;
    short8 h = *(const short8*)(fh + base);
    short8 lo = *(const short8*)(fl + base);
    #pragma unroll
    for (int cc=0;cc<8;cc++){
      float v = bfu2f((ush)h[cc]) + bfu2f((ush)lo[cc]);
      acc = fmaf(v, wT[(q*8+cc)*9 + t], acc);
    }
  }
  red[q*32+p] = acc;
  __syncthreads();
  if (tid < 32){
    float s = bias[0];
    #pragma unroll
    for (int k=0;k<8;k++) s += red[k*32+tid];
    long idx = ((long)b*5+ni)*HW + gy*WW + blockIdx.x*32 + tid;
    if (flag[0] > 0.5f) ((bf16*)out)[idx] = __float2bfloat16(s);
    else                ((float*)out)[idx] = s;
  }
}

extern "C" void kernel_launch(void* const* d_in, const int* in_sizes, int n_in,
                              void* d_out, int out_size, void* d_ws, size_t ws_size,
                              hipStream_t stream) {
  float* ws = (float*)d_ws;

  size_t off = 16;
  auto alloc = [&](size_t nel){ size_t o = off; off += (nel + 7) & ~(size_t)7; return o; };

  static const int IN_N[17] = {327680, 576, 64, 184320, 320, 184320, 320,
                               73728, 64, 147456, 256, 497664, 864, 147456,
                               256, 576, 1};
  size_t cin[17];
  for (int i=0;i<17;i++) cin[i] = alloc(IN_N[i]);

  size_t wt_init = alloc(640);
  size_t wdcn_pk[4]; for (int s=0;s<4;s++) wdcn_pk[s] = alloc(24576);
  size_t wt_rec = alloc(640);
  size_t pk_res1[5], pk_res2[5];
  for (int i=0;i<5;i++) pk_res1[i] = alloc(18432);
  for (int i=0;i<5;i++) pk_res2[i] = alloc(18432);
  size_t pk_bn[2]; for (int h=0;h<2;h++) pk_bn[h] = alloc(18432);
  size_t pk_off[4]; for (int s=0;s<4;s++) pk_off[s] = alloc(18432);
  size_t pk_com[4]; for (int s=0;s<4;s++) pk_com[s] = alloc(73728);

  size_t feat_h_o = alloc(10485760);
  size_t feat_l_o = alloc(10485760);
  size_t U = alloc(26738688);

  ush* feat_h = (ush*)(ws + feat_h_o);
  ush* feat_l = (ush*)(ws + feat_l_o);
  ush* feaA_h = (ush*)(ws + U);
  ush* feaA_l = (ush*)(ws + U + 2097152);
  ush* feaB_h = (ush*)(ws + U + 4194304);
  ush* feaB_l = (ush*)(ws + U + 6291456);
  ush* obuf_h = (ush*)(ws + U + 8388608);
  ush* obuf_l = (ush*)(ws + U + 10485760);
  float* ombuf = ws + U + 12582912;
  ush* hbuf_h = (ush*)(ws + U);
  ush* hbuf_l = (ush*)(ws + U + 10485760);
  ush* part_h = obuf_h;
  ush* part_l = obuf_l;

  float* flag = ws;

  detect_dtype<<<dim3(1), dim3(256), 0, stream>>>((const ush*)d_in[0], flag);
  for (int i=0;i<17;i++){
    int n = IN_N[i];
    convert_in<<<dim3((n+255)/256), dim3(256), 0, stream>>>(d_in[i], ws+cin[i], n, flag);
  }
  const float* b_init = ws+cin[2];
  const float* res_b1 = ws+cin[4];
  const float* res_b2 = ws+cin[6];
  const float* b_bn   = ws+cin[8];
  const float* off_b  = ws+cin[10];
  const float* com_b  = ws+cin[12];
  const float* dcn_b  = ws+cin[14];
  const float* b_rec  = ws+cin[16];

  auto tr = [&](size_t src_o, size_t dst_o, int Co, int CiK){
    int total = Co*CiK;
    transpose_w<<<dim3((total+255)/256), dim3(256), 0, stream>>>(ws+src_o, ws+dst_o, Co, CiK);
  };
  tr(cin[1], wt_init, 64, 9);
  tr(cin[15], wt_rec, 1, 576);
  for (int s=0;s<4;s++)
    pack_dcn_w<<<dim3(192), dim3(256), 0, stream>>>(ws+cin[13]+(size_t)s*36864,
                                                    (ush*)(ws+wdcn_pk[s]));

  auto pack = [&](size_t src_o, size_t dst_o, int Cout, int Cin, int kh, int nOcB){
    int total = nOcB*36864;
    pack_w2<<<dim3((total+255)/256), dim3(256), 0, stream>>>(
        ws+src_o, (ush*)(ws+dst_o), Cout, Cin, kh, nOcB);
  };
  for (int i=0;i<5;i++) pack(cin[3]+(size_t)i*36864, pk_res1[i], 64, 64, 0, 1);
  for (int i=0;i<5;i++) pack(cin[5]+(size_t)i*36864, pk_res2[i], 64, 64, 0, 1);
  for (int h=0;h<2;h++) pack(cin[7], pk_bn[h], 64, 128, h, 1);
  for (int s=0;s<4;s++) pack(cin[9]+(size_t)s*36864,  pk_off[s], 64, 64, 0, 1);
  for (int s=0;s<4;s++) pack(cin[11]+(size_t)s*124416, pk_com[s], 216, 64, 0, 4);

  dim3 cblk(256);
  auto conv = [&](const ush* in_h, const ush* in_l, long in_ps, size_t pk,
                  const float* bias, int has_bias,
                  const ush* add_h, const ush* add_l, long add_ps, int add_cs,
                  ush* o_h, ush* o_l, long out_ps, int out_cs,
                  float* o_pf, int pf_C,
                  int Cout, int nOcB, int relu, int N, int nPl){
    if (nPl == 2)
      conv_mfma<2,2><<<dim3(8,16,N*nOcB), cblk, 0, stream>>>(
          in_h, in_l, in_ps, (const ush*)(ws+pk), bias, has_bias,
          add_h, add_l, add_ps, add_cs, o_h, o_l, out_ps, out_cs,
          o_pf, pf_C, Cout, nOcB, relu);
    else
      conv_mfma<1,3><<<dim3(8,16,N*nOcB), cblk, 0, stream>>>(
          in_h, in_l, in_ps, (const ush*)(ws+pk), bias, has_bias,
          add_h, add_l, add_ps, add_cs, o_h, o_l, out_ps, out_cs,
          o_pf, pf_C, Cout, nOcB, relu);
  };

  // ---- feature extraction
  conv_init_kernel<<<dim3(8,8,20), cblk, 0, stream>>>(ws+cin[0], ws+wt_init, b_init,
                                                      feat_h, feat_l);
  for (int i=0;i<5;i++){
    conv(feat_h, feat_l, HW, pk_res1[i], res_b1+(size_t)i*64, 1,
         nullptr, nullptr, 0, 0, hbuf_h, hbuf_l, HW, 64, nullptr, 0, 64, 1, 1, 20, 2);
    conv(hbuf_h, hbuf_l, HW, pk_res2[i], res_b2+(size_t)i*64, 1,
         feat_h, feat_l, HW, 64, feat_h, feat_l, HW, 64, nullptr, 0, 64, 1, 0, 20, 2);
  }
  // ---- per-neighbor alignment
  for (int i=0;i<5;i++){
    conv(feat_h + (size_t)2*HW*64, feat_l + (size_t)2*HW*64, 5L*HW, pk_bn[0], b_bn, 1,
         nullptr, nullptr, 0, 0, part_h, part_l, HW, 64, nullptr, 0, 64, 1, 0, 4, 2);
    conv(feat_h + (size_t)i*HW*64, feat_l + (size_t)i*HW*64, 5L*HW, pk_bn[1], b_bn, 0,
         part_h, part_l, HW, 64, feaA_h, feaA_l, HW, 64, nullptr, 0, 64, 1, 0, 4, 2);
    ush *fa_h = feaA_h, *fa_l = feaA_l, *fb_h = feaB_h, *fb_l = feaB_l;
    for (int s=0;s<4;s++){
      conv(fa_h, fa_l, HW, pk_off[s], off_b+(size_t)s*64, 1,
           nullptr, nullptr, 0, 0, obuf_h, nullptr, HW, 64, nullptr, 0, 64, 1, 0, 4, 2);
      conv(obuf_h, obuf_h, HW, pk_com[s], com_b+(size_t)s*216, 1,
           nullptr, nullptr, 0, 0, nullptr, nullptr, 0, 0, ombuf, 216, 216, 4, 0, 4, 1);
      const ush *xs_h, *xs_l; long xps;
      if (s == 2){ xs_h = feat_h + (size_t)i*HW*64; xs_l = feat_l + (size_t)i*HW*64; xps = 5L*HW; }
      else       { xs_h = fa_h;                     xs_l = fa_l;                     xps = HW; }
      dcn_mfma<<<dim3(128,4), cblk, 0, stream>>>(xs_h, xs_l, xps, ombuf,
          (const ush*)(ws+wdcn_pk[s]), dcn_b+(size_t)s*64, fb_h, fb_l);
      ush* t;
      t = fa_h; fa_h = fb_h; fb_h = t;
      t = fa_l; fa_l = fb_l; fb_l = t;
    }
    rec_kernel<<<dim3(4,128,4), cblk, 0, stream>>>(fa_h, fa_l, ws+wt_rec, b_rec, d_out, i, flag);
  }
}

// Round 9
// 4274.664 us; speedup vs baseline: 1.9013x; 1.9013x over previous
//
#include <hip/hip_runtime.h>
#include <hip/hip_bf16.h>

typedef __hip_bfloat16 bf16;
typedef __attribute__((ext_vector_type(8))) short short8;
typedef __attribute__((ext_vector_type(4))) float floatx4;
typedef unsigned short ush;

#define HH 128
#define WW 128
#define HW 16384

__device__ __forceinline__ float b2f(bf16 v){ return __bfloat162float(v); }
__device__ __forceinline__ float bfu2f(ush u){
  union{unsigned int i; float f;} c; c.i = ((unsigned int)u)<<16; return c.f;
}
__device__ __forceinline__ ush f2bfu(float f){
  bf16 h = __float2bfloat16(f);
  return *(ush*)&h;
}

// ---------- dtype detector: flag=1.0 if x is bf16, 0.0 if f32
__global__ void detect_dtype(const ush* __restrict__ x, float* __restrict__ flag){
  __shared__ int bad;
  if (threadIdx.x==0) bad = 0;
  __syncthreads();
  for (int j=threadIdx.x; j<4096; j+=256){
    float f = bfu2f(x[j]);
    if (!(fabsf(f) < 1e4f)) atomicOr(&bad, 1);
  }
  __syncthreads();
  if (threadIdx.x==0) flag[0] = bad ? 0.f : 1.f;
}

// ---------- input convert: src (bf16 or f32 per flag) -> f32
__global__ void convert_in(const void* __restrict__ src, float* __restrict__ dst, int n,
                           const float* __restrict__ flag){
  int i = blockIdx.x*256 + threadIdx.x;
  if (i >= n) return;
  float v = (flag[0] > 0.5f) ? b2f(((const bf16*)src)[i]) : ((const float*)src)[i];
  dst[i] = v;
}

// ---------- weight transpose: src f32 [Co][CiK] -> dst f32 [CiK][Co]
__global__ void transpose_w(const float* __restrict__ src, float* __restrict__ dst, int Co, int CiK){
  int tid = blockIdx.x*256 + threadIdx.x;
  if (tid >= Co*CiK) return;
  int co = tid / CiK, r = tid - co*CiK;
  dst[(long)r*Co + co] = src[tid];
}

// ---------- weight pack v2: f32 [Cout][Cin][3][3] -> bf16 fragment-order
__global__ void pack_w2(const float* __restrict__ src, ush* __restrict__ dst,
                        int Cout, int Cin, int kh, int nOcB){
  int idx = blockIdx.x*256 + threadIdx.x;
  int total = nOcB*36864;
  if (idx >= total) return;
  int ocb = idx / 36864; int r = idx - ocb*36864;
  int c  = r & 7;
  int lx = (r>>3) & 15;
  int n  = (r>>7) & 3;
  int lk = (r>>9) & 3;
  int j  = r>>11;
  int t = j>>1, ch = j&1;
  int oc = n*16+lx;
  int k = ch*32 + lk*8 + c;
  int ocg = ocb*64 + oc, icg = kh*64 + k;
  float v = (ocg < Cout && icg < Cin) ? src[((long)ocg*Cin + icg)*9 + t] : 0.f;
  dst[idx] = f2bfu(v);
}

// ---------- DCN weight pack: f32 [64 oc][64 ic][9] -> bf16 [8 g][64 oc][96]
__global__ void pack_dcn_w(const float* __restrict__ src, ush* __restrict__ dst){
  int idx = blockIdx.x*256 + threadIdx.x;
  if (idx >= 49152) return;
  int g = idx / 6144; int r = idx - g*6144;
  int oc = r / 96; int k = r - oc*96;
  float v = 0.f;
  if (k < 72){
    int tap = k >> 3, c = k & 7;
    v = src[((long)oc*64 + g*8 + c)*9 + tap];
  }
  dst[idx] = f2bfu(v);
}

// ---------- conv_init: x f32 [20][HW] -> feat NHWC hi/lo bf16 [20][HW][64], relu
__global__ __launch_bounds__(256) void conv_init_kernel(const float* __restrict__ x,
    const float* __restrict__ wT, const float* __restrict__ bias,
    ush* __restrict__ fh, ush* __restrict__ fl){
  __shared__ ush L[256*66];
  int tid = threadIdx.x;
  int tx = tid & 15, ty = tid >> 4;
  int gx = blockIdx.x*16+tx, gy = blockIdx.y*16+ty;
  int n = blockIdx.z;
  const float* xp = x + (long)n*HW;
  float v[9];
  #pragma unroll
  for (int dy=0;dy<3;dy++)
    #pragma unroll
    for (int dx=0;dx<3;dx++){
      int yy = gy+dy-1, xx = gx+dx-1;
      bool ok = (yy>=0)&&(yy<HH)&&(xx>=0)&&(xx<WW);
      v[dy*3+dx] = ok ? xp[yy*WW+xx] : 0.f;
    }
  float acc[64];
  #pragma unroll 1
  for (int oc=0; oc<64; oc++){
    float a = bias[oc];
    #pragma unroll
    for (int k=0;k<9;k++) a = fmaf(v[k], wT[k*64+oc], a);
    acc[oc] = fmaxf(a, 0.f);
  }
  #pragma unroll 1
  for (int pass=0; pass<2; pass++){
    #pragma unroll 1
    for (int oc=0; oc<64; oc++){
      float a = acc[oc];
      ush h = f2bfu(a);
      L[tid*66+oc] = pass ? f2bfu(a - bfu2f(h)) : h;
    }
    __syncthreads();
    ush* dst = pass ? fl : fh;
    for (int j=tid; j<2048; j+=256){
      int c8 = j&7, pidx = j>>3;
      int row = pidx>>4, col = pidx&15;
      long addr = ((long)n*HW + (blockIdx.y*16+row)*WW + blockIdx.x*16+col)*64 + c8*8;
      *(short8*)(dst+addr) = *(const short8*)(L + pidx*66 + c8*8);
    }
    __syncthreads();
  }
}

// ---------- MFMA implicit-GEMM 3x3 SAME conv (NPL planes). B direct from global.
template<int NPL, int MINW>
__global__ __launch_bounds__(256, MINW) void conv_mfma(
    const ush* __restrict__ in_hi, const ush* __restrict__ in_lo, long in_ps,
    const ush* __restrict__ wpack,
    const float* __restrict__ bias, int has_bias,
    const ush* __restrict__ add_hi, const ush* __restrict__ add_lo,
    long add_ps, int add_cs,
    ush* __restrict__ out_hi, ush* __restrict__ out_lo,
    long out_ps, int out_cs,
    float* __restrict__ out_pf, int pf_C,
    int Cout, int nOcB, int relu)
{
  __shared__ ush A[NPL*11520];
  int tid = threadIdx.x;
  int z = blockIdx.z; int img = z / nOcB; int ocb = z - img*nOcB;
  int x0 = blockIdx.x*16 - 1, y0 = blockIdx.y*8 - 1;
  int w = tid>>6, l = tid&63, lx = l&15, lk = l>>4;
  const ush* wfrag = wpack + (long)ocb*36864 + lk*4*128 + lx*8;
  const ush* ih = in_hi + (long)img*in_ps*64;
  const ush* il = in_lo + (long)img*in_ps*64;
  #pragma unroll
  for (int p=0;p<NPL;p++){
    const ush* src = p ? il : ih;
    ush* dstp = A + p*11520;
    for (int j=tid; j<1440; j+=256){
      int pidx = j>>3, c8 = j&7;
      int row = pidx/18, col = pidx - row*18;
      int yy = y0+row, xx = x0+col;
      uint4 v = make_uint4(0u,0u,0u,0u);
      if ((unsigned)yy < 128u && (unsigned)xx < 128u)
        v = *(const uint4*)(src + ((long)(yy*WW+xx))*64 + c8*8);
      *(uint4*)(dstp + pidx*64 + ((c8 ^ (pidx&7))<<3)) = v;
    }
  }
  floatx4 acc[2][4];
  #pragma unroll
  for (int mt=0;mt<2;mt++)
    #pragma unroll
    for (int n=0;n<4;n++) acc[mt][n] = (floatx4){0.f,0.f,0.f,0.f};
  short8 bf[2][4];
  #pragma unroll
  for (int n=0;n<4;n++)
    bf[0][n] = *(const short8*)(wfrag + (0*16 + n)*128);
  __syncthreads();
  #pragma unroll
  for (int j=0;j<18;j++){
    int t = j>>1, ch = j&1;
    if (j<17){
      #pragma unroll
      for (int n=0;n<4;n++)
        bf[(j+1)&1][n] = *(const short8*)(wfrag + ((j+1)*16 + n)*128);
    }
    int ky = t/3, kx = t - ky*3;
    int jc = ch*4 + lk;
    #pragma unroll
    for (int mt=0; mt<2; mt++){
      int pidx = (w*2+mt+ky)*18 + lx + kx;
      #pragma unroll
      for (int p=0;p<NPL;p++){
        short8 af = *(const short8*)(A + p*11520 + pidx*64 + ((jc ^ (pidx&7))<<3));
        #pragma unroll
        for (int n=0;n<4;n++)
          acc[mt][n] = __builtin_amdgcn_mfma_f32_16x16x32_bf16(af, bf[j&1][n], acc[mt][n], 0,0,0);
      }
    }
  }
  int ybase = blockIdx.y*8 + w*2;
  int xbase = blockIdx.x*16 + lk*4;
  #pragma unroll
  for (int mt=0;mt<2;mt++){
    int y = ybase + mt;
    #pragma unroll
    for (int n=0;n<4;n++){
      int ocg = ocb*64 + n*16 + lx;
      if (ocg < Cout){
        float bv = has_bias ? bias[ocg] : 0.f;
        #pragma unroll
        for (int r=0;r<4;r++){
          int xg = xbase + r;
          float v = acc[mt][n][r] + bv;
          if (add_hi){
            long ap = ((long)img*add_ps + y*WW + xg)*add_cs + ocg;
            v += bfu2f(add_hi[ap]) + bfu2f(add_lo[ap]);
          }
          if (relu) v = fmaxf(v, 0.f);
          if (out_pf){
            out_pf[((long)img*pf_C + ocg)*HW + y*WW + xg] = v;
          } else {
            long pp = (long)img*out_ps + y*WW + xg;
            ush h = f2bfu(v);
            out_hi[pp*out_cs + ocg] = h;
            if (out_lo) out_lo[pp*out_cs + ocg] = f2bfu(v - bfu2f(h));
          }
        }
      }
    }
  }
}

// ---------- repack NHWC hi/lo -> group-planar bf16 hi/lo [4][8][HW][8]
// tid = pix*8 + c8: reads fully coalesced, writes 8 16B-streams per wave
__global__ __launch_bounds__(256) void repack_gp(const ush* __restrict__ in_h,
    const ush* __restrict__ in_l, long in_ps,
    ush* __restrict__ gph, ush* __restrict__ gpl){
  long idx = (long)blockIdx.x*256 + threadIdx.x;   // over 4*HW*8 = 524288
  int img = (int)(idx >> 17);
  int rem = (int)(idx & 131071);
  int pix = rem >> 3, c8 = rem & 7;
  long src = ((long)img*in_ps + pix)*64 + c8*8;
  long dst = (((long)(img*8+c8))*HW + pix)*8;
  *(short8*)(gph+dst) = *(const short8*)(in_h+src);
  *(short8*)(gpl+dst) = *(const short8*)(in_l+src);
}

// ---------- MFMA modulated deformable conv; gp bf16 hi/lo group-planar in
__global__ __launch_bounds__(256) void dcn_mfma(
    const ush* __restrict__ gph, const ush* __restrict__ gpl,
    const float* __restrict__ om,
    const ush* __restrict__ wpk,
    const float* __restrict__ bias,
    ush* __restrict__ out_hi, ush* __restrict__ out_lo)
{
  __shared__ ush Ah[128*104];
  __shared__ ush Al[128*104];
  __shared__ ush Bt[64*104];
  int tid = threadIdx.x;
  int gy = blockIdx.x, img = blockIdx.y;
  {
    short8 z = {0,0,0,0,0,0,0,0};
    for (int j=tid; j<384; j+=256){
      int px = j/3, c = j - px*3;
      *(short8*)(Ah + px*104 + 72 + c*8) = z;
      *(short8*)(Al + px*104 + 72 + c*8) = z;
    }
  }
  int w = tid>>6, l = tid&63, lx = l&15, lk = l>>4;
  int px_s = tid & 127, hf = tid >> 7;
  const float* omb = om + (long)img*216*HW + gy*WW + px_s;
  floatx4 acc[2][4];
  #pragma unroll
  for (int mt=0;mt<2;mt++)
    #pragma unroll
    for (int n=0;n<4;n++) acc[mt][n] = (floatx4){0.f,0.f,0.f,0.f};

  #pragma unroll 1
  for (int g=0; g<8; g++){
    __syncthreads();
    const ush* wsrc = wpk + g*6144;
    for (int j=tid; j<768; j+=256){
      int oc = j/12, kc = j - oc*12;
      *(short8*)(Bt + oc*104 + kc*8) = *(const short8*)(wsrc + oc*96 + kc*8);
    }
    const ush* gh = gph + ((long)(img*8+g))*HW*8;
    const ush* gl = gpl + ((long)(img*8+g))*HW*8;
    int t0 = hf ? 5 : 0, t1 = hf ? 9 : 5;
    #pragma unroll 1
    for (int t=t0; t<t1; t++){
      int ch = g*9+t;
      float dy = omb[(long)ch*HW];
      float dx = omb[(long)(72+ch)*HW];
      float mv = omb[(long)(144+ch)*HW];
      float m = 1.f/(1.f+__expf(-mv));
      float py = (float)gy + (float)(t/3 - 1) + dy;
      float pxf = (float)px_s + (float)(t%3 - 1) + dx;
      float fy = floorf(py), fx = floorf(pxf);
      int y0 = (int)fy, x0 = (int)fx;
      float wy = py - fy, wx = pxf - fx;
      bool y0v = (y0>=0 && y0<HH), y1v = (y0+1>=0 && y0+1<HH);
      bool x0v = (x0>=0 && x0<WW), x1v = (x0+1>=0 && x0+1<WW);
      float w00 = (1.f-wy)*(1.f-wx)*m * ((y0v&&x0v)?1.f:0.f);
      float w01 = (1.f-wy)*wx*m      * ((y0v&&x1v)?1.f:0.f);
      float w10 = wy*(1.f-wx)*m      * ((y1v&&x0v)?1.f:0.f);
      float w11 = wy*wx*m            * ((y1v&&x1v)?1.f:0.f);
      int y0c = min(max(y0,0),HH-1), y1c = min(max(y0+1,0),HH-1);
      int x0c = min(max(x0,0),WW-1), x1c = min(max(x0+1,0),WW-1);
      long a00 = ((long)(y0c*WW+x0c))<<3, a01 = ((long)(y0c*WW+x1c))<<3;
      long a10 = ((long)(y1c*WW+x0c))<<3, a11 = ((long)(y1c*WW+x1c))<<3;
      short8 h00 = *(const short8*)(gh+a00), l00 = *(const short8*)(gl+a00);
      short8 h01 = *(const short8*)(gh+a01), l01 = *(const short8*)(gl+a01);
      short8 h10 = *(const short8*)(gh+a10), l10 = *(const short8*)(gl+a10);
      short8 h11 = *(const short8*)(gh+a11), l11 = *(const short8*)(gl+a11);
      short8 vh, vl;
      #pragma unroll
      for (int c=0;c<8;c++){
        float s00 = bfu2f((ush)h00[c]) + bfu2f((ush)l00[c]);
        float s01 = bfu2f((ush)h01[c]) + bfu2f((ush)l01[c]);
        float s10 = bfu2f((ush)h10[c]) + bfu2f((ush)l10[c]);
        float s11 = bfu2f((ush)h11[c]) + bfu2f((ush)l11[c]);
        float val = w00*s00 + w01*s01 + w10*s10 + w11*s11;
        ush h = f2bfu(val);
        vh[c] = (short)h;
        vl[c] = (short)f2bfu(val - bfu2f(h));
      }
      *(short8*)(Ah + px_s*104 + t*8) = vh;
      *(short8*)(Al + px_s*104 + t*8) = vl;
    }
    __syncthreads();
    #pragma unroll
    for (int ks=0; ks<3; ks++){
      short8 bfg[4];
      #pragma unroll
      for (int n=0;n<4;n++)
        bfg[n] = *(const short8*)(Bt + (n*16+lx)*104 + ks*32 + lk*8);
      #pragma unroll
      for (int mt=0; mt<2; mt++){
        int px = (w*2+mt)*16 + lx;
        short8 ah = *(const short8*)(Ah + px*104 + ks*32 + lk*8);
        short8 al = *(const short8*)(Al + px*104 + ks*32 + lk*8);
        #pragma unroll
        for (int n=0;n<4;n++){
          acc[mt][n] = __builtin_amdgcn_mfma_f32_16x16x32_bf16(ah, bfg[n], acc[mt][n], 0,0,0);
          acc[mt][n] = __builtin_amdgcn_mfma_f32_16x16x32_bf16(al, bfg[n], acc[mt][n], 0,0,0);
        }
      }
    }
  }
  long base = ((long)img*HW + gy*WW)*64;
  #pragma unroll
  for (int mt=0;mt<2;mt++){
    #pragma unroll
    for (int n=0;n<4;n++){
      int oc = n*16 + lx;
      float bv = bias[oc];
      #pragma unroll
      for (int r=0;r<4;r++){
        int pxl = (w*2+mt)*16 + lk*4 + r;
        float v = acc[mt][n][r] + bv;
        ush h = f2bfu(v);
        out_hi[base + (long)pxl*64 + oc] = h;
        out_lo[base + (long)pxl*64 + oc] = f2bfu(v - bfu2f(h));
      }
    }
  }
}

// ---------- reconstruction conv: channel-split + LDS reduce
__global__ __launch_bounds__(256) void rec_kernel(
    const ush* __restrict__ fh, const ush* __restrict__ fl,
    const float* __restrict__ wT, const float* __restrict__ bias,
    void* __restrict__ out, int ni, const float* __restrict__ flag){
  __shared__ float red[256];
  int tid = threadIdx.x;
  int p = tid & 31, q = tid >> 5;
  int gx = blockIdx.x*32 + p;
  int gy = blockIdx.y;
  int b = blockIdx.z;
  float acc = 0.f;
  #pragma unroll
  for (int t=0;t<9;t++){
    int yy = gy + t/3 - 1, xx = gx + t%3 - 1;
    if (yy<0||yy>=HH||xx<0||xx>=WW) continue;
    long base = ((long)b*HW + yy*WW + xx)*64 + q*8;
    short8 h = *(const short8*)(fh + base);
    short8 lo = *(const short8*)(fl + base);
    #pragma unroll
    for (int cc=0;cc<8;cc++){
      float v = bfu2f((ush)h[cc]) + bfu2f((ush)lo[cc]);
      acc = fmaf(v, wT[(q*8+cc)*9 + t], acc);
    }
  }
  red[q*32+p] = acc;
  __syncthreads();
  if (tid < 32){
    float s = bias[0];
    #pragma unroll
    for (int k=0;k<8;k++) s += red[k*32+tid];
    long idx = ((long)b*5+ni)*HW + gy*WW + blockIdx.x*32 + tid;
    if (flag[0] > 0.5f) ((bf16*)out)[idx] = __float2bfloat16(s);
    else                ((float*)out)[idx] = s;
  }
}

extern "C" void kernel_launch(void* const* d_in, const int* in_sizes, int n_in,
                              void* d_out, int out_size, void* d_ws, size_t ws_size,
                              hipStream_t stream) {
  float* ws = (float*)d_ws;

  size_t off = 16;
  auto alloc = [&](size_t nel){ size_t o = off; off += (nel + 7) & ~(size_t)7; return o; };

  static const int IN_N[17] = {327680, 576, 64, 184320, 320, 184320, 320,
                               73728, 64, 147456, 256, 497664, 864, 147456,
                               256, 576, 1};
  size_t cin[17];
  for (int i=0;i<17;i++) cin[i] = alloc(IN_N[i]);

  size_t wt_init = alloc(640);
  size_t wdcn_pk[4]; for (int s=0;s<4;s++) wdcn_pk[s] = alloc(24576);
  size_t wt_rec = alloc(640);
  size_t pk_res1[5], pk_res2[5];
  for (int i=0;i<5;i++) pk_res1[i] = alloc(18432);
  for (int i=0;i<5;i++) pk_res2[i] = alloc(18432);
  size_t pk_bn[2]; for (int h=0;h<2;h++) pk_bn[h] = alloc(18432);
  size_t pk_off[4]; for (int s=0;s<4;s++) pk_off[s] = alloc(18432);
  size_t pk_com[4]; for (int s=0;s<4;s++) pk_com[s] = alloc(73728);

  size_t feat_h_o = alloc(10485760);
  size_t feat_l_o = alloc(10485760);
  size_t U = alloc(26738688);

  ush* feat_h = (ush*)(ws + feat_h_o);
  ush* feat_l = (ush*)(ws + feat_l_o);
  ush* feaA_h = (ush*)(ws + U);
  ush* feaA_l = (ush*)(ws + U + 2097152);
  ush* feaB_h = (ush*)(ws + U + 4194304);
  ush* feaB_l = (ush*)(ws + U + 6291456);
  ush* obuf_h = (ush*)(ws + U + 8388608);
  ush* obuf_l = (ush*)(ws + U + 10485760);
  ush* gph    = (ush*)(ws + U + 8388608);    // aliases obuf (dead when gp live)
  ush* gpl    = (ush*)(ws + U + 10485760);
  float* ombuf = ws + U + 12582912;
  ush* hbuf_h = (ush*)(ws + U);
  ush* hbuf_l = (ush*)(ws + U + 10485760);
  ush* part_h = obuf_h;
  ush* part_l = obuf_l;

  float* flag = ws;

  detect_dtype<<<dim3(1), dim3(256), 0, stream>>>((const ush*)d_in[0], flag);
  for (int i=0;i<17;i++){
    int n = IN_N[i];
    convert_in<<<dim3((n+255)/256), dim3(256), 0, stream>>>(d_in[i], ws+cin[i], n, flag);
  }
  const float* b_init = ws+cin[2];
  const float* res_b1 = ws+cin[4];
  const float* res_b2 = ws+cin[6];
  const float* b_bn   = ws+cin[8];
  const float* off_b  = ws+cin[10];
  const float* com_b  = ws+cin[12];
  const float* dcn_b  = ws+cin[14];
  const float* b_rec  = ws+cin[16];

  auto tr = [&](size_t src_o, size_t dst_o, int Co, int CiK){
    int total = Co*CiK;
    transpose_w<<<dim3((total+255)/256), dim3(256), 0, stream>>>(ws+src_o, ws+dst_o, Co, CiK);
  };
  tr(cin[1], wt_init, 64, 9);
  tr(cin[15], wt_rec, 1, 576);
  for (int s=0;s<4;s++)
    pack_dcn_w<<<dim3(192), dim3(256), 0, stream>>>(ws+cin[13]+(size_t)s*36864,
                                                    (ush*)(ws+wdcn_pk[s]));

  auto pack = [&](size_t src_o, size_t dst_o, int Cout, int Cin, int kh, int nOcB){
    int total = nOcB*36864;
    pack_w2<<<dim3((total+255)/256), dim3(256), 0, stream>>>(
        ws+src_o, (ush*)(ws+dst_o), Cout, Cin, kh, nOcB);
  };
  for (int i=0;i<5;i++) pack(cin[3]+(size_t)i*36864, pk_res1[i], 64, 64, 0, 1);
  for (int i=0;i<5;i++) pack(cin[5]+(size_t)i*36864, pk_res2[i], 64, 64, 0, 1);
  for (int h=0;h<2;h++) pack(cin[7], pk_bn[h], 64, 128, h, 1);
  for (int s=0;s<4;s++) pack(cin[9]+(size_t)s*36864,  pk_off[s], 64, 64, 0, 1);
  for (int s=0;s<4;s++) pack(cin[11]+(size_t)s*124416, pk_com[s], 216, 64, 0, 4);

  dim3 cblk(256);
  auto conv = [&](const ush* in_h, const ush* in_l, long in_ps, size_t pk,
                  const float* bias, int has_bias,
                  const ush* add_h, const ush* add_l, long add_ps, int add_cs,
                  ush* o_h, ush* o_l, long out_ps, int out_cs,
                  float* o_pf, int pf_C,
                  int Cout, int nOcB, int relu, int N, int nPl){
    if (nPl == 2)
      conv_mfma<2,2><<<dim3(8,16,N*nOcB), cblk, 0, stream>>>(
          in_h, in_l, in_ps, (const ush*)(ws+pk), bias, has_bias,
          add_h, add_l, add_ps, add_cs, o_h, o_l, out_ps, out_cs,
          o_pf, pf_C, Cout, nOcB, relu);
    else
      conv_mfma<1,3><<<dim3(8,16,N*nOcB), cblk, 0, stream>>>(
          in_h, in_l, in_ps, (const ush*)(ws+pk), bias, has_bias,
          add_h, add_l, add_ps, add_cs, o_h, o_l, out_ps, out_cs,
          o_pf, pf_C, Cout, nOcB, relu);
  };

  // ---- feature extraction
  conv_init_kernel<<<dim3(8,8,20), cblk, 0, stream>>>(ws+cin[0], ws+wt_init, b_init,
                                                      feat_h, feat_l);
  for (int i=0;i<5;i++){
    conv(feat_h, feat_l, HW, pk_res1[i], res_b1+(size_t)i*64, 1,
         nullptr, nullptr, 0, 0, hbuf_h, hbuf_l, HW, 64, nullptr, 0, 64, 1, 1, 20, 2);
    conv(hbuf_h, hbuf_l, HW, pk_res2[i], res_b2+(size_t)i*64, 1,
         feat_h, feat_l, HW, 64, feat_h, feat_l, HW, 64, nullptr, 0, 64, 1, 0, 20, 2);
  }
  // ---- per-neighbor alignment
  for (int i=0;i<5;i++){
    conv(feat_h + (size_t)2*HW*64, feat_l + (size_t)2*HW*64, 5L*HW, pk_bn[0], b_bn, 1,
         nullptr, nullptr, 0, 0, part_h, part_l, HW, 64, nullptr, 0, 64, 1, 0, 4, 2);
    conv(feat_h + (size_t)i*HW*64, feat_l + (size_t)i*HW*64, 5L*HW, pk_bn[1], b_bn, 0,
         part_h, part_l, HW, 64, feaA_h, feaA_l, HW, 64, nullptr, 0, 64, 1, 0, 4, 2);
    ush *fa_h = feaA_h, *fa_l = feaA_l, *fb_h = feaB_h, *fb_l = feaB_l;
    for (int s=0;s<4;s++){
      conv(fa_h, fa_l, HW, pk_off[s], off_b+(size_t)s*64, 1,
           nullptr, nullptr, 0, 0, obuf_h, nullptr, HW, 64, nullptr, 0, 64, 1, 0, 4, 2);
      conv(obuf_h, obuf_h, HW, pk_com[s], com_b+(size_t)s*216, 1,
           nullptr, nullptr, 0, 0, nullptr, nullptr, 0, 0, ombuf, 216, 216, 4, 0, 4, 1);
      const ush *xs_h, *xs_l; long xps;
      if (s == 2){ xs_h = feat_h + (size_t)i*HW*64; xs_l = feat_l + (size_t)i*HW*64; xps = 5L*HW; }
      else       { xs_h = fa_h;                     xs_l = fa_l;                     xps = HW; }
      repack_gp<<<dim3(2048), cblk, 0, stream>>>(xs_h, xs_l, xps, gph, gpl);
      dcn_mfma<<<dim3(128,4), cblk, 0, stream>>>(gph, gpl, ombuf,
          (const ush*)(ws+wdcn_pk[s]), dcn_b+(size_t)s*64, fb_h, fb_l);
      ush* t;
      t = fa_h; fa_h = fb_h; fb_h = t;
      t = fa_l; fa_l = fb_l; fb_l = t;
    }
    rec_kernel<<<dim3(4,128,4), cblk, 0, stream>>>(fa_h, fa_l, ws+wt_rec, b_rec, d_out, i, flag);
  }
}

// Round 10
// 4104.737 us; speedup vs baseline: 1.9800x; 1.0414x over previous
//
#include <hip/hip_runtime.h>
#include <hip/hip_bf16.h>

typedef __hip_bfloat16 bf16;
typedef __attribute__((ext_vector_type(8))) short short8;
typedef __attribute__((ext_vector_type(4))) float floatx4;
typedef unsigned short ush;

#define HH 128
#define WW 128
#define HW 16384

__device__ __forceinline__ float b2f(bf16 v){ return __bfloat162float(v); }
__device__ __forceinline__ float bfu2f(ush u){
  union{unsigned int i; float f;} c; c.i = ((unsigned int)u)<<16; return c.f;
}
__device__ __forceinline__ ush f2bfu(float f){
  bf16 h = __float2bfloat16(f);
  return *(ush*)&h;
}

// ---------- dtype detector: flag=1.0 if x is bf16, 0.0 if f32
__global__ void detect_dtype(const ush* __restrict__ x, float* __restrict__ flag){
  __shared__ int bad;
  if (threadIdx.x==0) bad = 0;
  __syncthreads();
  for (int j=threadIdx.x; j<4096; j+=256){
    float f = bfu2f(x[j]);
    if (!(fabsf(f) < 1e4f)) atomicOr(&bad, 1);
  }
  __syncthreads();
  if (threadIdx.x==0) flag[0] = bad ? 0.f : 1.f;
}

// ---------- input convert: src (bf16 or f32 per flag) -> f32
__global__ void convert_in(const void* __restrict__ src, float* __restrict__ dst, int n,
                           const float* __restrict__ flag){
  int i = blockIdx.x*256 + threadIdx.x;
  if (i >= n) return;
  float v = (flag[0] > 0.5f) ? b2f(((const bf16*)src)[i]) : ((const float*)src)[i];
  dst[i] = v;
}

// ---------- weight transpose: src f32 [Co][CiK] -> dst f32 [CiK][Co]
__global__ void transpose_w(const float* __restrict__ src, float* __restrict__ dst, int Co, int CiK){
  int tid = blockIdx.x*256 + threadIdx.x;
  if (tid >= Co*CiK) return;
  int co = tid / CiK, r = tid - co*CiK;
  dst[(long)r*Co + co] = src[tid];
}

// ---------- weight pack v2: f32 [Cout][Cin][3][3] -> bf16 fragment-order
__global__ void pack_w2(const float* __restrict__ src, ush* __restrict__ dst,
                        int Cout, int Cin, int kh, int nOcB){
  int idx = blockIdx.x*256 + threadIdx.x;
  int total = nOcB*36864;
  if (idx >= total) return;
  int ocb = idx / 36864; int r = idx - ocb*36864;
  int c  = r & 7;
  int lx = (r>>3) & 15;
  int n  = (r>>7) & 3;
  int lk = (r>>9) & 3;
  int j  = r>>11;
  int t = j>>1, ch = j&1;
  int oc = n*16+lx;
  int k = ch*32 + lk*8 + c;
  int ocg = ocb*64 + oc, icg = kh*64 + k;
  float v = (ocg < Cout && icg < Cin) ? src[((long)ocg*Cin + icg)*9 + t] : 0.f;
  dst[idx] = f2bfu(v);
}

// ---------- DCN weight pack: f32 [64 oc][64 ic][9] -> bf16 [8 g][64 oc][96]
__global__ void pack_dcn_w(const float* __restrict__ src, ush* __restrict__ dst){
  int idx = blockIdx.x*256 + threadIdx.x;
  if (idx >= 49152) return;
  int g = idx / 6144; int r = idx - g*6144;
  int oc = r / 96; int k = r - oc*96;
  float v = 0.f;
  if (k < 72){
    int tap = k >> 3, c = k & 7;
    v = src[((long)oc*64 + g*8 + c)*9 + tap];
  }
  dst[idx] = f2bfu(v);
}

// ---------- conv_init: x f32 [20][HW] -> feat NHWC hi/lo bf16 [20][HW][64], relu
__global__ __launch_bounds__(256) void conv_init_kernel(const float* __restrict__ x,
    const float* __restrict__ wT, const float* __restrict__ bias,
    ush* __restrict__ fh, ush* __restrict__ fl){
  __shared__ ush L[256*66];
  int tid = threadIdx.x;
  int tx = tid & 15, ty = tid >> 4;
  int gx = blockIdx.x*16+tx, gy = blockIdx.y*16+ty;
  int n = blockIdx.z;
  const float* xp = x + (long)n*HW;
  float v[9];
  #pragma unroll
  for (int dy=0;dy<3;dy++)
    #pragma unroll
    for (int dx=0;dx<3;dx++){
      int yy = gy+dy-1, xx = gx+dx-1;
      bool ok = (yy>=0)&&(yy<HH)&&(xx>=0)&&(xx<WW);
      v[dy*3+dx] = ok ? xp[yy*WW+xx] : 0.f;
    }
  float acc[64];
  #pragma unroll 1
  for (int oc=0; oc<64; oc++){
    float a = bias[oc];
    #pragma unroll
    for (int k=0;k<9;k++) a = fmaf(v[k], wT[k*64+oc], a);
    acc[oc] = fmaxf(a, 0.f);
  }
  #pragma unroll 1
  for (int pass=0; pass<2; pass++){
    #pragma unroll 1
    for (int oc=0; oc<64; oc++){
      float a = acc[oc];
      ush h = f2bfu(a);
      L[tid*66+oc] = pass ? f2bfu(a - bfu2f(h)) : h;
    }
    __syncthreads();
    ush* dst = pass ? fl : fh;
    for (int j=tid; j<2048; j+=256){
      int c8 = j&7, pidx = j>>3;
      int row = pidx>>4, col = pidx&15;
      long addr = ((long)n*HW + (blockIdx.y*16+row)*WW + blockIdx.x*16+col)*64 + c8*8;
      *(short8*)(dst+addr) = *(const short8*)(L + pidx*66 + c8*8);
    }
    __syncthreads();
  }
}

// ---------- MFMA implicit-GEMM 3x3 SAME conv (NPL planes). B direct from global,
// fragment-packed, 4-deep register ring (all indices static under full unroll).
template<int NPL, int MINW>
__global__ __launch_bounds__(256, MINW) void conv_mfma(
    const ush* __restrict__ in_hi, const ush* __restrict__ in_lo, long in_ps,
    const ush* __restrict__ wpack,
    const float* __restrict__ bias, int has_bias,
    const ush* __restrict__ add_hi, const ush* __restrict__ add_lo,
    long add_ps, int add_cs,
    ush* __restrict__ out_hi, ush* __restrict__ out_lo,
    long out_ps, int out_cs,
    float* __restrict__ out_pf, int pf_C,
    int Cout, int nOcB, int relu)
{
  __shared__ ush A[NPL*11520];
  int tid = threadIdx.x;
  int z = blockIdx.z; int img = z / nOcB; int ocb = z - img*nOcB;
  int x0 = blockIdx.x*16 - 1, y0 = blockIdx.y*8 - 1;
  int w = tid>>6, l = tid&63, lx = l&15, lk = l>>4;
  const ush* wfrag = wpack + (long)ocb*36864 + lk*4*128 + lx*8;
  const ush* ih = in_hi + (long)img*in_ps*64;
  const ush* il = in_lo + (long)img*in_ps*64;
  #pragma unroll
  for (int p=0;p<NPL;p++){
    const ush* src = p ? il : ih;
    ush* dstp = A + p*11520;
    for (int j=tid; j<1440; j+=256){
      int pidx = j>>3, c8 = j&7;
      int row = pidx/18, col = pidx - row*18;
      int yy = y0+row, xx = x0+col;
      uint4 v = make_uint4(0u,0u,0u,0u);
      if ((unsigned)yy < 128u && (unsigned)xx < 128u)
        v = *(const uint4*)(src + ((long)(yy*WW+xx))*64 + c8*8);
      *(uint4*)(dstp + pidx*64 + ((c8 ^ (pidx&7))<<3)) = v;
    }
  }
  floatx4 acc[2][4];
  #pragma unroll
  for (int mt=0;mt<2;mt++)
    #pragma unroll
    for (int n=0;n<4;n++) acc[mt][n] = (floatx4){0.f,0.f,0.f,0.f};
  short8 bf[4][4];
  #pragma unroll
  for (int s=0;s<3;s++)
    #pragma unroll
    for (int n=0;n<4;n++)
      bf[s][n] = *(const short8*)(wfrag + (s*16 + n)*128);
  __syncthreads();
  #pragma unroll
  for (int j=0;j<18;j++){
    int t = j>>1, ch = j&1;
    if (j<15){
      #pragma unroll
      for (int n=0;n<4;n++)
        bf[(j+3)&3][n] = *(const short8*)(wfrag + ((j+3)*16 + n)*128);
    }
    int ky = t/3, kx = t - ky*3;
    int jc = ch*4 + lk;
    #pragma unroll
    for (int mt=0; mt<2; mt++){
      int pidx = (w*2+mt+ky)*18 + lx + kx;
      #pragma unroll
      for (int p=0;p<NPL;p++){
        short8 af = *(const short8*)(A + p*11520 + pidx*64 + ((jc ^ (pidx&7))<<3));
        #pragma unroll
        for (int n=0;n<4;n++)
          acc[mt][n] = __builtin_amdgcn_mfma_f32_16x16x32_bf16(af, bf[j&3][n], acc[mt][n], 0,0,0);
      }
    }
  }
  int ybase = blockIdx.y*8 + w*2;
  int xbase = blockIdx.x*16 + lk*4;
  #pragma unroll
  for (int mt=0;mt<2;mt++){
    int y = ybase + mt;
    #pragma unroll
    for (int n=0;n<4;n++){
      int ocg = ocb*64 + n*16 + lx;
      if (ocg < Cout){
        float bv = has_bias ? bias[ocg] : 0.f;
        #pragma unroll
        for (int r=0;r<4;r++){
          int xg = xbase + r;
          float v = acc[mt][n][r] + bv;
          if (add_hi){
            long ap = ((long)img*add_ps + y*WW + xg)*add_cs + ocg;
            v += bfu2f(add_hi[ap]) + bfu2f(add_lo[ap]);
          }
          if (relu) v = fmaxf(v, 0.f);
          if (out_pf){
            out_pf[((long)img*pf_C + ocg)*HW + y*WW + xg] = v;
          } else {
            long pp = (long)img*out_ps + y*WW + xg;
            ush h = f2bfu(v);
            out_hi[pp*out_cs + ocg] = h;
            if (out_lo) out_lo[pp*out_cs + ocg] = f2bfu(v - bfu2f(h));
          }
        }
      }
    }
  }
}

// ---------- repack NHWC hi/lo -> group-planar f32 [4][8][HW][8]
// tid = pix*8 + c8: coalesced 16B reads, 32B writes per group plane
__global__ __launch_bounds__(256) void repack_gp(const ush* __restrict__ in_h,
    const ush* __restrict__ in_l, long in_ps, float* __restrict__ gp){
  long idx = (long)blockIdx.x*256 + threadIdx.x;   // over 4*HW*8 = 524288
  int img = (int)(idx >> 17);
  int rem = (int)(idx & 131071);
  int pix = rem >> 3, c8 = rem & 7;
  long src = ((long)img*in_ps + pix)*64 + c8*8;
  short8 h = *(const short8*)(in_h+src);
  short8 lo = *(const short8*)(in_l+src);
  float* d = gp + (((long)(img*8+c8))*HW + pix)*8;
  #pragma unroll
  for (int c=0;c<8;c++) d[c] = bfu2f((ush)h[c]) + bfu2f((ush)lo[c]);
}

// ---------- MFMA modulated deformable conv; gp f32 group-planar in
__global__ __launch_bounds__(256) void dcn_mfma(
    const float* __restrict__ gp,
    const float* __restrict__ om,
    const ush* __restrict__ wpk,
    const float* __restrict__ bias,
    ush* __restrict__ out_hi, ush* __restrict__ out_lo)
{
  __shared__ ush Ah[128*104];
  __shared__ ush Al[128*104];
  __shared__ ush Bt[64*104];
  int tid = threadIdx.x;
  int gy = blockIdx.x, img = blockIdx.y;
  {
    short8 z = {0,0,0,0,0,0,0,0};
    for (int j=tid; j<384; j+=256){
      int px = j/3, c = j - px*3;
      *(short8*)(Ah + px*104 + 72 + c*8) = z;
      *(short8*)(Al + px*104 + 72 + c*8) = z;
    }
  }
  int w = tid>>6, l = tid&63, lx = l&15, lk = l>>4;
  int px_s = tid & 127, hf = tid >> 7;
  const float* omb = om + (long)img*216*HW + gy*WW + px_s;
  floatx4 acc[2][4];
  #pragma unroll
  for (int mt=0;mt<2;mt++)
    #pragma unroll
    for (int n=0;n<4;n++) acc[mt][n] = (floatx4){0.f,0.f,0.f,0.f};

  #pragma unroll 1
  for (int g=0; g<8; g++){
    __syncthreads();
    const ush* wsrc = wpk + g*6144;
    for (int j=tid; j<768; j+=256){
      int oc = j/12, kc = j - oc*12;
      *(short8*)(Bt + oc*104 + kc*8) = *(const short8*)(wsrc + oc*96 + kc*8);
    }
    const float* gpb = gp + ((long)(img*8+g))*HW*8;
    int t0 = hf ? 5 : 0, t1 = hf ? 9 : 5;
    #pragma unroll 1
    for (int t=t0; t<t1; t++){
      int ch = g*9+t;
      float dy = omb[(long)ch*HW];
      float dx = omb[(long)(72+ch)*HW];
      float mv = omb[(long)(144+ch)*HW];
      float m = 1.f/(1.f+__expf(-mv));
      float py = (float)gy + (float)(t/3 - 1) + dy;
      float pxf = (float)px_s + (float)(t%3 - 1) + dx;
      float fy = floorf(py), fx = floorf(pxf);
      int y0 = (int)fy, x0 = (int)fx;
      float wy = py - fy, wx = pxf - fx;
      bool y0v = (y0>=0 && y0<HH), y1v = (y0+1>=0 && y0+1<HH);
      bool x0v = (x0>=0 && x0<WW), x1v = (x0+1>=0 && x0+1<WW);
      float w00 = (1.f-wy)*(1.f-wx)*m * ((y0v&&x0v)?1.f:0.f);
      float w01 = (1.f-wy)*wx*m      * ((y0v&&x1v)?1.f:0.f);
      float w10 = wy*(1.f-wx)*m      * ((y1v&&x0v)?1.f:0.f);
      float w11 = wy*wx*m            * ((y1v&&x1v)?1.f:0.f);
      int y0c = min(max(y0,0),HH-1), y1c = min(max(y0+1,0),HH-1);
      int x0c = min(max(x0,0),WW-1), x1c = min(max(x0+1,0),WW-1);
      const float* p00 = gpb + (((long)(y0c*WW+x0c))<<3);
      const float* p01 = gpb + (((long)(y0c*WW+x1c))<<3);
      const float* p10 = gpb + (((long)(y1c*WW+x0c))<<3);
      const float* p11 = gpb + (((long)(y1c*WW+x1c))<<3);
      float4 a00=*(const float4*)p00, b00=*(const float4*)(p00+4);
      float4 a01=*(const float4*)p01, b01=*(const float4*)(p01+4);
      float4 a10=*(const float4*)p10, b10=*(const float4*)(p10+4);
      float4 a11=*(const float4*)p11, b11=*(const float4*)(p11+4);
      float val[8];
      val[0]=w00*a00.x+w01*a01.x+w10*a10.x+w11*a11.x;
      val[1]=w00*a00.y+w01*a01.y+w10*a10.y+w11*a11.y;
      val[2]=w00*a00.z+w01*a01.z+w10*a10.z+w11*a11.z;
      val[3]=w00*a00.w+w01*a01.w+w10*a10.w+w11*a11.w;
      val[4]=w00*b00.x+w01*b01.x+w10*b10.x+w11*b11.x;
      val[5]=w00*b00.y+w01*b01.y+w10*b10.y+w11*b11.y;
      val[6]=w00*b00.z+w01*b01.z+w10*b10.z+w11*b11.z;
      val[7]=w00*b00.w+w01*b01.w+w10*b10.w+w11*b11.w;
      short8 vh, vl;
      #pragma unroll
      for (int c=0;c<8;c++){
        ush h = f2bfu(val[c]);
        vh[c] = (short)h;
        vl[c] = (short)f2bfu(val[c] - bfu2f(h));
      }
      *(short8*)(Ah + px_s*104 + t*8) = vh;
      *(short8*)(Al + px_s*104 + t*8) = vl;
    }
    __syncthreads();
    #pragma unroll
    for (int ks=0; ks<3; ks++){
      short8 bfg[4];
      #pragma unroll
      for (int n=0;n<4;n++)
        bfg[n] = *(const short8*)(Bt + (n*16+lx)*104 + ks*32 + lk*8);
      #pragma unroll
      for (int mt=0; mt<2; mt++){
        int px = (w*2+mt)*16 + lx;
        short8 ah = *(const short8*)(Ah + px*104 + ks*32 + lk*8);
        short8 al = *(const short8*)(Al + px*104 + ks*32 + lk*8);
        #pragma unroll
        for (int n=0;n<4;n++){
          acc[mt][n] = __builtin_amdgcn_mfma_f32_16x16x32_bf16(ah, bfg[n], acc[mt][n], 0,0,0);
          acc[mt][n] = __builtin_amdgcn_mfma_f32_16x16x32_bf16(al, bfg[n], acc[mt][n], 0,0,0);
        }
      }
    }
  }
  long base = ((long)img*HW + gy*WW)*64;
  #pragma unroll
  for (int mt=0;mt<2;mt++){
    #pragma unroll
    for (int n=0;n<4;n++){
      int oc = n*16 + lx;
      float bv = bias[oc];
      #pragma unroll
      for (int r=0;r<4;r++){
        int pxl = (w*2+mt)*16 + lk*4 + r;
        float v = acc[mt][n][r] + bv;
        ush h = f2bfu(v);
        out_hi[base + (long)pxl*64 + oc] = h;
        out_lo[base + (long)pxl*64 + oc] = f2bfu(v - bfu2f(h));
      }
    }
  }
}

// ---------- reconstruction conv: channel-split + LDS reduce
__global__ __launch_bounds__(256) void rec_kernel(
    const ush* __restrict__ fh, const ush* __restrict__ fl,
    const float* __restrict__ wT, const float* __restrict__ bias,
    void* __restrict__ out, int ni, const float* __restrict__ flag){
  __shared__ float red[256];
  int tid = threadIdx.x;
  int p = tid & 31, q = tid >> 5;
  int gx = blockIdx.x*32 + p;
  int gy = blockIdx.y;
  int b = blockIdx.z;
  float acc = 0.f;
  #pragma unroll
  for (int t=0;t<9;t++){
    int yy = gy + t/3 - 1, xx = gx + t%3 - 1;
    if (yy<0||yy>=HH||xx<0||xx>=WW) continue;
    long base = ((long)b*HW + yy*WW + xx)*64 + q*8;
    short8 h = *(const short8*)(fh + base);
    short8 lo = *(const short8*)(fl + base);
    #pragma unroll
    for (int cc=0;cc<8;cc++){
      float v = bfu2f((ush)h[cc]) + bfu2f((ush)lo[cc]);
      acc = fmaf(v, wT[(q*8+cc)*9 + t], acc);
    }
  }
  red[q*32+p] = acc;
  __syncthreads();
  if (tid < 32){
    float s = bias[0];
    #pragma unroll
    for (int k=0;k<8;k++) s += red[k*32+tid];
    long idx = ((long)b*5+ni)*HW + gy*WW + blockIdx.x*32 + tid;
    if (flag[0] > 0.5f) ((bf16*)out)[idx] = __float2bfloat16(s);
    else                ((float*)out)[idx] = s;
  }
}

extern "C" void kernel_launch(void* const* d_in, const int* in_sizes, int n_in,
                              void* d_out, int out_size, void* d_ws, size_t ws_size,
                              hipStream_t stream) {
  float* ws = (float*)d_ws;

  size_t off = 16;
  auto alloc = [&](size_t nel){ size_t o = off; off += (nel + 7) & ~(size_t)7; return o; };

  static const int IN_N[17] = {327680, 576, 64, 184320, 320, 184320, 320,
                               73728, 64, 147456, 256, 497664, 864, 147456,
                               256, 576, 1};
  size_t cin[17];
  for (int i=0;i<17;i++) cin[i] = alloc(IN_N[i]);

  size_t wt_init = alloc(640);
  size_t wdcn_pk[4]; for (int s=0;s<4;s++) wdcn_pk[s] = alloc(24576);
  size_t wt_rec = alloc(640);
  size_t pk_res1[5], pk_res2[5];
  for (int i=0;i<5;i++) pk_res1[i] = alloc(18432);
  for (int i=0;i<5;i++) pk_res2[i] = alloc(18432);
  size_t pk_bn[2]; for (int h=0;h<2;h++) pk_bn[h] = alloc(18432);
  size_t pk_off[4]; for (int s=0;s<4;s++) pk_off[s] = alloc(18432);
  size_t pk_com[4]; for (int s=0;s<4;s++) pk_com[s] = alloc(73728);

  size_t feat_h_o = alloc(10485760);
  size_t feat_l_o = alloc(10485760);
  size_t U = alloc(26738688);

  ush* feat_h = (ush*)(ws + feat_h_o);
  ush* feat_l = (ush*)(ws + feat_l_o);
  ush* feaA_h = (ush*)(ws + U);
  ush* feaA_l = (ush*)(ws + U + 2097152);
  ush* feaB_h = (ush*)(ws + U + 4194304);
  ush* feaB_l = (ush*)(ws + U + 6291456);
  ush* obuf_h = (ush*)(ws + U + 8388608);
  ush* obuf_l = (ush*)(ws + U + 10485760);
  float* gpbuf = ws + U + 8388608;       // f32 gp aliases obuf (dead when gp live)
  float* ombuf = ws + U + 12582912;
  ush* hbuf_h = (ush*)(ws + U);
  ush* hbuf_l = (ush*)(ws + U + 10485760);
  ush* part_h = obuf_h;
  ush* part_l = obuf_l;

  float* flag = ws;

  detect_dtype<<<dim3(1), dim3(256), 0, stream>>>((const ush*)d_in[0], flag);
  for (int i=0;i<17;i++){
    int n = IN_N[i];
    convert_in<<<dim3((n+255)/256), dim3(256), 0, stream>>>(d_in[i], ws+cin[i], n, flag);
  }
  const float* b_init = ws+cin[2];
  const float* res_b1 = ws+cin[4];
  const float* res_b2 = ws+cin[6];
  const float* b_bn   = ws+cin[8];
  const float* off_b  = ws+cin[10];
  const float* com_b  = ws+cin[12];
  const float* dcn_b  = ws+cin[14];
  const float* b_rec  = ws+cin[16];

  auto tr = [&](size_t src_o, size_t dst_o, int Co, int CiK){
    int total = Co*CiK;
    transpose_w<<<dim3((total+255)/256), dim3(256), 0, stream>>>(ws+src_o, ws+dst_o, Co, CiK);
  };
  tr(cin[1], wt_init, 64, 9);
  tr(cin[15], wt_rec, 1, 576);
  for (int s=0;s<4;s++)
    pack_dcn_w<<<dim3(192), dim3(256), 0, stream>>>(ws+cin[13]+(size_t)s*36864,
                                                    (ush*)(ws+wdcn_pk[s]));

  auto pack = [&](size_t src_o, size_t dst_o, int Cout, int Cin, int kh, int nOcB){
    int total = nOcB*36864;
    pack_w2<<<dim3((total+255)/256), dim3(256), 0, stream>>>(
        ws+src_o, (ush*)(ws+dst_o), Cout, Cin, kh, nOcB);
  };
  for (int i=0;i<5;i++) pack(cin[3]+(size_t)i*36864, pk_res1[i], 64, 64, 0, 1);
  for (int i=0;i<5;i++) pack(cin[5]+(size_t)i*36864, pk_res2[i], 64, 64, 0, 1);
  for (int h=0;h<2;h++) pack(cin[7], pk_bn[h], 64, 128, h, 1);
  for (int s=0;s<4;s++) pack(cin[9]+(size_t)s*36864,  pk_off[s], 64, 64, 0, 1);
  for (int s=0;s<4;s++) pack(cin[11]+(size_t)s*124416, pk_com[s], 216, 64, 0, 4);

  dim3 cblk(256);
  auto conv = [&](const ush* in_h, const ush* in_l, long in_ps, size_t pk,
                  const float* bias, int has_bias,
                  const ush* add_h, const ush* add_l, long add_ps, int add_cs,
                  ush* o_h, ush* o_l, long out_ps, int out_cs,
                  float* o_pf, int pf_C,
                  int Cout, int nOcB, int relu, int N, int nPl){
    if (nPl == 2)
      conv_mfma<2,2><<<dim3(8,16,N*nOcB), cblk, 0, stream>>>(
          in_h, in_l, in_ps, (const ush*)(ws+pk), bias, has_bias,
          add_h, add_l, add_ps, add_cs, o_h, o_l, out_ps, out_cs,
          o_pf, pf_C, Cout, nOcB, relu);
    else
      conv_mfma<1,3><<<dim3(8,16,N*nOcB), cblk, 0, stream>>>(
          in_h, in_l, in_ps, (const ush*)(ws+pk), bias, has_bias,
          add_h, add_l, add_ps, add_cs, o_h, o_l, out_ps, out_cs,
          o_pf, pf_C, Cout, nOcB, relu);
  };

  // ---- feature extraction
  conv_init_kernel<<<dim3(8,8,20), cblk, 0, stream>>>(ws+cin[0], ws+wt_init, b_init,
                                                      feat_h, feat_l);
  for (int i=0;i<5;i++){
    conv(feat_h, feat_l, HW, pk_res1[i], res_b1+(size_t)i*64, 1,
         nullptr, nullptr, 0, 0, hbuf_h, hbuf_l, HW, 64, nullptr, 0, 64, 1, 1, 20, 2);
    conv(hbuf_h, hbuf_l, HW, pk_res2[i], res_b2+(size_t)i*64, 1,
         feat_h, feat_l, HW, 64, feat_h, feat_l, HW, 64, nullptr, 0, 64, 1, 0, 20, 2);
  }
  // ---- per-neighbor alignment
  for (int i=0;i<5;i++){
    conv(feat_h + (size_t)2*HW*64, feat_l + (size_t)2*HW*64, 5L*HW, pk_bn[0], b_bn, 1,
         nullptr, nullptr, 0, 0, part_h, part_l, HW, 64, nullptr, 0, 64, 1, 0, 4, 2);
    conv(feat_h + (size_t)i*HW*64, feat_l + (size_t)i*HW*64, 5L*HW, pk_bn[1], b_bn, 0,
         part_h, part_l, HW, 64, feaA_h, feaA_l, HW, 64, nullptr, 0, 64, 1, 0, 4, 2);
    ush *fa_h = feaA_h, *fa_l = feaA_l, *fb_h = feaB_h, *fb_l = feaB_l;
    for (int s=0;s<4;s++){
      conv(fa_h, fa_l, HW, pk_off[s], off_b+(size_t)s*64, 1,
           nullptr, nullptr, 0, 0, obuf_h, nullptr, HW, 64, nullptr, 0, 64, 1, 0, 4, 2);
      conv(obuf_h, obuf_h, HW, pk_com[s], com_b+(size_t)s*216, 1,
           nullptr, nullptr, 0, 0, nullptr, nullptr, 0, 0, ombuf, 216, 216, 4, 0, 4, 1);
      const ush *xs_h, *xs_l; long xps;
      if (s == 2){ xs_h = feat_h + (size_t)i*HW*64; xs_l = feat_l + (size_t)i*HW*64; xps = 5L*HW; }
      else       { xs_h = fa_h;                     xs_l = fa_l;                     xps = HW; }
      repack_gp<<<dim3(2048), cblk, 0, stream>>>(xs_h, xs_l, xps, gpbuf);
      dcn_mfma<<<dim3(128,4), cblk, 0, stream>>>(gpbuf, ombuf,
          (const ush*)(ws+wdcn_pk[s]), dcn_b+(size_t)s*64, fb_h, fb_l);
      ush* t;
      t = fa_h; fa_h = fb_h; fb_h = t;
      t = fa_l; fa_l = fb_l; fb_l = t;
    }
    rec_kernel<<<dim3(4,128,4), cblk, 0, stream>>>(fa_h, fa_l, ws+wt_rec, b_rec, d_out, i, flag);
  }
}

// Round 11
// 3967.754 us; speedup vs baseline: 2.0484x; 1.0345x over previous
//
#include <hip/hip_runtime.h>
#include <hip/hip_bf16.h>

typedef __hip_bfloat16 bf16;
typedef __attribute__((ext_vector_type(8))) short short8;
typedef __attribute__((ext_vector_type(4))) float floatx4;
typedef unsigned short ush;

#define HH 128
#define WW 128
#define HW 16384

__device__ __forceinline__ float b2f(bf16 v){ return __bfloat162float(v); }
__device__ __forceinline__ float bfu2f(ush u){
  union{unsigned int i; float f;} c; c.i = ((unsigned int)u)<<16; return c.f;
}
__device__ __forceinline__ ush f2bfu(float f){
  bf16 h = __float2bfloat16(f);
  return *(ush*)&h;
}

// ---------- dtype detector: flag=1.0 if x is bf16, 0.0 if f32
__global__ void detect_dtype(const ush* __restrict__ x, float* __restrict__ flag){
  __shared__ int bad;
  if (threadIdx.x==0) bad = 0;
  __syncthreads();
  for (int j=threadIdx.x; j<4096; j+=256){
    float f = bfu2f(x[j]);
    if (!(fabsf(f) < 1e4f)) atomicOr(&bad, 1);
  }
  __syncthreads();
  if (threadIdx.x==0) flag[0] = bad ? 0.f : 1.f;
}

// ---------- input convert: src (bf16 or f32 per flag) -> f32
__global__ void convert_in(const void* __restrict__ src, float* __restrict__ dst, int n,
                           const float* __restrict__ flag){
  int i = blockIdx.x*256 + threadIdx.x;
  if (i >= n) return;
  float v = (flag[0] > 0.5f) ? b2f(((const bf16*)src)[i]) : ((const float*)src)[i];
  dst[i] = v;
}

// ---------- weight transpose: src f32 [Co][CiK] -> dst f32 [CiK][Co]
__global__ void transpose_w(const float* __restrict__ src, float* __restrict__ dst, int Co, int CiK){
  int tid = blockIdx.x*256 + threadIdx.x;
  if (tid >= Co*CiK) return;
  int co = tid / CiK, r = tid - co*CiK;
  dst[(long)r*Co + co] = src[tid];
}

// ---------- weight pack v2: f32 [Cout][Cin][3][3] -> bf16 fragment-order
__global__ void pack_w2(const float* __restrict__ src, ush* __restrict__ dst,
                        int Cout, int Cin, int kh, int nOcB){
  int idx = blockIdx.x*256 + threadIdx.x;
  int total = nOcB*36864;
  if (idx >= total) return;
  int ocb = idx / 36864; int r = idx - ocb*36864;
  int c  = r & 7;
  int lx = (r>>3) & 15;
  int n  = (r>>7) & 3;
  int lk = (r>>9) & 3;
  int j  = r>>11;
  int t = j>>1, ch = j&1;
  int oc = n*16+lx;
  int k = ch*32 + lk*8 + c;
  int ocg = ocb*64 + oc, icg = kh*64 + k;
  float v = (ocg < Cout && icg < Cin) ? src[((long)ocg*Cin + icg)*9 + t] : 0.f;
  dst[idx] = f2bfu(v);
}

// ---------- DCN weight pack: f32 [64 oc][64 ic][9] -> bf16 [8 g][64 oc][96]
__global__ void pack_dcn_w(const float* __restrict__ src, ush* __restrict__ dst){
  int idx = blockIdx.x*256 + threadIdx.x;
  if (idx >= 49152) return;
  int g = idx / 6144; int r = idx - g*6144;
  int oc = r / 96; int k = r - oc*96;
  float v = 0.f;
  if (k < 72){
    int tap = k >> 3, c = k & 7;
    v = src[((long)oc*64 + g*8 + c)*9 + tap];
  }
  dst[idx] = f2bfu(v);
}

// ---------- conv_init: x f32 [20][HW] -> feat NHWC hi/lo bf16 [20][HW][64], relu
__global__ __launch_bounds__(256) void conv_init_kernel(const float* __restrict__ x,
    const float* __restrict__ wT, const float* __restrict__ bias,
    ush* __restrict__ fh, ush* __restrict__ fl){
  __shared__ ush L[256*66];
  int tid = threadIdx.x;
  int tx = tid & 15, ty = tid >> 4;
  int gx = blockIdx.x*16+tx, gy = blockIdx.y*16+ty;
  int n = blockIdx.z;
  const float* xp = x + (long)n*HW;
  float v[9];
  #pragma unroll
  for (int dy=0;dy<3;dy++)
    #pragma unroll
    for (int dx=0;dx<3;dx++){
      int yy = gy+dy-1, xx = gx+dx-1;
      bool ok = (yy>=0)&&(yy<HH)&&(xx>=0)&&(xx<WW);
      v[dy*3+dx] = ok ? xp[yy*WW+xx] : 0.f;
    }
  float acc[64];
  #pragma unroll 1
  for (int oc=0; oc<64; oc++){
    float a = bias[oc];
    #pragma unroll
    for (int k=0;k<9;k++) a = fmaf(v[k], wT[k*64+oc], a);
    acc[oc] = fmaxf(a, 0.f);
  }
  #pragma unroll 1
  for (int pass=0; pass<2; pass++){
    #pragma unroll 1
    for (int oc=0; oc<64; oc++){
      float a = acc[oc];
      ush h = f2bfu(a);
      L[tid*66+oc] = pass ? f2bfu(a - bfu2f(h)) : h;
    }
    __syncthreads();
    ush* dst = pass ? fl : fh;
    for (int j=tid; j<2048; j+=256){
      int c8 = j&7, pidx = j>>3;
      int row = pidx>>4, col = pidx&15;
      long addr = ((long)n*HW + (blockIdx.y*16+row)*WW + blockIdx.x*16+col)*64 + c8*8;
      *(short8*)(dst+addr) = *(const short8*)(L + pidx*66 + c8*8);
    }
    __syncthreads();
  }
}

// ---------- MFMA implicit-GEMM 3x3 SAME conv.
// NPL = activation planes, MT = M-tiles per wave (rows per block = 4*MT).
template<int NPL, int MINW, int MT>
__global__ __launch_bounds__(256, MINW) void conv_mfma(
    const ush* __restrict__ in_hi, const ush* __restrict__ in_lo, long in_ps,
    const ush* __restrict__ wpack,
    const float* __restrict__ bias, int has_bias,
    const ush* __restrict__ add_hi, const ush* __restrict__ add_lo,
    long add_ps, int add_cs,
    ush* __restrict__ out_hi, ush* __restrict__ out_lo,
    long out_ps, int out_cs,
    float* __restrict__ out_pf, int pf_C,
    int Cout, int nOcB, int relu)
{
  constexpr int ROWS = 4*MT + 2;
  constexpr int APX  = ROWS*18;
  __shared__ ush A[NPL*APX*64];
  int tid = threadIdx.x;
  int z = blockIdx.z; int img = z / nOcB; int ocb = z - img*nOcB;
  int x0 = blockIdx.x*16 - 1, y0 = blockIdx.y*(4*MT) - 1;
  int w = tid>>6, l = tid&63, lx = l&15, lk = l>>4;
  const ush* wfrag = wpack + (long)ocb*36864 + lk*4*128 + lx*8;
  const ush* ih = in_hi + (long)img*in_ps*64;
  const ush* il = in_lo + (long)img*in_ps*64;
  #pragma unroll
  for (int p=0;p<NPL;p++){
    const ush* src = p ? il : ih;
    ush* dstp = A + p*APX*64;
    for (int j=tid; j<APX*8; j+=256){
      int pidx = j>>3, c8 = j&7;
      int row = pidx/18, col = pidx - row*18;
      int yy = y0+row, xx = x0+col;
      uint4 v = make_uint4(0u,0u,0u,0u);
      if ((unsigned)yy < 128u && (unsigned)xx < 128u)
        v = *(const uint4*)(src + ((long)(yy*WW+xx))*64 + c8*8);
      *(uint4*)(dstp + pidx*64 + ((c8 ^ (pidx&7))<<3)) = v;
    }
  }
  floatx4 acc[MT][4];
  #pragma unroll
  for (int mt=0;mt<MT;mt++)
    #pragma unroll
    for (int n=0;n<4;n++) acc[mt][n] = (floatx4){0.f,0.f,0.f,0.f};
  short8 bf[4][4];
  #pragma unroll
  for (int s=0;s<3;s++)
    #pragma unroll
    for (int n=0;n<4;n++)
      bf[s][n] = *(const short8*)(wfrag + (s*16 + n)*128);
  __syncthreads();
  #pragma unroll
  for (int j=0;j<18;j++){
    int t = j>>1, ch = j&1;
    if (j<15){
      #pragma unroll
      for (int n=0;n<4;n++)
        bf[(j+3)&3][n] = *(const short8*)(wfrag + ((j+3)*16 + n)*128);
    }
    int ky = t/3, kx = t - ky*3;
    int jc = ch*4 + lk;
    #pragma unroll
    for (int mt=0; mt<MT; mt++){
      int pidx = (w*MT+mt+ky)*18 + lx + kx;
      #pragma unroll
      for (int p=0;p<NPL;p++){
        short8 af = *(const short8*)(A + p*APX*64 + pidx*64 + ((jc ^ (pidx&7))<<3));
        #pragma unroll
        for (int n=0;n<4;n++)
          acc[mt][n] = __builtin_amdgcn_mfma_f32_16x16x32_bf16(af, bf[j&3][n], acc[mt][n], 0,0,0);
      }
    }
  }
  int ybase = blockIdx.y*(4*MT) + w*MT;
  int xbase = blockIdx.x*16 + lk*4;
  #pragma unroll
  for (int mt=0;mt<MT;mt++){
    int y = ybase + mt;
    #pragma unroll
    for (int n=0;n<4;n++){
      int ocg = ocb*64 + n*16 + lx;
      if (ocg < Cout){
        float bv = has_bias ? bias[ocg] : 0.f;
        #pragma unroll
        for (int r=0;r<4;r++){
          int xg = xbase + r;
          float v = acc[mt][n][r] + bv;
          if (add_hi){
            long ap = ((long)img*add_ps + y*WW + xg)*add_cs + ocg;
            v += bfu2f(add_hi[ap]) + bfu2f(add_lo[ap]);
          }
          if (relu) v = fmaxf(v, 0.f);
          if (out_pf){
            out_pf[((long)img*pf_C + ocg)*HW + y*WW + xg] = v;
          } else {
            long pp = (long)img*out_ps + y*WW + xg;
            ush h = f2bfu(v);
            out_hi[pp*out_cs + ocg] = h;
            if (out_lo) out_lo[pp*out_cs + ocg] = f2bfu(v - bfu2f(h));
          }
        }
      }
    }
  }
}

// ---------- repack NHWC hi/lo -> group-planar f32 [4][8][HW][8]
__global__ __launch_bounds__(256) void repack_gp(const ush* __restrict__ in_h,
    const ush* __restrict__ in_l, long in_ps, float* __restrict__ gp){
  long idx = (long)blockIdx.x*256 + threadIdx.x;
  int img = (int)(idx >> 17);
  int rem = (int)(idx & 131071);
  int pix = rem >> 3, c8 = rem & 7;
  long src = ((long)img*in_ps + pix)*64 + c8*8;
  short8 h = *(const short8*)(in_h+src);
  short8 lo = *(const short8*)(in_l+src);
  float* d = gp + (((long)(img*8+c8))*HW + pix)*8;
  #pragma unroll
  for (int c=0;c<8;c++) d[c] = bfu2f((ush)h[c]) + bfu2f((ush)lo[c]);
}

// ---------- MFMA modulated deformable conv; gp f32 group-planar in,
// single-plane bf16 A (sampled values; lo plane dropped: 2^-9 rel, negligible)
__global__ __launch_bounds__(256) void dcn_mfma(
    const float* __restrict__ gp,
    const float* __restrict__ om,
    const ush* __restrict__ wpk,
    const float* __restrict__ bias,
    ush* __restrict__ out_hi, ush* __restrict__ out_lo)
{
  __shared__ ush Ah[128*104];
  __shared__ ush Bt[64*104];
  int tid = threadIdx.x;
  int gy = blockIdx.x, img = blockIdx.y;
  {
    short8 z = {0,0,0,0,0,0,0,0};
    for (int j=tid; j<384; j+=256){
      int px = j/3, c = j - px*3;
      *(short8*)(Ah + px*104 + 72 + c*8) = z;
    }
  }
  int w = tid>>6, l = tid&63, lx = l&15, lk = l>>4;
  int px_s = tid & 127, hf = tid >> 7;
  const float* omb = om + (long)img*216*HW + gy*WW + px_s;
  floatx4 acc[2][4];
  #pragma unroll
  for (int mt=0;mt<2;mt++)
    #pragma unroll
    for (int n=0;n<4;n++) acc[mt][n] = (floatx4){0.f,0.f,0.f,0.f};

  #pragma unroll 1
  for (int g=0; g<8; g++){
    __syncthreads();
    const ush* wsrc = wpk + g*6144;
    for (int j=tid; j<768; j+=256){
      int oc = j/12, kc = j - oc*12;
      *(short8*)(Bt + oc*104 + kc*8) = *(const short8*)(wsrc + oc*96 + kc*8);
    }
    const float* gpb = gp + ((long)(img*8+g))*HW*8;
    int t0 = hf ? 5 : 0, t1 = hf ? 9 : 5;
    #pragma unroll 1
    for (int t=t0; t<t1; t++){
      int ch = g*9+t;
      float dy = omb[(long)ch*HW];
      float dx = omb[(long)(72+ch)*HW];
      float mv = omb[(long)(144+ch)*HW];
      float m = 1.f/(1.f+__expf(-mv));
      float py = (float)gy + (float)(t/3 - 1) + dy;
      float pxf = (float)px_s + (float)(t%3 - 1) + dx;
      float fy = floorf(py), fx = floorf(pxf);
      int y0 = (int)fy, x0 = (int)fx;
      float wy = py - fy, wx = pxf - fx;
      bool y0v = (y0>=0 && y0<HH), y1v = (y0+1>=0 && y0+1<HH);
      bool x0v = (x0>=0 && x0<WW), x1v = (x0+1>=0 && x0+1<WW);
      float w00 = (1.f-wy)*(1.f-wx)*m * ((y0v&&x0v)?1.f:0.f);
      float w01 = (1.f-wy)*wx*m      * ((y0v&&x1v)?1.f:0.f);
      float w10 = wy*(1.f-wx)*m      * ((y1v&&x0v)?1.f:0.f);
      float w11 = wy*wx*m            * ((y1v&&x1v)?1.f:0.f);
      int y0c = min(max(y0,0),HH-1), y1c = min(max(y0+1,0),HH-1);
      int x0c = min(max(x0,0),WW-1), x1c = min(max(x0+1,0),WW-1);
      const float* p00 = gpb + (((long)(y0c*WW+x0c))<<3);
      const float* p01 = gpb + (((long)(y0c*WW+x1c))<<3);
      const float* p10 = gpb + (((long)(y1c*WW+x0c))<<3);
      const float* p11 = gpb + (((long)(y1c*WW+x1c))<<3);
      float4 a00=*(const float4*)p00, b00=*(const float4*)(p00+4);
      float4 a01=*(const float4*)p01, b01=*(const float4*)(p01+4);
      float4 a10=*(const float4*)p10, b10=*(const float4*)(p10+4);
      float4 a11=*(const float4*)p11, b11=*(const float4*)(p11+4);
      float val[8];
      val[0]=w00*a00.x+w01*a01.x+w10*a10.x+w11*a11.x;
      val[1]=w00*a00.y+w01*a01.y+w10*a10.y+w11*a11.y;
      val[2]=w00*a00.z+w01*a01.z+w10*a10.z+w11*a11.z;
      val[3]=w00*a00.w+w01*a01.w+w10*a10.w+w11*a11.w;
      val[4]=w00*b00.x+w01*b01.x+w10*b10.x+w11*b11.x;
      val[5]=w00*b00.y+w01*b01.y+w10*b10.y+w11*b11.y;
      val[6]=w00*b00.z+w01*b01.z+w10*b10.z+w11*b11.z;
      val[7]=w00*b00.w+w01*b01.w+w10*b10.w+w11*b11.w;
      short8 vh;
      #pragma unroll
      for (int c=0;c<8;c++) vh[c] = (short)f2bfu(val[c]);
      *(short8*)(Ah + px_s*104 + t*8) = vh;
    }
    __syncthreads();
    #pragma unroll
    for (int ks=0; ks<3; ks++){
      short8 bfg[4];
      #pragma unroll
      for (int n=0;n<4;n++)
        bfg[n] = *(const short8*)(Bt + (n*16+lx)*104 + ks*32 + lk*8);
      #pragma unroll
      for (int mt=0; mt<2; mt++){
        int px = (w*2+mt)*16 + lx;
        short8 ah = *(const short8*)(Ah + px*104 + ks*32 + lk*8);
        #pragma unroll
        for (int n=0;n<4;n++)
          acc[mt][n] = __builtin_amdgcn_mfma_f32_16x16x32_bf16(ah, bfg[n], acc[mt][n], 0,0,0);
      }
    }
  }
  long base = ((long)img*HW + gy*WW)*64;
  #pragma unroll
  for (int mt=0;mt<2;mt++){
    #pragma unroll
    for (int n=0;n<4;n++){
      int oc = n*16 + lx;
      float bv = bias[oc];
      #pragma unroll
      for (int r=0;r<4;r++){
        int pxl = (w*2+mt)*16 + lk*4 + r;
        float v = acc[mt][n][r] + bv;
        ush h = f2bfu(v);
        out_hi[base + (long)pxl*64 + oc] = h;
        out_lo[base + (long)pxl*64 + oc] = f2bfu(v - bfu2f(h));
      }
    }
  }
}

// ---------- reconstruction conv: channel-split + LDS reduce
__global__ __launch_bounds__(256) void rec_kernel(
    const ush* __restrict__ fh, const ush* __restrict__ fl,
    const float* __restrict__ wT, const float* __restrict__ bias,
    void* __restrict__ out, int ni, const float* __restrict__ flag){
  __shared__ float red[256];
  int tid = threadIdx.x;
  int p = tid & 31, q = tid >> 5;
  int gx = blockIdx.x*32 + p;
  int gy = blockIdx.y;
  int b = blockIdx.z;
  float acc = 0.f;
  #pragma unroll
  for (int t=0;t<9;t++){
    int yy = gy + t/3 - 1, xx = gx + t%3 - 1;
    if (yy<0||yy>=HH||xx<0||xx>=WW) continue;
    long base = ((long)b*HW + yy*WW + xx)*64 + q*8;
    short8 h = *(const short8*)(fh + base);
    short8 lo = *(const short8*)(fl + base);
    #pragma unroll
    for (int cc=0;cc<8;cc++){
      float v = bfu2f((ush)h[cc]) + bfu2f((ush)lo[cc]);
      acc = fmaf(v, wT[(q*8+cc)*9 + t], acc);
    }
  }
  red[q*32+p] = acc;
  __syncthreads();
  if (tid < 32){
    float s = bias[0];
    #pragma unroll
    for (int k=0;k<8;k++) s += red[k*32+tid];
    long idx = ((long)b*5+ni)*HW + gy*WW + blockIdx.x*32 + tid;
    if (flag[0] > 0.5f) ((bf16*)out)[idx] = __float2bfloat16(s);
    else                ((float*)out)[idx] = s;
  }
}

extern "C" void kernel_launch(void* const* d_in, const int* in_sizes, int n_in,
                              void* d_out, int out_size, void* d_ws, size_t ws_size,
                              hipStream_t stream) {
  float* ws = (float*)d_ws;

  size_t off = 16;
  auto alloc = [&](size_t nel){ size_t o = off; off += (nel + 7) & ~(size_t)7; return o; };

  static const int IN_N[17] = {327680, 576, 64, 184320, 320, 184320, 320,
                               73728, 64, 147456, 256, 497664, 864, 147456,
                               256, 576, 1};
  size_t cin[17];
  for (int i=0;i<17;i++) cin[i] = alloc(IN_N[i]);

  size_t wt_init = alloc(640);
  size_t wdcn_pk[4]; for (int s=0;s<4;s++) wdcn_pk[s] = alloc(24576);
  size_t wt_rec = alloc(640);
  size_t pk_res1[5], pk_res2[5];
  for (int i=0;i<5;i++) pk_res1[i] = alloc(18432);
  for (int i=0;i<5;i++) pk_res2[i] = alloc(18432);
  size_t pk_bn[2]; for (int h=0;h<2;h++) pk_bn[h] = alloc(18432);
  size_t pk_off[4]; for (int s=0;s<4;s++) pk_off[s] = alloc(18432);
  size_t pk_com[4]; for (int s=0;s<4;s++) pk_com[s] = alloc(73728);

  size_t feat_h_o = alloc(10485760);
  size_t feat_l_o = alloc(10485760);
  size_t U = alloc(26738688);

  ush* feat_h = (ush*)(ws + feat_h_o);
  ush* feat_l = (ush*)(ws + feat_l_o);
  ush* feaA_h = (ush*)(ws + U);
  ush* feaA_l = (ush*)(ws + U + 2097152);
  ush* feaB_h = (ush*)(ws + U + 4194304);
  ush* feaB_l = (ush*)(ws + U + 6291456);
  ush* obuf_h = (ush*)(ws + U + 8388608);
  ush* obuf_l = (ush*)(ws + U + 10485760);
  float* gpbuf = ws + U + 8388608;       // f32 gp aliases obuf (dead when gp live)
  float* ombuf = ws + U + 12582912;
  ush* hbuf_h = (ush*)(ws + U);
  ush* hbuf_l = (ush*)(ws + U + 10485760);
  ush* part_h = obuf_h;
  ush* part_l = obuf_l;

  float* flag = ws;

  detect_dtype<<<dim3(1), dim3(256), 0, stream>>>((const ush*)d_in[0], flag);
  for (int i=0;i<17;i++){
    int n = IN_N[i];
    convert_in<<<dim3((n+255)/256), dim3(256), 0, stream>>>(d_in[i], ws+cin[i], n, flag);
  }
  const float* b_init = ws+cin[2];
  const float* res_b1 = ws+cin[4];
  const float* res_b2 = ws+cin[6];
  const float* b_bn   = ws+cin[8];
  const float* off_b  = ws+cin[10];
  const float* com_b  = ws+cin[12];
  const float* dcn_b  = ws+cin[14];
  const float* b_rec  = ws+cin[16];

  auto tr = [&](size_t src_o, size_t dst_o, int Co, int CiK){
    int total = Co*CiK;
    transpose_w<<<dim3((total+255)/256), dim3(256), 0, stream>>>(ws+src_o, ws+dst_o, Co, CiK);
  };
  tr(cin[1], wt_init, 64, 9);
  tr(cin[15], wt_rec, 1, 576);
  for (int s=0;s<4;s++)
    pack_dcn_w<<<dim3(192), dim3(256), 0, stream>>>(ws+cin[13]+(size_t)s*36864,
                                                    (ush*)(ws+wdcn_pk[s]));

  auto pack = [&](size_t src_o, size_t dst_o, int Cout, int Cin, int kh, int nOcB){
    int total = nOcB*36864;
    pack_w2<<<dim3((total+255)/256), dim3(256), 0, stream>>>(
        ws+src_o, (ush*)(ws+dst_o), Cout, Cin, kh, nOcB);
  };
  for (int i=0;i<5;i++) pack(cin[3]+(size_t)i*36864, pk_res1[i], 64, 64, 0, 1);
  for (int i=0;i<5;i++) pack(cin[5]+(size_t)i*36864, pk_res2[i], 64, 64, 0, 1);
  for (int h=0;h<2;h++) pack(cin[7], pk_bn[h], 64, 128, h, 1);
  for (int s=0;s<4;s++) pack(cin[9]+(size_t)s*36864,  pk_off[s], 64, 64, 0, 1);
  for (int s=0;s<4;s++) pack(cin[11]+(size_t)s*124416, pk_com[s], 216, 64, 0, 4);

  dim3 cblk(256);
  // mtMode: 2 = 8-row tiles (big grids), 1 = 4-row tiles (small grids, 2x blocks)
  auto conv = [&](const ush* in_h, const ush* in_l, long in_ps, size_t pk,
                  const float* bias, int has_bias,
                  const ush* add_h, const ush* add_l, long add_ps, int add_cs,
                  ush* o_h, ush* o_l, long out_ps, int out_cs,
                  float* o_pf, int pf_C,
                  int Cout, int nOcB, int relu, int N, int nPl, int mtMode){
    if (nPl == 2 && mtMode == 2)
      conv_mfma<2,2,2><<<dim3(8,16,N*nOcB), cblk, 0, stream>>>(
          in_h, in_l, in_ps, (const ush*)(ws+pk), bias, has_bias,
          add_h, add_l, add_ps, add_cs, o_h, o_l, out_ps, out_cs,
          o_pf, pf_C, Cout, nOcB, relu);
    else if (nPl == 2 && mtMode == 1)
      conv_mfma<2,2,1><<<dim3(8,32,N*nOcB), cblk, 0, stream>>>(
          in_h, in_l, in_ps, (const ush*)(ws+pk), bias, has_bias,
          add_h, add_l, add_ps, add_cs, o_h, o_l, out_ps, out_cs,
          o_pf, pf_C, Cout, nOcB, relu);
    else
      conv_mfma<1,3,2><<<dim3(8,16,N*nOcB), cblk, 0, stream>>>(
          in_h, in_l, in_ps, (const ush*)(ws+pk), bias, has_bias,
          add_h, add_l, add_ps, add_cs, o_h, o_l, out_ps, out_cs,
          o_pf, pf_C, Cout, nOcB, relu);
  };

  // ---- feature extraction
  conv_init_kernel<<<dim3(8,8,20), cblk, 0, stream>>>(ws+cin[0], ws+wt_init, b_init,
                                                      feat_h, feat_l);
  for (int i=0;i<5;i++){
    conv(feat_h, feat_l, HW, pk_res1[i], res_b1+(size_t)i*64, 1,
         nullptr, nullptr, 0, 0, hbuf_h, hbuf_l, HW, 64, nullptr, 0, 64, 1, 1, 20, 2, 2);
    conv(hbuf_h, hbuf_l, HW, pk_res2[i], res_b2+(size_t)i*64, 1,
         feat_h, feat_l, HW, 64, feat_h, feat_l, HW, 64, nullptr, 0, 64, 1, 0, 20, 2, 2);
  }
  // ---- per-neighbor alignment
  for (int i=0;i<5;i++){
    conv(feat_h + (size_t)2*HW*64, feat_l + (size_t)2*HW*64, 5L*HW, pk_bn[0], b_bn, 1,
         nullptr, nullptr, 0, 0, part_h, part_l, HW, 64, nullptr, 0, 64, 1, 0, 4, 2, 1);
    conv(feat_h + (size_t)i*HW*64, feat_l + (size_t)i*HW*64, 5L*HW, pk_bn[1], b_bn, 0,
         part_h, part_l, HW, 64, feaA_h, feaA_l, HW, 64, nullptr, 0, 64, 1, 0, 4, 2, 1);
    ush *fa_h = feaA_h, *fa_l = feaA_l, *fb_h = feaB_h, *fb_l = feaB_l;
    for (int s=0;s<4;s++){
      conv(fa_h, fa_l, HW, pk_off[s], off_b+(size_t)s*64, 1,
           nullptr, nullptr, 0, 0, obuf_h, nullptr, HW, 64, nullptr, 0, 64, 1, 0, 4, 2, 1);
      conv(obuf_h, obuf_h, HW, pk_com[s], com_b+(size_t)s*216, 1,
           nullptr, nullptr, 0, 0, nullptr, nullptr, 0, 0, ombuf, 216, 216, 4, 0, 4, 1, 2);
      const ush *xs_h, *xs_l; long xps;
      if (s == 2){ xs_h = feat_h + (size_t)i*HW*64; xs_l = feat_l + (size_t)i*HW*64; xps = 5L*HW; }
      else       { xs_h = fa_h;                     xs_l = fa_l;                     xps = HW; }
      repack_gp<<<dim3(2048), cblk, 0, stream>>>(xs_h, xs_l, xps, gpbuf);
      dcn_mfma<<<dim3(128,4), cblk, 0, stream>>>(gpbuf, ombuf,
          (const ush*)(ws+wdcn_pk[s]), dcn_b+(size_t)s*64, fb_h, fb_l);
      ush* t;
      t = fa_h; fa_h = fb_h; fb_h = t;
      t = fa_l; fa_l = fb_l; fb_l = t;
    }
    rec_kernel<<<dim3(4,128,4), cblk, 0, stream>>>(fa_h, fa_l, ws+wt_rec, b_rec, d_out, i, flag);
  }
}

// Round 12
// 3680.633 us; speedup vs baseline: 2.2082x; 1.0780x over previous
//
#include <hip/hip_runtime.h>
#include <hip/hip_bf16.h>

typedef __hip_bfloat16 bf16;
typedef __attribute__((ext_vector_type(8))) short short8;
typedef __attribute__((ext_vector_type(4))) float floatx4;
typedef unsigned short ush;

#define HH 128
#define WW 128
#define HW 16384

__device__ __forceinline__ float b2f(bf16 v){ return __bfloat162float(v); }
__device__ __forceinline__ float bfu2f(ush u){
  union{unsigned int i; float f;} c; c.i = ((unsigned int)u)<<16; return c.f;
}
__device__ __forceinline__ ush f2bfu(float f){
  bf16 h = __float2bfloat16(f);
  return *(ush*)&h;
}

// ---------- dtype detector: flag=1.0 if x is bf16, 0.0 if f32
__global__ void detect_dtype(const ush* __restrict__ x, float* __restrict__ flag){
  __shared__ int bad;
  if (threadIdx.x==0) bad = 0;
  __syncthreads();
  for (int j=threadIdx.x; j<4096; j+=256){
    float f = bfu2f(x[j]);
    if (!(fabsf(f) < 1e4f)) atomicOr(&bad, 1);
  }
  __syncthreads();
  if (threadIdx.x==0) flag[0] = bad ? 0.f : 1.f;
}

// ---------- input convert
__global__ void convert_in(const void* __restrict__ src, float* __restrict__ dst, int n,
                           const float* __restrict__ flag){
  int i = blockIdx.x*256 + threadIdx.x;
  if (i >= n) return;
  float v = (flag[0] > 0.5f) ? b2f(((const bf16*)src)[i]) : ((const float*)src)[i];
  dst[i] = v;
}

// ---------- weight transpose: src f32 [Co][CiK] -> dst f32 [CiK][Co]
__global__ void transpose_w(const float* __restrict__ src, float* __restrict__ dst, int Co, int CiK){
  int tid = blockIdx.x*256 + threadIdx.x;
  if (tid >= Co*CiK) return;
  int co = tid / CiK, r = tid - co*CiK;
  dst[(long)r*Co + co] = src[tid];
}

// ---------- weight pack v2: fragment-order
__global__ void pack_w2(const float* __restrict__ src, ush* __restrict__ dst,
                        int Cout, int Cin, int kh, int nOcB){
  int idx = blockIdx.x*256 + threadIdx.x;
  int total = nOcB*36864;
  if (idx >= total) return;
  int ocb = idx / 36864; int r = idx - ocb*36864;
  int c  = r & 7;
  int lx = (r>>3) & 15;
  int n  = (r>>7) & 3;
  int lk = (r>>9) & 3;
  int j  = r>>11;
  int t = j>>1, ch = j&1;
  int oc = n*16+lx;
  int k = ch*32 + lk*8 + c;
  int ocg = ocb*64 + oc, icg = kh*64 + k;
  float v = (ocg < Cout && icg < Cin) ? src[((long)ocg*Cin + icg)*9 + t] : 0.f;
  dst[idx] = f2bfu(v);
}

// ---------- DCN weight pack
__global__ void pack_dcn_w(const float* __restrict__ src, ush* __restrict__ dst){
  int idx = blockIdx.x*256 + threadIdx.x;
  if (idx >= 49152) return;
  int g = idx / 6144; int r = idx - g*6144;
  int oc = r / 96; int k = r - oc*96;
  float v = 0.f;
  if (k < 72){
    int tap = k >> 3, c = k & 7;
    v = src[((long)oc*64 + g*8 + c)*9 + tap];
  }
  dst[idx] = f2bfu(v);
}

// ---------- conv_init
__global__ __launch_bounds__(256) void conv_init_kernel(const float* __restrict__ x,
    const float* __restrict__ wT, const float* __restrict__ bias,
    ush* __restrict__ fh, ush* __restrict__ fl){
  __shared__ ush L[256*66];
  int tid = threadIdx.x;
  int tx = tid & 15, ty = tid >> 4;
  int gx = blockIdx.x*16+tx, gy = blockIdx.y*16+ty;
  int n = blockIdx.z;
  const float* xp = x + (long)n*HW;
  float v[9];
  #pragma unroll
  for (int dy=0;dy<3;dy++)
    #pragma unroll
    for (int dx=0;dx<3;dx++){
      int yy = gy+dy-1, xx = gx+dx-1;
      bool ok = (yy>=0)&&(yy<HH)&&(xx>=0)&&(xx<WW);
      v[dy*3+dx] = ok ? xp[yy*WW+xx] : 0.f;
    }
  float acc[64];
  #pragma unroll 1
  for (int oc=0; oc<64; oc++){
    float a = bias[oc];
    #pragma unroll
    for (int k=0;k<9;k++) a = fmaf(v[k], wT[k*64+oc], a);
    acc[oc] = fmaxf(a, 0.f);
  }
  #pragma unroll 1
  for (int pass=0; pass<2; pass++){
    #pragma unroll 1
    for (int oc=0; oc<64; oc++){
      float a = acc[oc];
      ush h = f2bfu(a);
      L[tid*66+oc] = pass ? f2bfu(a - bfu2f(h)) : h;
    }
    __syncthreads();
    ush* dst = pass ? fl : fh;
    for (int j=tid; j<2048; j+=256){
      int c8 = j&7, pidx = j>>3;
      int row = pidx>>4, col = pidx&15;
      long addr = ((long)n*HW + (blockIdx.y*16+row)*WW + blockIdx.x*16+col)*64 + c8*8;
      *(short8*)(dst+addr) = *(const short8*)(L + pidx*66 + c8*8);
    }
    __syncthreads();
  }
}

// ---------- MFMA implicit-GEMM 3x3 SAME conv.
// NPL planes, MT M-tiles/wave. Optional fused second input (in2/wpack2).
// NHWC output path uses LDS-staged coalesced flush (reuses A).
template<int NPL, int MINW, int MT>
__global__ __launch_bounds__(256, MINW) void conv_mfma(
    const ush* __restrict__ in_hi, const ush* __restrict__ in_lo, long in_ps,
    const ush* __restrict__ in2_hi, const ush* __restrict__ in2_lo, long in2_ps,
    const ush* __restrict__ wpack, const ush* __restrict__ wpack2,
    const float* __restrict__ bias, int has_bias,
    const ush* __restrict__ add_hi, const ush* __restrict__ add_lo,
    long add_ps, int add_cs,
    ush* __restrict__ out_hi, ush* __restrict__ out_lo,
    long out_ps, int out_cs,
    float* __restrict__ out_pf, int pf_C,
    int Cout, int nOcB, int relu)
{
  constexpr int ROWS = 4*MT + 2;
  constexpr int APX  = ROWS*18;
  __shared__ ush A[NPL*APX*64];
  int tid = threadIdx.x;
  int z = blockIdx.z; int img = z / nOcB; int ocb = z - img*nOcB;
  int x0 = blockIdx.x*16 - 1, y0 = blockIdx.y*(4*MT) - 1;
  int w = tid>>6, l = tid&63, lx = l&15, lk = l>>4;
  floatx4 acc[MT][4];
  #pragma unroll
  for (int mt=0;mt<MT;mt++)
    #pragma unroll
    for (int n=0;n<4;n++) acc[mt][n] = (floatx4){0.f,0.f,0.f,0.f};

  auto phase = [&](const ush* ihb, const ush* ilb, const ush* wfb){
    __syncthreads();
    #pragma unroll
    for (int p=0;p<NPL;p++){
      const ush* src = p ? ilb : ihb;
      ush* dstp = A + p*APX*64;
      for (int j=tid; j<APX*8; j+=256){
        int pidx = j>>3, c8 = j&7;
        int row = pidx/18, col = pidx - row*18;
        int yy = y0+row, xx = x0+col;
        uint4 v = make_uint4(0u,0u,0u,0u);
        if ((unsigned)yy < 128u && (unsigned)xx < 128u)
          v = *(const uint4*)(src + ((long)(yy*WW+xx))*64 + c8*8);
        *(uint4*)(dstp + pidx*64 + ((c8 ^ (pidx&7))<<3)) = v;
      }
    }
    const ush* wfrag = wfb + lk*4*128 + lx*8;
    short8 bf[4][4];
    #pragma unroll
    for (int s=0;s<3;s++)
      #pragma unroll
      for (int n=0;n<4;n++)
        bf[s][n] = *(const short8*)(wfrag + (s*16 + n)*128);
    __syncthreads();
    #pragma unroll
    for (int j=0;j<18;j++){
      int t = j>>1, ch = j&1;
      if (j<15){
        #pragma unroll
        for (int n=0;n<4;n++)
          bf[(j+3)&3][n] = *(const short8*)(wfrag + ((j+3)*16 + n)*128);
      }
      int ky = t/3, kx = t - ky*3;
      int jc = ch*4 + lk;
      #pragma unroll
      for (int mt=0; mt<MT; mt++){
        int pidx = (w*MT+mt+ky)*18 + lx + kx;
        #pragma unroll
        for (int p=0;p<NPL;p++){
          short8 af = *(const short8*)(A + p*APX*64 + pidx*64 + ((jc ^ (pidx&7))<<3));
          #pragma unroll
          for (int n=0;n<4;n++)
            acc[mt][n] = __builtin_amdgcn_mfma_f32_16x16x32_bf16(af, bf[j&3][n], acc[mt][n], 0,0,0);
        }
      }
    }
  };
  phase(in_hi + (long)img*in_ps*64, in_lo + (long)img*in_ps*64,
        wpack + (long)ocb*36864);
  if (wpack2)
    phase(in2_hi + (long)img*in2_ps*64, in2_lo + (long)img*in2_ps*64,
          wpack2 + (long)ocb*36864);

  int ybase = blockIdx.y*(4*MT) + w*MT;
  int xbase = blockIdx.x*16 + lk*4;
  if (out_pf){
    #pragma unroll
    for (int mt=0;mt<MT;mt++){
      int y = ybase + mt;
      #pragma unroll
      for (int n=0;n<4;n++){
        int ocg = ocb*64 + n*16 + lx;
        if (ocg < Cout){
          float bv = has_bias ? bias[ocg] : 0.f;
          #pragma unroll
          for (int r=0;r<4;r++){
            int xg = xbase + r;
            out_pf[((long)img*pf_C + ocg)*HW + y*WW + xg] = acc[mt][n][r] + bv;
          }
        }
      }
    }
  } else {
    // LDS-staged coalesced epilogue (Cout==64, out_cs==64, ocb==0)
    constexpr int NPX = 4*MT*16;
    __syncthreads();
    ush* L0 = A;
    ush* L1 = A + NPX*66;
    #pragma unroll
    for (int mt=0;mt<MT;mt++){
      int y = ybase + mt;
      int rowl = w*MT + mt;
      #pragma unroll
      for (int n=0;n<4;n++){
        int ocg = n*16 + lx;
        float bv = has_bias ? bias[ocg] : 0.f;
        #pragma unroll
        for (int r=0;r<4;r++){
          int coll = lk*4 + r;
          float v = acc[mt][n][r] + bv;
          if (add_hi){
            long ap = ((long)img*add_ps + y*WW + blockIdx.x*16 + coll)*add_cs + ocg;
            v += bfu2f(add_hi[ap]) + bfu2f(add_lo[ap]);
          }
          if (relu) v = fmaxf(v, 0.f);
          ush h = f2bfu(v);
          L0[(rowl*16+coll)*66 + ocg] = h;
          if (out_lo) L1[(rowl*16+coll)*66 + ocg] = f2bfu(v - bfu2f(h));
        }
      }
    }
    __syncthreads();
    for (int j=tid; j<NPX*8; j+=256){
      int pidx = j>>3, c8 = j&7;
      int row = pidx>>4, col = pidx&15;
      long pp = (long)img*out_ps + (blockIdx.y*(4*MT)+row)*WW + blockIdx.x*16+col;
      *(short8*)(out_hi + pp*64 + c8*8) = *(const short8*)(L0 + pidx*66 + c8*8);
      if (out_lo)
        *(short8*)(out_lo + pp*64 + c8*8) = *(const short8*)(L1 + pidx*66 + c8*8);
    }
  }
}

// ---------- repack NHWC hi/lo -> group-planar f32 [4][8][HW][8]
__global__ __launch_bounds__(256) void repack_gp(const ush* __restrict__ in_h,
    const ush* __restrict__ in_l, long in_ps, float* __restrict__ gp){
  long idx = (long)blockIdx.x*256 + threadIdx.x;
  int img = (int)(idx >> 17);
  int rem = (int)(idx & 131071);
  int pix = rem >> 3, c8 = rem & 7;
  long src = ((long)img*in_ps + pix)*64 + c8*8;
  short8 h = *(const short8*)(in_h+src);
  short8 lo = *(const short8*)(in_l+src);
  float* d = gp + (((long)(img*8+c8))*HW + pix)*8;
  #pragma unroll
  for (int c=0;c<8;c++) d[c] = bfu2f((ush)h[c]) + bfu2f((ush)lo[c]);
}

// ---------- MFMA modulated deformable conv; single-plane A, staged epilogue
__global__ __launch_bounds__(256) void dcn_mfma(
    const float* __restrict__ gp,
    const float* __restrict__ om,
    const ush* __restrict__ wpk,
    const float* __restrict__ bias,
    ush* __restrict__ out_hi, ush* __restrict__ out_lo)
{
  __shared__ ush S[19968];           // Ah [128*104] + Bt [64*104]
  ush* Ah = S;
  ush* Bt = S + 13312;
  int tid = threadIdx.x;
  int gy = blockIdx.x, img = blockIdx.y;
  {
    short8 z = {0,0,0,0,0,0,0,0};
    for (int j=tid; j<384; j+=256){
      int px = j/3, c = j - px*3;
      *(short8*)(Ah + px*104 + 72 + c*8) = z;
    }
  }
  int w = tid>>6, l = tid&63, lx = l&15, lk = l>>4;
  int px_s = tid & 127, hf = tid >> 7;
  const float* omb = om + (long)img*216*HW + gy*WW + px_s;
  floatx4 acc[2][4];
  #pragma unroll
  for (int mt=0;mt<2;mt++)
    #pragma unroll
    for (int n=0;n<4;n++) acc[mt][n] = (floatx4){0.f,0.f,0.f,0.f};

  #pragma unroll 1
  for (int g=0; g<8; g++){
    __syncthreads();
    const ush* wsrc = wpk + g*6144;
    for (int j=tid; j<768; j+=256){
      int oc = j/12, kc = j - oc*12;
      *(short8*)(Bt + oc*104 + kc*8) = *(const short8*)(wsrc + oc*96 + kc*8);
    }
    const float* gpb = gp + ((long)(img*8+g))*HW*8;
    int t0 = hf ? 5 : 0, t1 = hf ? 9 : 5;
    #pragma unroll 1
    for (int t=t0; t<t1; t++){
      int ch = g*9+t;
      float dy = omb[(long)ch*HW];
      float dx = omb[(long)(72+ch)*HW];
      float mv = omb[(long)(144+ch)*HW];
      float m = 1.f/(1.f+__expf(-mv));
      float py = (float)gy + (float)(t/3 - 1) + dy;
      float pxf = (float)px_s + (float)(t%3 - 1) + dx;
      float fy = floorf(py), fx = floorf(pxf);
      int y0 = (int)fy, x0 = (int)fx;
      float wy = py - fy, wx = pxf - fx;
      bool y0v = (y0>=0 && y0<HH), y1v = (y0+1>=0 && y0+1<HH);
      bool x0v = (x0>=0 && x0<WW), x1v = (x0+1>=0 && x0+1<WW);
      float w00 = (1.f-wy)*(1.f-wx)*m * ((y0v&&x0v)?1.f:0.f);
      float w01 = (1.f-wy)*wx*m      * ((y0v&&x1v)?1.f:0.f);
      float w10 = wy*(1.f-wx)*m      * ((y1v&&x0v)?1.f:0.f);
      float w11 = wy*wx*m            * ((y1v&&x1v)?1.f:0.f);
      int y0c = min(max(y0,0),HH-1), y1c = min(max(y0+1,0),HH-1);
      int x0c = min(max(x0,0),WW-1), x1c = min(max(x0+1,0),WW-1);
      const float* p00 = gpb + (((long)(y0c*WW+x0c))<<3);
      const float* p01 = gpb + (((long)(y0c*WW+x1c))<<3);
      const float* p10 = gpb + (((long)(y1c*WW+x0c))<<3);
      const float* p11 = gpb + (((long)(y1c*WW+x1c))<<3);
      float4 a00=*(const float4*)p00, b00=*(const float4*)(p00+4);
      float4 a01=*(const float4*)p01, b01=*(const float4*)(p01+4);
      float4 a10=*(const float4*)p10, b10=*(const float4*)(p10+4);
      float4 a11=*(const float4*)p11, b11=*(const float4*)(p11+4);
      float val[8];
      val[0]=w00*a00.x+w01*a01.x+w10*a10.x+w11*a11.x;
      val[1]=w00*a00.y+w01*a01.y+w10*a10.y+w11*a11.y;
      val[2]=w00*a00.z+w01*a01.z+w10*a10.z+w11*a11.z;
      val[3]=w00*a00.w+w01*a01.w+w10*a10.w+w11*a11.w;
      val[4]=w00*b00.x+w01*b01.x+w10*b10.x+w11*b11.x;
      val[5]=w00*b00.y+w01*b01.y+w10*b10.y+w11*b11.y;
      val[6]=w00*b00.z+w01*b01.z+w10*b10.z+w11*b11.z;
      val[7]=w00*b00.w+w01*b01.w+w10*b10.w+w11*b11.w;
      short8 vh;
      #pragma unroll
      for (int c=0;c<8;c++) vh[c] = (short)f2bfu(val[c]);
      *(short8*)(Ah + px_s*104 + t*8) = vh;
    }
    __syncthreads();
    #pragma unroll
    for (int ks=0; ks<3; ks++){
      short8 bfg[4];
      #pragma unroll
      for (int n=0;n<4;n++)
        bfg[n] = *(const short8*)(Bt + (n*16+lx)*104 + ks*32 + lk*8);
      #pragma unroll
      for (int mt=0; mt<2; mt++){
        int px = (w*2+mt)*16 + lx;
        short8 ah = *(const short8*)(Ah + px*104 + ks*32 + lk*8);
        #pragma unroll
        for (int n=0;n<4;n++)
          acc[mt][n] = __builtin_amdgcn_mfma_f32_16x16x32_bf16(ah, bfg[n], acc[mt][n], 0,0,0);
      }
    }
  }
  // staged epilogue: S reused as L0[128][66] + L1 (needs 16896 <= 19968)
  __syncthreads();
  ush* L0 = S;
  ush* L1 = S + 128*66;
  #pragma unroll
  for (int mt=0;mt<2;mt++){
    #pragma unroll
    for (int n=0;n<4;n++){
      int oc = n*16 + lx;
      float bv = bias[oc];
      #pragma unroll
      for (int r=0;r<4;r++){
        int pxl = (w*2+mt)*16 + lk*4 + r;
        float v = acc[mt][n][r] + bv;
        ush h = f2bfu(v);
        L0[pxl*66 + oc] = h;
        L1[pxl*66 + oc] = f2bfu(v - bfu2f(h));
      }
    }
  }
  __syncthreads();
  long base = ((long)img*HW + gy*WW)*64;
  for (int j=tid; j<1024; j+=256){
    int pidx = j>>3, c8 = j&7;
    *(short8*)(out_hi + base + pidx*64 + c8*8) = *(const short8*)(L0 + pidx*66 + c8*8);
    *(short8*)(out_lo + base + pidx*64 + c8*8) = *(const short8*)(L1 + pidx*66 + c8*8);
  }
}

// ---------- reconstruction conv: channel-split + LDS reduce
__global__ __launch_bounds__(256) void rec_kernel(
    const ush* __restrict__ fh, const ush* __restrict__ fl,
    const float* __restrict__ wT, const float* __restrict__ bias,
    void* __restrict__ out, int ni, const float* __restrict__ flag){
  __shared__ float red[256];
  int tid = threadIdx.x;
  int p = tid & 31, q = tid >> 5;
  int gx = blockIdx.x*32 + p;
  int gy = blockIdx.y;
  int b = blockIdx.z;
  float acc = 0.f;
  #pragma unroll
  for (int t=0;t<9;t++){
    int yy = gy + t/3 - 1, xx = gx + t%3 - 1;
    if (yy<0||yy>=HH||xx<0||xx>=WW) continue;
    long base = ((long)b*HW + yy*WW + xx)*64 + q*8;
    short8 h = *(const short8*)(fh + base);
    short8 lo = *(const short8*)(fl + base);
    #pragma unroll
    for (int cc=0;cc<8;cc++){
      float v = bfu2f((ush)h[cc]) + bfu2f((ush)lo[cc]);
      acc = fmaf(v, wT[(q*8+cc)*9 + t], acc);
    }
  }
  red[q*32+p] = acc;
  __syncthreads();
  if (tid < 32){
    float s = bias[0];
    #pragma unroll
    for (int k=0;k<8;k++) s += red[k*32+tid];
    long idx = ((long)b*5+ni)*HW + gy*WW + blockIdx.x*32 + tid;
    if (flag[0] > 0.5f) ((bf16*)out)[idx] = __float2bfloat16(s);
    else                ((float*)out)[idx] = s;
  }
}

extern "C" void kernel_launch(void* const* d_in, const int* in_sizes, int n_in,
                              void* d_out, int out_size, void* d_ws, size_t ws_size,
                              hipStream_t stream) {
  float* ws = (float*)d_ws;

  size_t off = 16;
  auto alloc = [&](size_t nel){ size_t o = off; off += (nel + 7) & ~(size_t)7; return o; };

  static const int IN_N[17] = {327680, 576, 64, 184320, 320, 184320, 320,
                               73728, 64, 147456, 256, 497664, 864, 147456,
                               256, 576, 1};
  size_t cin[17];
  for (int i=0;i<17;i++) cin[i] = alloc(IN_N[i]);

  size_t wt_init = alloc(640);
  size_t wdcn_pk[4]; for (int s=0;s<4;s++) wdcn_pk[s] = alloc(24576);
  size_t wt_rec = alloc(640);
  size_t pk_res1[5], pk_res2[5];
  for (int i=0;i<5;i++) pk_res1[i] = alloc(18432);
  for (int i=0;i<5;i++) pk_res2[i] = alloc(18432);
  size_t pk_bn[2]; for (int h=0;h<2;h++) pk_bn[h] = alloc(18432);
  size_t pk_off[4]; for (int s=0;s<4;s++) pk_off[s] = alloc(18432);
  size_t pk_com[4]; for (int s=0;s<4;s++) pk_com[s] = alloc(73728);

  size_t feat_h_o = alloc(10485760);
  size_t feat_l_o = alloc(10485760);
  size_t U = alloc(26738688);

  ush* feat_h = (ush*)(ws + feat_h_o);
  ush* feat_l = (ush*)(ws + feat_l_o);
  ush* feaA_h = (ush*)(ws + U);
  ush* feaA_l = (ush*)(ws + U + 2097152);
  ush* feaB_h = (ush*)(ws + U + 4194304);
  ush* feaB_l = (ush*)(ws + U + 6291456);
  ush* obuf_h = (ush*)(ws + U + 8388608);
  ush* obuf_l = (ush*)(ws + U + 10485760);
  float* gpbuf = ws + U + 8388608;       // f32 gp aliases obuf (dead when gp live)
  float* ombuf = ws + U + 12582912;
  ush* hbuf_h = (ush*)(ws + U);
  ush* hbuf_l = (ush*)(ws + U + 10485760);

  float* flag = ws;

  detect_dtype<<<dim3(1), dim3(256), 0, stream>>>((const ush*)d_in[0], flag);
  for (int i=0;i<17;i++){
    int n = IN_N[i];
    convert_in<<<dim3((n+255)/256), dim3(256), 0, stream>>>(d_in[i], ws+cin[i], n, flag);
  }
  const float* b_init = ws+cin[2];
  const float* res_b1 = ws+cin[4];
  const float* res_b2 = ws+cin[6];
  const float* b_bn   = ws+cin[8];
  const float* off_b  = ws+cin[10];
  const float* com_b  = ws+cin[12];
  const float* dcn_b  = ws+cin[14];
  const float* b_rec  = ws+cin[16];

  auto tr = [&](size_t src_o, size_t dst_o, int Co, int CiK){
    int total = Co*CiK;
    transpose_w<<<dim3((total+255)/256), dim3(256), 0, stream>>>(ws+src_o, ws+dst_o, Co, CiK);
  };
  tr(cin[1], wt_init, 64, 9);
  tr(cin[15], wt_rec, 1, 576);
  for (int s=0;s<4;s++)
    pack_dcn_w<<<dim3(192), dim3(256), 0, stream>>>(ws+cin[13]+(size_t)s*36864,
                                                    (ush*)(ws+wdcn_pk[s]));

  auto pack = [&](size_t src_o, size_t dst_o, int Cout, int Cin, int kh, int nOcB){
    int total = nOcB*36864;
    pack_w2<<<dim3((total+255)/256), dim3(256), 0, stream>>>(
        ws+src_o, (ush*)(ws+dst_o), Cout, Cin, kh, nOcB);
  };
  for (int i=0;i<5;i++) pack(cin[3]+(size_t)i*36864, pk_res1[i], 64, 64, 0, 1);
  for (int i=0;i<5;i++) pack(cin[5]+(size_t)i*36864, pk_res2[i], 64, 64, 0, 1);
  for (int h=0;h<2;h++) pack(cin[7], pk_bn[h], 64, 128, h, 1);
  for (int s=0;s<4;s++) pack(cin[9]+(size_t)s*36864,  pk_off[s], 64, 64, 0, 1);
  for (int s=0;s<4;s++) pack(cin[11]+(size_t)s*124416, pk_com[s], 216, 64, 0, 4);

  dim3 cblk(256);
  auto conv = [&](const ush* in_h, const ush* in_l, long in_ps,
                  const ush* in2_h, const ush* in2_l, long in2_ps,
                  size_t pk, const ush* pk2p,
                  const float* bias, int has_bias,
                  const ush* add_h, const ush* add_l, long add_ps, int add_cs,
                  ush* o_h, ush* o_l, long out_ps, int out_cs,
                  float* o_pf, int pf_C,
                  int Cout, int nOcB, int relu, int N, int nPl, int mtMode){
    if (nPl == 2 && mtMode == 2)
      conv_mfma<2,2,2><<<dim3(8,16,N*nOcB), cblk, 0, stream>>>(
          in_h, in_l, in_ps, in2_h, in2_l, in2_ps,
          (const ush*)(ws+pk), pk2p, bias, has_bias,
          add_h, add_l, add_ps, add_cs, o_h, o_l, out_ps, out_cs,
          o_pf, pf_C, Cout, nOcB, relu);
    else if (nPl == 2 && mtMode == 1)
      conv_mfma<2,2,1><<<dim3(8,32,N*nOcB), cblk, 0, stream>>>(
          in_h, in_l, in_ps, in2_h, in2_l, in2_ps,
          (const ush*)(ws+pk), pk2p, bias, has_bias,
          add_h, add_l, add_ps, add_cs, o_h, o_l, out_ps, out_cs,
          o_pf, pf_C, Cout, nOcB, relu);
    else
      conv_mfma<1,3,2><<<dim3(8,16,N*nOcB), cblk, 0, stream>>>(
          in_h, in_l, in_ps, in2_h, in2_l, in2_ps,
          (const ush*)(ws+pk), pk2p, bias, has_bias,
          add_h, add_l, add_ps, add_cs, o_h, o_l, out_ps, out_cs,
          o_pf, pf_C, Cout, nOcB, relu);
  };

  // ---- feature extraction
  conv_init_kernel<<<dim3(8,8,20), cblk, 0, stream>>>(ws+cin[0], ws+wt_init, b_init,
                                                      feat_h, feat_l);
  for (int i=0;i<5;i++){
    conv(feat_h, feat_l, HW, nullptr, nullptr, 0, pk_res1[i], nullptr,
         res_b1+(size_t)i*64, 1,
         nullptr, nullptr, 0, 0, hbuf_h, hbuf_l, HW, 64, nullptr, 0, 64, 1, 1, 20, 2, 2);
    conv(hbuf_h, hbuf_l, HW, nullptr, nullptr, 0, pk_res2[i], nullptr,
         res_b2+(size_t)i*64, 1,
         feat_h, feat_l, HW, 64, feat_h, feat_l, HW, 64, nullptr, 0, 64, 1, 0, 20, 2, 2);
  }
  // ---- per-neighbor alignment
  for (int i=0;i<5;i++){
    // fused conv_bn over concatenated [ref, nei] via dual-phase kernel
    conv(feat_h + (size_t)2*HW*64, feat_l + (size_t)2*HW*64, 5L*HW,
         feat_h + (size_t)i*HW*64, feat_l + (size_t)i*HW*64, 5L*HW,
         pk_bn[0], (const ush*)(ws+pk_bn[1]), b_bn, 1,
         nullptr, nullptr, 0, 0, feaA_h, feaA_l, HW, 64, nullptr, 0, 64, 1, 0, 4, 2, 1);
    ush *fa_h = feaA_h, *fa_l = feaA_l, *fb_h = feaB_h, *fb_l = feaB_l;
    for (int s=0;s<4;s++){
      conv(fa_h, fa_l, HW, nullptr, nullptr, 0, pk_off[s], nullptr,
           off_b+(size_t)s*64, 1,
           nullptr, nullptr, 0, 0, obuf_h, nullptr, HW, 64, nullptr, 0, 64, 1, 0, 4, 2, 1);
      conv(obuf_h, obuf_h, HW, nullptr, nullptr, 0, pk_com[s], nullptr,
           com_b+(size_t)s*216, 1,
           nullptr, nullptr, 0, 0, nullptr, nullptr, 0, 0, ombuf, 216, 216, 4, 0, 4, 1, 2);
      const ush *xs_h, *xs_l; long xps;
      if (s == 2){ xs_h = feat_h + (size_t)i*HW*64; xs_l = feat_l + (size_t)i*HW*64; xps = 5L*HW; }
      else       { xs_h = fa_h;                     xs_l = fa_l;                     xps = HW; }
      repack_gp<<<dim3(2048), cblk, 0, stream>>>(xs_h, xs_l, xps, gpbuf);
      dcn_mfma<<<dim3(128,4), cblk, 0, stream>>>(gpbuf, ombuf,
          (const ush*)(ws+wdcn_pk[s]), dcn_b+(size_t)s*64, fb_h, fb_l);
      ush* t;
      t = fa_h; fa_h = fb_h; fb_h = t;
      t = fa_l; fa_l = fb_l; fb_l = t;
    }
    rec_kernel<<<dim3(4,128,4), cblk, 0, stream>>>(fa_h, fa_l, ws+wt_rec, b_rec, d_out, i, flag);
  }
}

// Round 13
// 3597.673 us; speedup vs baseline: 2.2591x; 1.0231x over previous
//
#include <hip/hip_runtime.h>
#include <hip/hip_bf16.h>

typedef __hip_bfloat16 bf16;
typedef __attribute__((ext_vector_type(8))) short short8;
typedef __attribute__((ext_vector_type(4))) float floatx4;
typedef unsigned short ush;

#define HH 128
#define WW 128
#define HW 16384

__device__ __forceinline__ float b2f(bf16 v){ return __bfloat162float(v); }
__device__ __forceinline__ float bfu2f(ush u){
  union{unsigned int i; float f;} c; c.i = ((unsigned int)u)<<16; return c.f;
}
__device__ __forceinline__ ush f2bfu(float f){
  bf16 h = __float2bfloat16(f);
  return *(ush*)&h;
}

// ---------- dtype detector: flag=1.0 if x is bf16, 0.0 if f32
__global__ void detect_dtype(const ush* __restrict__ x, float* __restrict__ flag){
  __shared__ int bad;
  if (threadIdx.x==0) bad = 0;
  __syncthreads();
  for (int j=threadIdx.x; j<4096; j+=256){
    float f = bfu2f(x[j]);
    if (!(fabsf(f) < 1e4f)) atomicOr(&bad, 1);
  }
  __syncthreads();
  if (threadIdx.x==0) flag[0] = bad ? 0.f : 1.f;
}

// ---------- input convert
__global__ void convert_in(const void* __restrict__ src, float* __restrict__ dst, int n,
                           const float* __restrict__ flag){
  int i = blockIdx.x*256 + threadIdx.x;
  if (i >= n) return;
  float v = (flag[0] > 0.5f) ? b2f(((const bf16*)src)[i]) : ((const float*)src)[i];
  dst[i] = v;
}

// ---------- weight transpose: src f32 [Co][CiK] -> dst f32 [CiK][Co]
__global__ void transpose_w(const float* __restrict__ src, float* __restrict__ dst, int Co, int CiK){
  int tid = blockIdx.x*256 + threadIdx.x;
  if (tid >= Co*CiK) return;
  int co = tid / CiK, r = tid - co*CiK;
  dst[(long)r*Co + co] = src[tid];
}

// ---------- weight pack v2: fragment-order
__global__ void pack_w2(const float* __restrict__ src, ush* __restrict__ dst,
                        int Cout, int Cin, int kh, int nOcB){
  int idx = blockIdx.x*256 + threadIdx.x;
  int total = nOcB*36864;
  if (idx >= total) return;
  int ocb = idx / 36864; int r = idx - ocb*36864;
  int c  = r & 7;
  int lx = (r>>3) & 15;
  int n  = (r>>7) & 3;
  int lk = (r>>9) & 3;
  int j  = r>>11;
  int t = j>>1, ch = j&1;
  int oc = n*16+lx;
  int k = ch*32 + lk*8 + c;
  int ocg = ocb*64 + oc, icg = kh*64 + k;
  float v = (ocg < Cout && icg < Cin) ? src[((long)ocg*Cin + icg)*9 + t] : 0.f;
  dst[idx] = f2bfu(v);
}

// ---------- DCN weight pack
__global__ void pack_dcn_w(const float* __restrict__ src, ush* __restrict__ dst){
  int idx = blockIdx.x*256 + threadIdx.x;
  if (idx >= 49152) return;
  int g = idx / 6144; int r = idx - g*6144;
  int oc = r / 96; int k = r - oc*96;
  float v = 0.f;
  if (k < 72){
    int tap = k >> 3, c = k & 7;
    v = src[((long)oc*64 + g*8 + c)*9 + tap];
  }
  dst[idx] = f2bfu(v);
}

// ---------- conv_init
__global__ __launch_bounds__(256) void conv_init_kernel(const float* __restrict__ x,
    const float* __restrict__ wT, const float* __restrict__ bias,
    ush* __restrict__ fh, ush* __restrict__ fl){
  __shared__ ush L[256*66];
  int tid = threadIdx.x;
  int tx = tid & 15, ty = tid >> 4;
  int gx = blockIdx.x*16+tx, gy = blockIdx.y*16+ty;
  int n = blockIdx.z;
  const float* xp = x + (long)n*HW;
  float v[9];
  #pragma unroll
  for (int dy=0;dy<3;dy++)
    #pragma unroll
    for (int dx=0;dx<3;dx++){
      int yy = gy+dy-1, xx = gx+dx-1;
      bool ok = (yy>=0)&&(yy<HH)&&(xx>=0)&&(xx<WW);
      v[dy*3+dx] = ok ? xp[yy*WW+xx] : 0.f;
    }
  float acc[64];
  #pragma unroll 1
  for (int oc=0; oc<64; oc++){
    float a = bias[oc];
    #pragma unroll
    for (int k=0;k<9;k++) a = fmaf(v[k], wT[k*64+oc], a);
    acc[oc] = fmaxf(a, 0.f);
  }
  #pragma unroll 1
  for (int pass=0; pass<2; pass++){
    #pragma unroll 1
    for (int oc=0; oc<64; oc++){
      float a = acc[oc];
      ush h = f2bfu(a);
      L[tid*66+oc] = pass ? f2bfu(a - bfu2f(h)) : h;
    }
    __syncthreads();
    ush* dst = pass ? fl : fh;
    for (int j=tid; j<2048; j+=256){
      int c8 = j&7, pidx = j>>3;
      int row = pidx>>4, col = pidx&15;
      long addr = ((long)n*HW + (blockIdx.y*16+row)*WW + blockIdx.x*16+col)*64 + c8*8;
      *(short8*)(dst+addr) = *(const short8*)(L + pidx*66 + c8*8);
    }
    __syncthreads();
  }
}

// ---------- MFMA implicit-GEMM 3x3 SAME conv.
// NPL planes, MT M-tiles/wave. Optional fused second input (in2/wpack2).
// NHWC output path uses LDS-staged coalesced flush (reuses A).
template<int NPL, int MINW, int MT>
__global__ __launch_bounds__(256, MINW) void conv_mfma(
    const ush* __restrict__ in_hi, const ush* __restrict__ in_lo, long in_ps,
    const ush* __restrict__ in2_hi, const ush* __restrict__ in2_lo, long in2_ps,
    const ush* __restrict__ wpack, const ush* __restrict__ wpack2,
    const float* __restrict__ bias, int has_bias,
    const ush* __restrict__ add_hi, const ush* __restrict__ add_lo,
    long add_ps, int add_cs,
    ush* __restrict__ out_hi, ush* __restrict__ out_lo,
    long out_ps, int out_cs,
    float* __restrict__ out_pf, int pf_C,
    int Cout, int nOcB, int relu)
{
  constexpr int ROWS = 4*MT + 2;
  constexpr int APX  = ROWS*18;
  constexpr int NPX  = 4*MT*16;
  constexpr int LDSN = (NPL*APX*64 > 2*NPX*66) ? NPL*APX*64 : 2*NPX*66;
  __shared__ ush A[LDSN];
  int tid = threadIdx.x;
  int z = blockIdx.z; int img = z / nOcB; int ocb = z - img*nOcB;
  int x0 = blockIdx.x*16 - 1, y0 = blockIdx.y*(4*MT) - 1;
  int w = tid>>6, l = tid&63, lx = l&15, lk = l>>4;
  floatx4 acc[MT][4];
  #pragma unroll
  for (int mt=0;mt<MT;mt++)
    #pragma unroll
    for (int n=0;n<4;n++) acc[mt][n] = (floatx4){0.f,0.f,0.f,0.f};

  auto phase = [&](const ush* ihb, const ush* ilb, const ush* wfb){
    __syncthreads();
    #pragma unroll
    for (int p=0;p<NPL;p++){
      const ush* src = p ? ilb : ihb;
      ush* dstp = A + p*APX*64;
      for (int j=tid; j<APX*8; j+=256){
        int pidx = j>>3, c8 = j&7;
        int row = pidx/18, col = pidx - row*18;
        int yy = y0+row, xx = x0+col;
        uint4 v = make_uint4(0u,0u,0u,0u);
        if ((unsigned)yy < 128u && (unsigned)xx < 128u)
          v = *(const uint4*)(src + ((long)(yy*WW+xx))*64 + c8*8);
        *(uint4*)(dstp + pidx*64 + ((c8 ^ (pidx&7))<<3)) = v;
      }
    }
    const ush* wfrag = wfb + lk*4*128 + lx*8;
    short8 bf[4][4];
    #pragma unroll
    for (int s=0;s<3;s++)
      #pragma unroll
      for (int n=0;n<4;n++)
        bf[s][n] = *(const short8*)(wfrag + (s*16 + n)*128);
    __syncthreads();
    #pragma unroll
    for (int j=0;j<18;j++){
      int t = j>>1, ch = j&1;
      if (j<15){
        #pragma unroll
        for (int n=0;n<4;n++)
          bf[(j+3)&3][n] = *(const short8*)(wfrag + ((j+3)*16 + n)*128);
      }
      int ky = t/3, kx = t - ky*3;
      int jc = ch*4 + lk;
      #pragma unroll
      for (int mt=0; mt<MT; mt++){
        int pidx = (w*MT+mt+ky)*18 + lx + kx;
        #pragma unroll
        for (int p=0;p<NPL;p++){
          short8 af = *(const short8*)(A + p*APX*64 + pidx*64 + ((jc ^ (pidx&7))<<3));
          #pragma unroll
          for (int n=0;n<4;n++)
            acc[mt][n] = __builtin_amdgcn_mfma_f32_16x16x32_bf16(af, bf[j&3][n], acc[mt][n], 0,0,0);
        }
      }
    }
  };
  phase(in_hi + (long)img*in_ps*64, in_lo + (long)img*in_ps*64,
        wpack + (long)ocb*36864);
  if (wpack2)
    phase(in2_hi + (long)img*in2_ps*64, in2_lo + (long)img*in2_ps*64,
          wpack2 + (long)ocb*36864);

  int ybase = blockIdx.y*(4*MT) + w*MT;
  int xbase = blockIdx.x*16 + lk*4;
  if (out_pf){
    #pragma unroll
    for (int mt=0;mt<MT;mt++){
      int y = ybase + mt;
      #pragma unroll
      for (int n=0;n<4;n++){
        int ocg = ocb*64 + n*16 + lx;
        if (ocg < Cout){
          float bv = has_bias ? bias[ocg] : 0.f;
          #pragma unroll
          for (int r=0;r<4;r++){
            int xg = xbase + r;
            out_pf[((long)img*pf_C + ocg)*HW + y*WW + xg] = acc[mt][n][r] + bv;
          }
        }
      }
    }
  } else {
    // LDS-staged coalesced epilogue (Cout==64, out_cs==64, ocb==0)
    __syncthreads();
    ush* L0 = A;
    ush* L1 = A + NPX*66;
    #pragma unroll
    for (int mt=0;mt<MT;mt++){
      int y = ybase + mt;
      int rowl = w*MT + mt;
      #pragma unroll
      for (int n=0;n<4;n++){
        int ocg = n*16 + lx;
        float bv = has_bias ? bias[ocg] : 0.f;
        #pragma unroll
        for (int r=0;r<4;r++){
          int coll = lk*4 + r;
          float v = acc[mt][n][r] + bv;
          if (add_hi){
            long ap = ((long)img*add_ps + y*WW + blockIdx.x*16 + coll)*add_cs + ocg;
            v += bfu2f(add_hi[ap]) + bfu2f(add_lo[ap]);
          }
          if (relu) v = fmaxf(v, 0.f);
          ush h = f2bfu(v);
          L0[(rowl*16+coll)*66 + ocg] = h;
          if (out_lo) L1[(rowl*16+coll)*66 + ocg] = f2bfu(v - bfu2f(h));
        }
      }
    }
    __syncthreads();
    for (int j=tid; j<NPX*8; j+=256){
      int pidx = j>>3, c8 = j&7;
      int row = pidx>>4, col = pidx&15;
      long pp = (long)img*out_ps + (blockIdx.y*(4*MT)+row)*WW + blockIdx.x*16+col;
      *(short8*)(out_hi + pp*64 + c8*8) = *(const short8*)(L0 + pidx*66 + c8*8);
      if (out_lo)
        *(short8*)(out_lo + pp*64 + c8*8) = *(const short8*)(L1 + pidx*66 + c8*8);
    }
  }
}

// ---------- repack NHWC hi/lo -> group-planar f32 [4][8][HW][8]
__global__ __launch_bounds__(256) void repack_gp(const ush* __restrict__ in_h,
    const ush* __restrict__ in_l, long in_ps, float* __restrict__ gp){
  long idx = (long)blockIdx.x*256 + threadIdx.x;
  int img = (int)(idx >> 17);
  int rem = (int)(idx & 131071);
  int pix = rem >> 3, c8 = rem & 7;
  long src = ((long)img*in_ps + pix)*64 + c8*8;
  short8 h = *(const short8*)(in_h+src);
  short8 lo = *(const short8*)(in_l+src);
  float* d = gp + (((long)(img*8+c8))*HW + pix)*8;
  #pragma unroll
  for (int c=0;c<8;c++) d[c] = bfu2f((ush)h[c]) + bfu2f((ush)lo[c]);
}

// ---------- MFMA modulated deformable conv; single-plane A, staged epilogue
__global__ __launch_bounds__(256) void dcn_mfma(
    const float* __restrict__ gp,
    const float* __restrict__ om,
    const ush* __restrict__ wpk,
    const float* __restrict__ bias,
    ush* __restrict__ out_hi, ush* __restrict__ out_lo)
{
  __shared__ ush S[19968];           // Ah [128*104] + Bt [64*104]
  ush* Ah = S;
  ush* Bt = S + 13312;
  int tid = threadIdx.x;
  int gy = blockIdx.x, img = blockIdx.y;
  {
    short8 z = {0,0,0,0,0,0,0,0};
    for (int j=tid; j<384; j+=256){
      int px = j/3, c = j - px*3;
      *(short8*)(Ah + px*104 + 72 + c*8) = z;
    }
  }
  int w = tid>>6, l = tid&63, lx = l&15, lk = l>>4;
  int px_s = tid & 127, hf = tid >> 7;
  const float* omb = om + (long)img*216*HW + gy*WW + px_s;
  floatx4 acc[2][4];
  #pragma unroll
  for (int mt=0;mt<2;mt++)
    #pragma unroll
    for (int n=0;n<4;n++) acc[mt][n] = (floatx4){0.f,0.f,0.f,0.f};

  #pragma unroll 1
  for (int g=0; g<8; g++){
    __syncthreads();
    const ush* wsrc = wpk + g*6144;
    for (int j=tid; j<768; j+=256){
      int oc = j/12, kc = j - oc*12;
      *(short8*)(Bt + oc*104 + kc*8) = *(const short8*)(wsrc + oc*96 + kc*8);
    }
    const float* gpb = gp + ((long)(img*8+g))*HW*8;
    int t0 = hf ? 5 : 0, t1 = hf ? 9 : 5;
    #pragma unroll 1
    for (int t=t0; t<t1; t++){
      int ch = g*9+t;
      float dy = omb[(long)ch*HW];
      float dx = omb[(long)(72+ch)*HW];
      float mv = omb[(long)(144+ch)*HW];
      float m = 1.f/(1.f+__expf(-mv));
      float py = (float)gy + (float)(t/3 - 1) + dy;
      float pxf = (float)px_s + (float)(t%3 - 1) + dx;
      float fy = floorf(py), fx = floorf(pxf);
      int y0 = (int)fy, x0 = (int)fx;
      float wy = py - fy, wx = pxf - fx;
      bool y0v = (y0>=0 && y0<HH), y1v = (y0+1>=0 && y0+1<HH);
      bool x0v = (x0>=0 && x0<WW), x1v = (x0+1>=0 && x0+1<WW);
      float w00 = (1.f-wy)*(1.f-wx)*m * ((y0v&&x0v)?1.f:0.f);
      float w01 = (1.f-wy)*wx*m      * ((y0v&&x1v)?1.f:0.f);
      float w10 = wy*(1.f-wx)*m      * ((y1v&&x0v)?1.f:0.f);
      float w11 = wy*wx*m            * ((y1v&&x1v)?1.f:0.f);
      int y0c = min(max(y0,0),HH-1), y1c = min(max(y0+1,0),HH-1);
      int x0c = min(max(x0,0),WW-1), x1c = min(max(x0+1,0),WW-1);
      const float* p00 = gpb + (((long)(y0c*WW+x0c))<<3);
      const float* p01 = gpb + (((long)(y0c*WW+x1c))<<3);
      const float* p10 = gpb + (((long)(y1c*WW+x0c))<<3);
      const float* p11 = gpb + (((long)(y1c*WW+x1c))<<3);
      float4 a00=*(const float4*)p00, b00=*(const float4*)(p00+4);
      float4 a01=*(const float4*)p01, b01=*(const float4*)(p01+4);
      float4 a10=*(const float4*)p10, b10=*(const float4*)(p10+4);
      float4 a11=*(const float4*)p11, b11=*(const float4*)(p11+4);
      float val[8];
      val[0]=w00*a00.x+w01*a01.x+w10*a10.x+w11*a11.x;
      val[1]=w00*a00.y+w01*a01.y+w10*a10.y+w11*a11.y;
      val[2]=w00*a00.z+w01*a01.z+w10*a10.z+w11*a11.z;
      val[3]=w00*a00.w+w01*a01.w+w10*a10.w+w11*a11.w;
      val[4]=w00*b00.x+w01*b01.x+w10*b10.x+w11*b11.x;
      val[5]=w00*b00.y+w01*b01.y+w10*b10.y+w11*b11.y;
      val[6]=w00*b00.z+w01*b01.z+w10*b10.z+w11*b11.z;
      val[7]=w00*b00.w+w01*b01.w+w10*b10.w+w11*b11.w;
      short8 vh;
      #pragma unroll
      for (int c=0;c<8;c++) vh[c] = (short)f2bfu(val[c]);
      *(short8*)(Ah + px_s*104 + t*8) = vh;
    }
    __syncthreads();
    #pragma unroll
    for (int ks=0; ks<3; ks++){
      short8 bfg[4];
      #pragma unroll
      for (int n=0;n<4;n++)
        bfg[n] = *(const short8*)(Bt + (n*16+lx)*104 + ks*32 + lk*8);
      #pragma unroll
      for (int mt=0; mt<2; mt++){
        int px = (w*2+mt)*16 + lx;
        short8 ah = *(const short8*)(Ah + px*104 + ks*32 + lk*8);
        #pragma unroll
        for (int n=0;n<4;n++)
          acc[mt][n] = __builtin_amdgcn_mfma_f32_16x16x32_bf16(ah, bfg[n], acc[mt][n], 0,0,0);
      }
    }
  }
  __syncthreads();
  ush* L0 = S;
  ush* L1 = S + 128*66;
  #pragma unroll
  for (int mt=0;mt<2;mt++){
    #pragma unroll
    for (int n=0;n<4;n++){
      int oc = n*16 + lx;
      float bv = bias[oc];
      #pragma unroll
      for (int r=0;r<4;r++){
        int pxl = (w*2+mt)*16 + lk*4 + r;
        float v = acc[mt][n][r] + bv;
        ush h = f2bfu(v);
        L0[pxl*66 + oc] = h;
        L1[pxl*66 + oc] = f2bfu(v - bfu2f(h));
      }
    }
  }
  __syncthreads();
  long base = ((long)img*HW + gy*WW)*64;
  for (int j=tid; j<1024; j+=256){
    int pidx = j>>3, c8 = j&7;
    *(short8*)(out_hi + base + pidx*64 + c8*8) = *(const short8*)(L0 + pidx*66 + c8*8);
    *(short8*)(out_lo + base + pidx*64 + c8*8) = *(const short8*)(L1 + pidx*66 + c8*8);
  }
}

// ---------- reconstruction conv: channel-split + LDS reduce
__global__ __launch_bounds__(256) void rec_kernel(
    const ush* __restrict__ fh, const ush* __restrict__ fl,
    const float* __restrict__ wT, const float* __restrict__ bias,
    void* __restrict__ out, int ni, const float* __restrict__ flag){
  __shared__ float red[256];
  int tid = threadIdx.x;
  int p = tid & 31, q = tid >> 5;
  int gx = blockIdx.x*32 + p;
  int gy = blockIdx.y;
  int b = blockIdx.z;
  float acc = 0.f;
  #pragma unroll
  for (int t=0;t<9;t++){
    int yy = gy + t/3 - 1, xx = gx + t%3 - 1;
    if (yy<0||yy>=HH||xx<0||xx>=WW) continue;
    long base = ((long)b*HW + yy*WW + xx)*64 + q*8;
    short8 h = *(const short8*)(fh + base);
    short8 lo = *(const short8*)(fl + base);
    #pragma unroll
    for (int cc=0;cc<8;cc++){
      float v = bfu2f((ush)h[cc]) + bfu2f((ush)lo[cc]);
      acc = fmaf(v, wT[(q*8+cc)*9 + t], acc);
    }
  }
  red[q*32+p] = acc;
  __syncthreads();
  if (tid < 32){
    float s = bias[0];
    #pragma unroll
    for (int k=0;k<8;k++) s += red[k*32+tid];
    long idx = ((long)b*5+ni)*HW + gy*WW + blockIdx.x*32 + tid;
    if (flag[0] > 0.5f) ((bf16*)out)[idx] = __float2bfloat16(s);
    else                ((float*)out)[idx] = s;
  }
}

extern "C" void kernel_launch(void* const* d_in, const int* in_sizes, int n_in,
                              void* d_out, int out_size, void* d_ws, size_t ws_size,
                              hipStream_t stream) {
  float* ws = (float*)d_ws;

  size_t off = 16;
  auto alloc = [&](size_t nel){ size_t o = off; off += (nel + 7) & ~(size_t)7; return o; };

  static const int IN_N[17] = {327680, 576, 64, 184320, 320, 184320, 320,
                               73728, 64, 147456, 256, 497664, 864, 147456,
                               256, 576, 1};
  size_t cin[17];
  for (int i=0;i<17;i++) cin[i] = alloc(IN_N[i]);

  size_t wt_init = alloc(640);
  size_t wdcn_pk[4]; for (int s=0;s<4;s++) wdcn_pk[s] = alloc(24576);
  size_t wt_rec = alloc(640);
  size_t pk_res1[5], pk_res2[5];
  for (int i=0;i<5;i++) pk_res1[i] = alloc(18432);
  for (int i=0;i<5;i++) pk_res2[i] = alloc(18432);
  size_t pk_bn[2]; for (int h=0;h<2;h++) pk_bn[h] = alloc(18432);
  size_t pk_off[4]; for (int s=0;s<4;s++) pk_off[s] = alloc(18432);
  size_t pk_com[4]; for (int s=0;s<4;s++) pk_com[s] = alloc(73728);

  size_t feat_h_o = alloc(10485760);
  size_t feat_l_o = alloc(10485760);
  size_t U = alloc(26738688);

  ush* feat_h = (ush*)(ws + feat_h_o);
  ush* feat_l = (ush*)(ws + feat_l_o);
  ush* feaA_h = (ush*)(ws + U);
  ush* feaA_l = (ush*)(ws + U + 2097152);
  ush* feaB_h = (ush*)(ws + U + 4194304);
  ush* feaB_l = (ush*)(ws + U + 6291456);
  ush* obuf_h = (ush*)(ws + U + 8388608);
  float* gpbuf = ws + U + 8388608;       // f32 gp aliases obuf (dead when gp live)
  float* ombuf = ws + U + 12582912;
  ush* hbuf_h = (ush*)(ws + U);          // res-phase alias (dead in neighbor loop)

  float* flag = ws;

  detect_dtype<<<dim3(1), dim3(256), 0, stream>>>((const ush*)d_in[0], flag);
  for (int i=0;i<17;i++){
    int n = IN_N[i];
    convert_in<<<dim3((n+255)/256), dim3(256), 0, stream>>>(d_in[i], ws+cin[i], n, flag);
  }
  const float* b_init = ws+cin[2];
  const float* res_b1 = ws+cin[4];
  const float* res_b2 = ws+cin[6];
  const float* b_bn   = ws+cin[8];
  const float* off_b  = ws+cin[10];
  const float* com_b  = ws+cin[12];
  const float* dcn_b  = ws+cin[14];
  const float* b_rec  = ws+cin[16];

  auto tr = [&](size_t src_o, size_t dst_o, int Co, int CiK){
    int total = Co*CiK;
    transpose_w<<<dim3((total+255)/256), dim3(256), 0, stream>>>(ws+src_o, ws+dst_o, Co, CiK);
  };
  tr(cin[1], wt_init, 64, 9);
  tr(cin[15], wt_rec, 1, 576);
  for (int s=0;s<4;s++)
    pack_dcn_w<<<dim3(192), dim3(256), 0, stream>>>(ws+cin[13]+(size_t)s*36864,
                                                    (ush*)(ws+wdcn_pk[s]));

  auto pack = [&](size_t src_o, size_t dst_o, int Cout, int Cin, int kh, int nOcB){
    int total = nOcB*36864;
    pack_w2<<<dim3((total+255)/256), dim3(256), 0, stream>>>(
        ws+src_o, (ush*)(ws+dst_o), Cout, Cin, kh, nOcB);
  };
  for (int i=0;i<5;i++) pack(cin[3]+(size_t)i*36864, pk_res1[i], 64, 64, 0, 1);
  for (int i=0;i<5;i++) pack(cin[5]+(size_t)i*36864, pk_res2[i], 64, 64, 0, 1);
  for (int h=0;h<2;h++) pack(cin[7], pk_bn[h], 64, 128, h, 1);
  for (int s=0;s<4;s++) pack(cin[9]+(size_t)s*36864,  pk_off[s], 64, 64, 0, 1);
  for (int s=0;s<4;s++) pack(cin[11]+(size_t)s*124416, pk_com[s], 216, 64, 0, 4);

  dim3 cblk(256);
  auto conv = [&](const ush* in_h, const ush* in_l, long in_ps,
                  const ush* in2_h, const ush* in2_l, long in2_ps,
                  size_t pk, const ush* pk2p,
                  const float* bias, int has_bias,
                  const ush* add_h, const ush* add_l, long add_ps, int add_cs,
                  ush* o_h, ush* o_l, long out_ps, int out_cs,
                  float* o_pf, int pf_C,
                  int Cout, int nOcB, int relu, int N, int nPl, int mtMode){
    if (nPl == 2 && mtMode == 2)
      conv_mfma<2,2,2><<<dim3(8,16,N*nOcB), cblk, 0, stream>>>(
          in_h, in_l, in_ps, in2_h, in2_l, in2_ps,
          (const ush*)(ws+pk), pk2p, bias, has_bias,
          add_h, add_l, add_ps, add_cs, o_h, o_l, out_ps, out_cs,
          o_pf, pf_C, Cout, nOcB, relu);
    else if (nPl == 2 && mtMode == 1)
      conv_mfma<2,2,1><<<dim3(8,32,N*nOcB), cblk, 0, stream>>>(
          in_h, in_l, in_ps, in2_h, in2_l, in2_ps,
          (const ush*)(ws+pk), pk2p, bias, has_bias,
          add_h, add_l, add_ps, add_cs, o_h, o_l, out_ps, out_cs,
          o_pf, pf_C, Cout, nOcB, relu);
    else
      conv_mfma<1,3,2><<<dim3(8,16,N*nOcB), cblk, 0, stream>>>(
          in_h, in_l, in_ps, in2_h, in2_l, in2_ps,
          (const ush*)(ws+pk), pk2p, bias, has_bias,
          add_h, add_l, add_ps, add_cs, o_h, o_l, out_ps, out_cs,
          o_pf, pf_C, Cout, nOcB, relu);
  };

  // ---- feature extraction
  conv_init_kernel<<<dim3(8,8,20), cblk, 0, stream>>>(ws+cin[0], ws+wt_init, b_init,
                                                      feat_h, feat_l);
  for (int i=0;i<5;i++){
    // res1: h = relu(conv(feat)) -> hi-only intermediate (short-lived; error
    // enters trunk only via the residual delta)
    conv(feat_h, feat_l, HW, nullptr, nullptr, 0, pk_res1[i], nullptr,
         res_b1+(size_t)i*64, 1,
         nullptr, nullptr, 0, 0, hbuf_h, nullptr, HW, 64, nullptr, 0, 64, 1, 1, 20, 2, 2);
    // res2: feat += conv(h), single-plane input (NPL=1)
    conv(hbuf_h, hbuf_h, HW, nullptr, nullptr, 0, pk_res2[i], nullptr,
         res_b2+(size_t)i*64, 1,
         feat_h, feat_l, HW, 64, feat_h, feat_l, HW, 64, nullptr, 0, 64, 1, 0, 20, 1, 2);
  }
  // ---- per-neighbor alignment
  for (int i=0;i<5;i++){
    conv(feat_h + (size_t)2*HW*64, feat_l + (size_t)2*HW*64, 5L*HW,
         feat_h + (size_t)i*HW*64, feat_l + (size_t)i*HW*64, 5L*HW,
         pk_bn[0], (const ush*)(ws+pk_bn[1]), b_bn, 1,
         nullptr, nullptr, 0, 0, feaA_h, feaA_l, HW, 64, nullptr, 0, 64, 1, 0, 4, 2, 1);
    ush *fa_h = feaA_h, *fa_l = feaA_l, *fb_h = feaB_h, *fb_l = feaB_l;
    for (int s=0;s<4;s++){
      conv(fa_h, fa_l, HW, nullptr, nullptr, 0, pk_off[s], nullptr,
           off_b+(size_t)s*64, 1,
           nullptr, nullptr, 0, 0, obuf_h, nullptr, HW, 64, nullptr, 0, 64, 1, 0, 4, 2, 1);
      conv(obuf_h, obuf_h, HW, nullptr, nullptr, 0, pk_com[s], nullptr,
           com_b+(size_t)s*216, 1,
           nullptr, nullptr, 0, 0, nullptr, nullptr, 0, 0, ombuf, 216, 216, 4, 0, 4, 1, 2);
      const ush *xs_h, *xs_l; long xps;
      if (s == 2){ xs_h = feat_h + (size_t)i*HW*64; xs_l = feat_l + (size_t)i*HW*64; xps = 5L*HW; }
      else       { xs_h = fa_h;                     xs_l = fa_l;                     xps = HW; }
      repack_gp<<<dim3(2048), cblk, 0, stream>>>(xs_h, xs_l, xps, gpbuf);
      dcn_mfma<<<dim3(128,4), cblk, 0, stream>>>(gpbuf, ombuf,
          (const ush*)(ws+wdcn_pk[s]), dcn_b+(size_t)s*64, fb_h, fb_l);
      ush* t;
      t = fa_h; fa_h = fb_h; fb_h = t;
      t = fa_l; fa_l = fb_l; fb_l = t;
    }
    rec_kernel<<<dim3(4,128,4), cblk, 0, stream>>>(fa_h, fa_l, ws+wt_rec, b_rec, d_out, i, flag);
  }
}

// Round 14
// 3435.696 us; speedup vs baseline: 2.3656x; 1.0471x over previous
//
#include <hip/hip_runtime.h>
#include <hip/hip_bf16.h>

typedef __hip_bfloat16 bf16;
typedef __attribute__((ext_vector_type(8))) short short8;
typedef __attribute__((ext_vector_type(4))) float floatx4;
typedef unsigned short ush;

#define HH 128
#define WW 128
#define HW 16384

__device__ __forceinline__ float b2f(bf16 v){ return __bfloat162float(v); }
__device__ __forceinline__ float bfu2f(ush u){
  union{unsigned int i; float f;} c; c.i = ((unsigned int)u)<<16; return c.f;
}
__device__ __forceinline__ ush f2bfu(float f){
  bf16 h = __float2bfloat16(f);
  return *(ush*)&h;
}

// ---------- dtype detector: flag=1.0 if x is bf16, 0.0 if f32
__global__ void detect_dtype(const ush* __restrict__ x, float* __restrict__ flag){
  __shared__ int bad;
  if (threadIdx.x==0) bad = 0;
  __syncthreads();
  for (int j=threadIdx.x; j<4096; j+=256){
    float f = bfu2f(x[j]);
    if (!(fabsf(f) < 1e4f)) atomicOr(&bad, 1);
  }
  __syncthreads();
  if (threadIdx.x==0) flag[0] = bad ? 0.f : 1.f;
}

// ---------- input convert
__global__ void convert_in(const void* __restrict__ src, float* __restrict__ dst, int n,
                           const float* __restrict__ flag){
  int i = blockIdx.x*256 + threadIdx.x;
  if (i >= n) return;
  float v = (flag[0] > 0.5f) ? b2f(((const bf16*)src)[i]) : ((const float*)src)[i];
  dst[i] = v;
}

// ---------- weight transpose: src f32 [Co][CiK] -> dst f32 [CiK][Co]
__global__ void transpose_w(const float* __restrict__ src, float* __restrict__ dst, int Co, int CiK){
  int tid = blockIdx.x*256 + threadIdx.x;
  if (tid >= Co*CiK) return;
  int co = tid / CiK, r = tid - co*CiK;
  dst[(long)r*Co + co] = src[tid];
}

// ---------- weight pack v2: fragment-order
__global__ void pack_w2(const float* __restrict__ src, ush* __restrict__ dst,
                        int Cout, int Cin, int kh, int nOcB){
  int idx = blockIdx.x*256 + threadIdx.x;
  int total = nOcB*36864;
  if (idx >= total) return;
  int ocb = idx / 36864; int r = idx - ocb*36864;
  int c  = r & 7;
  int lx = (r>>3) & 15;
  int n  = (r>>7) & 3;
  int lk = (r>>9) & 3;
  int j  = r>>11;
  int t = j>>1, ch = j&1;
  int oc = n*16+lx;
  int k = ch*32 + lk*8 + c;
  int ocg = ocb*64 + oc, icg = kh*64 + k;
  float v = (ocg < Cout && icg < Cin) ? src[((long)ocg*Cin + icg)*9 + t] : 0.f;
  dst[idx] = f2bfu(v);
}

// ---------- DCN weight pack
__global__ void pack_dcn_w(const float* __restrict__ src, ush* __restrict__ dst){
  int idx = blockIdx.x*256 + threadIdx.x;
  if (idx >= 49152) return;
  int g = idx / 6144; int r = idx - g*6144;
  int oc = r / 96; int k = r - oc*96;
  float v = 0.f;
  if (k < 72){
    int tap = k >> 3, c = k & 7;
    v = src[((long)oc*64 + g*8 + c)*9 + tap];
  }
  dst[idx] = f2bfu(v);
}

// ---------- conv_init
__global__ __launch_bounds__(256) void conv_init_kernel(const float* __restrict__ x,
    const float* __restrict__ wT, const float* __restrict__ bias,
    ush* __restrict__ fh, ush* __restrict__ fl){
  __shared__ ush L[256*66];
  int tid = threadIdx.x;
  int tx = tid & 15, ty = tid >> 4;
  int gx = blockIdx.x*16+tx, gy = blockIdx.y*16+ty;
  int n = blockIdx.z;
  const float* xp = x + (long)n*HW;
  float v[9];
  #pragma unroll
  for (int dy=0;dy<3;dy++)
    #pragma unroll
    for (int dx=0;dx<3;dx++){
      int yy = gy+dy-1, xx = gx+dx-1;
      bool ok = (yy>=0)&&(yy<HH)&&(xx>=0)&&(xx<WW);
      v[dy*3+dx] = ok ? xp[yy*WW+xx] : 0.f;
    }
  float acc[64];
  #pragma unroll 1
  for (int oc=0; oc<64; oc++){
    float a = bias[oc];
    #pragma unroll
    for (int k=0;k<9;k++) a = fmaf(v[k], wT[k*64+oc], a);
    acc[oc] = fmaxf(a, 0.f);
  }
  #pragma unroll 1
  for (int pass=0; pass<2; pass++){
    #pragma unroll 1
    for (int oc=0; oc<64; oc++){
      float a = acc[oc];
      ush h = f2bfu(a);
      L[tid*66+oc] = pass ? f2bfu(a - bfu2f(h)) : h;
    }
    __syncthreads();
    ush* dst = pass ? fl : fh;
    for (int j=tid; j<2048; j+=256){
      int c8 = j&7, pidx = j>>3;
      int row = pidx>>4, col = pidx&15;
      long addr = ((long)n*HW + (blockIdx.y*16+row)*WW + blockIdx.x*16+col)*64 + c8*8;
      *(short8*)(dst+addr) = *(const short8*)(L + pidx*66 + c8*8);
    }
    __syncthreads();
  }
}

// ---------- MFMA implicit-GEMM 3x3 SAME conv.
template<int NPL, int MINW, int MT>
__global__ __launch_bounds__(256, MINW) void conv_mfma(
    const ush* __restrict__ in_hi, const ush* __restrict__ in_lo, long in_ps,
    const ush* __restrict__ in2_hi, const ush* __restrict__ in2_lo, long in2_ps,
    const ush* __restrict__ wpack, const ush* __restrict__ wpack2,
    const float* __restrict__ bias, int has_bias,
    const ush* __restrict__ add_hi, const ush* __restrict__ add_lo,
    long add_ps, int add_cs,
    ush* __restrict__ out_hi, ush* __restrict__ out_lo,
    long out_ps, int out_cs,
    float* __restrict__ out_pf, int pf_C,
    int Cout, int nOcB, int relu)
{
  constexpr int ROWS = 4*MT + 2;
  constexpr int APX  = ROWS*18;
  constexpr int NPX  = 4*MT*16;
  constexpr int LDSN = (NPL*APX*64 > 2*NPX*66) ? NPL*APX*64 : 2*NPX*66;
  __shared__ ush A[LDSN];
  int tid = threadIdx.x;
  int z = blockIdx.z; int img = z / nOcB; int ocb = z - img*nOcB;
  int x0 = blockIdx.x*16 - 1, y0 = blockIdx.y*(4*MT) - 1;
  int w = tid>>6, l = tid&63, lx = l&15, lk = l>>4;
  floatx4 acc[MT][4];
  #pragma unroll
  for (int mt=0;mt<MT;mt++)
    #pragma unroll
    for (int n=0;n<4;n++) acc[mt][n] = (floatx4){0.f,0.f,0.f,0.f};

  auto phase = [&](const ush* ihb, const ush* ilb, const ush* wfb){
    __syncthreads();
    #pragma unroll
    for (int p=0;p<NPL;p++){
      const ush* src = p ? ilb : ihb;
      ush* dstp = A + p*APX*64;
      for (int j=tid; j<APX*8; j+=256){
        int pidx = j>>3, c8 = j&7;
        int row = pidx/18, col = pidx - row*18;
        int yy = y0+row, xx = x0+col;
        uint4 v = make_uint4(0u,0u,0u,0u);
        if ((unsigned)yy < 128u && (unsigned)xx < 128u)
          v = *(const uint4*)(src + ((long)(yy*WW+xx))*64 + c8*8);
        *(uint4*)(dstp + pidx*64 + ((c8 ^ (pidx&7))<<3)) = v;
      }
    }
    const ush* wfrag = wfb + lk*4*128 + lx*8;
    short8 bf[4][4];
    #pragma unroll
    for (int s=0;s<3;s++)
      #pragma unroll
      for (int n=0;n<4;n++)
        bf[s][n] = *(const short8*)(wfrag + (s*16 + n)*128);
    __syncthreads();
    #pragma unroll
    for (int j=0;j<18;j++){
      int t = j>>1, ch = j&1;
      if (j<15){
        #pragma unroll
        for (int n=0;n<4;n++)
          bf[(j+3)&3][n] = *(const short8*)(wfrag + ((j+3)*16 + n)*128);
      }
      int ky = t/3, kx = t - ky*3;
      int jc = ch*4 + lk;
      #pragma unroll
      for (int mt=0; mt<MT; mt++){
        int pidx = (w*MT+mt+ky)*18 + lx + kx;
        #pragma unroll
        for (int p=0;p<NPL;p++){
          short8 af = *(const short8*)(A + p*APX*64 + pidx*64 + ((jc ^ (pidx&7))<<3));
          #pragma unroll
          for (int n=0;n<4;n++)
            acc[mt][n] = __builtin_amdgcn_mfma_f32_16x16x32_bf16(af, bf[j&3][n], acc[mt][n], 0,0,0);
        }
      }
    }
  };
  phase(in_hi + (long)img*in_ps*64, in_lo + (long)img*in_ps*64,
        wpack + (long)ocb*36864);
  if (wpack2)
    phase(in2_hi + (long)img*in2_ps*64, in2_lo + (long)img*in2_ps*64,
          wpack2 + (long)ocb*36864);

  int ybase = blockIdx.y*(4*MT) + w*MT;
  int xbase = blockIdx.x*16 + lk*4;
  if (out_pf){
    #pragma unroll
    for (int mt=0;mt<MT;mt++){
      int y = ybase + mt;
      #pragma unroll
      for (int n=0;n<4;n++){
        int ocg = ocb*64 + n*16 + lx;
        if (ocg < Cout){
          float bv = has_bias ? bias[ocg] : 0.f;
          #pragma unroll
          for (int r=0;r<4;r++){
            int xg = xbase + r;
            out_pf[((long)img*pf_C + ocg)*HW + y*WW + xg] = acc[mt][n][r] + bv;
          }
        }
      }
    }
  } else {
    __syncthreads();
    ush* L0 = A;
    ush* L1 = A + NPX*66;
    #pragma unroll
    for (int mt=0;mt<MT;mt++){
      int y = ybase + mt;
      int rowl = w*MT + mt;
      #pragma unroll
      for (int n=0;n<4;n++){
        int ocg = n*16 + lx;
        float bv = has_bias ? bias[ocg] : 0.f;
        #pragma unroll
        for (int r=0;r<4;r++){
          int coll = lk*4 + r;
          float v = acc[mt][n][r] + bv;
          if (add_hi){
            long ap = ((long)img*add_ps + y*WW + blockIdx.x*16 + coll)*add_cs + ocg;
            v += bfu2f(add_hi[ap]) + bfu2f(add_lo[ap]);
          }
          if (relu) v = fmaxf(v, 0.f);
          ush h = f2bfu(v);
          L0[(rowl*16+coll)*66 + ocg] = h;
          if (out_lo) L1[(rowl*16+coll)*66 + ocg] = f2bfu(v - bfu2f(h));
        }
      }
    }
    __syncthreads();
    for (int j=tid; j<NPX*8; j+=256){
      int pidx = j>>3, c8 = j&7;
      int row = pidx>>4, col = pidx&15;
      long pp = (long)img*out_ps + (blockIdx.y*(4*MT)+row)*WW + blockIdx.x*16+col;
      *(short8*)(out_hi + pp*64 + c8*8) = *(const short8*)(L0 + pidx*66 + c8*8);
      if (out_lo)
        *(short8*)(out_lo + pp*64 + c8*8) = *(const short8*)(L1 + pidx*66 + c8*8);
    }
  }
}

// ---------- repack NHWC hi/lo -> group-planar f32 [4][8][HW][8]
__global__ __launch_bounds__(256) void repack_gp(const ush* __restrict__ in_h,
    const ush* __restrict__ in_l, long in_ps, float* __restrict__ gp){
  long idx = (long)blockIdx.x*256 + threadIdx.x;
  int img = (int)(idx >> 17);
  int rem = (int)(idx & 131071);
  int pix = rem >> 3, c8 = rem & 7;
  long src = ((long)img*in_ps + pix)*64 + c8*8;
  short8 h = *(const short8*)(in_h+src);
  short8 lo = *(const short8*)(in_l+src);
  float* d = gp + (((long)(img*8+c8))*HW + pix)*8;
  #pragma unroll
  for (int c=0;c<8;c++) d[c] = bfu2f((ush)h[c]) + bfu2f((ush)lo[c]);
}

// ---------- MFMA modulated deformable conv; half-row blocks (64 px), 4-way tap split
__global__ __launch_bounds__(256) void dcn_mfma(
    const float* __restrict__ gp,
    const float* __restrict__ om,
    const ush* __restrict__ wpk,
    const float* __restrict__ bias,
    ush* __restrict__ out_hi, ush* __restrict__ out_lo)
{
  __shared__ ush S[13312];           // Ah [64*104] + Bt [64*104]
  ush* Ah = S;
  ush* Bt = S + 6656;
  int tid = threadIdx.x;
  int half = blockIdx.x, gy = blockIdx.y, img = blockIdx.z;
  int xoff = half*64;
  {
    short8 z = {0,0,0,0,0,0,0,0};
    for (int j=tid; j<192; j+=256){
      int px = j/3, c = j - px*3;
      *(short8*)(Ah + px*104 + 72 + c*8) = z;
    }
  }
  int w = tid>>6, l = tid&63, lx = l&15, lk = l>>4;
  int px_s = tid & 63, q = tid >> 6;
  int t0 = (q==0)?0:(q*2+1), t1 = t0 + ((q==0)?3:2);
  const float* omb = om + (long)img*216*HW + gy*WW + xoff + px_s;
  floatx4 acc[4];
  #pragma unroll
  for (int n=0;n<4;n++) acc[n] = (floatx4){0.f,0.f,0.f,0.f};

  #pragma unroll 1
  for (int g=0; g<8; g++){
    __syncthreads();
    const ush* wsrc = wpk + g*6144;
    for (int j=tid; j<768; j+=256){
      int oc = j/12, kc = j - oc*12;
      *(short8*)(Bt + oc*104 + kc*8) = *(const short8*)(wsrc + oc*96 + kc*8);
    }
    const float* gpb = gp + ((long)(img*8+g))*HW*8;
    #pragma unroll 1
    for (int t=t0; t<t1; t++){
      int ch = g*9+t;
      float dy = omb[(long)ch*HW];
      float dx = omb[(long)(72+ch)*HW];
      float mv = omb[(long)(144+ch)*HW];
      float m = 1.f/(1.f+__expf(-mv));
      float py = (float)gy + (float)(t/3 - 1) + dy;
      float pxf = (float)(xoff + px_s) + (float)(t%3 - 1) + dx;
      float fy = floorf(py), fx = floorf(pxf);
      int y0 = (int)fy, x0 = (int)fx;
      float wy = py - fy, wx = pxf - fx;
      bool y0v = (y0>=0 && y0<HH), y1v = (y0+1>=0 && y0+1<HH);
      bool x0v = (x0>=0 && x0<WW), x1v = (x0+1>=0 && x0+1<WW);
      float w00 = (1.f-wy)*(1.f-wx)*m * ((y0v&&x0v)?1.f:0.f);
      float w01 = (1.f-wy)*wx*m      * ((y0v&&x1v)?1.f:0.f);
      float w10 = wy*(1.f-wx)*m      * ((y1v&&x0v)?1.f:0.f);
      float w11 = wy*wx*m            * ((y1v&&x1v)?1.f:0.f);
      int y0c = min(max(y0,0),HH-1), y1c = min(max(y0+1,0),HH-1);
      int x0c = min(max(x0,0),WW-1), x1c = min(max(x0+1,0),WW-1);
      const float* p00 = gpb + (((long)(y0c*WW+x0c))<<3);
      const float* p01 = gpb + (((long)(y0c*WW+x1c))<<3);
      const float* p10 = gpb + (((long)(y1c*WW+x0c))<<3);
      const float* p11 = gpb + (((long)(y1c*WW+x1c))<<3);
      float4 a00=*(const float4*)p00, b00=*(const float4*)(p00+4);
      float4 a01=*(const float4*)p01, b01=*(const float4*)(p01+4);
      float4 a10=*(const float4*)p10, b10=*(const float4*)(p10+4);
      float4 a11=*(const float4*)p11, b11=*(const float4*)(p11+4);
      float val[8];
      val[0]=w00*a00.x+w01*a01.x+w10*a10.x+w11*a11.x;
      val[1]=w00*a00.y+w01*a01.y+w10*a10.y+w11*a11.y;
      val[2]=w00*a00.z+w01*a01.z+w10*a10.z+w11*a11.z;
      val[3]=w00*a00.w+w01*a01.w+w10*a10.w+w11*a11.w;
      val[4]=w00*b00.x+w01*b01.x+w10*b10.x+w11*b11.x;
      val[5]=w00*b00.y+w01*b01.y+w10*b10.y+w11*b11.y;
      val[6]=w00*b00.z+w01*b01.z+w10*b10.z+w11*b11.z;
      val[7]=w00*b00.w+w01*b01.w+w10*b10.w+w11*b11.w;
      short8 vh;
      #pragma unroll
      for (int c=0;c<8;c++) vh[c] = (short)f2bfu(val[c]);
      *(short8*)(Ah + px_s*104 + t*8) = vh;
    }
    __syncthreads();
    #pragma unroll
    for (int ks=0; ks<3; ks++){
      short8 bfg[4];
      #pragma unroll
      for (int n=0;n<4;n++)
        bfg[n] = *(const short8*)(Bt + (n*16+lx)*104 + ks*32 + lk*8);
      int px = w*16 + lx;
      short8 ah = *(const short8*)(Ah + px*104 + ks*32 + lk*8);
      #pragma unroll
      for (int n=0;n<4;n++)
        acc[n] = __builtin_amdgcn_mfma_f32_16x16x32_bf16(ah, bfg[n], acc[n], 0,0,0);
    }
  }
  __syncthreads();
  ush* L0 = S;
  ush* L1 = S + 64*66;
  #pragma unroll
  for (int n=0;n<4;n++){
    int oc = n*16 + lx;
    float bv = bias[oc];
    #pragma unroll
    for (int r=0;r<4;r++){
      int pxl = w*16 + lk*4 + r;
      float v = acc[n][r] + bv;
      ush h = f2bfu(v);
      L0[pxl*66 + oc] = h;
      L1[pxl*66 + oc] = f2bfu(v - bfu2f(h));
    }
  }
  __syncthreads();
  long base = ((long)img*HW + gy*WW + xoff)*64;
  for (int j=tid; j<512; j+=256){
    int pidx = j>>3, c8 = j&7;
    *(short8*)(out_hi + base + pidx*64 + c8*8) = *(const short8*)(L0 + pidx*66 + c8*8);
    *(short8*)(out_lo + base + pidx*64 + c8*8) = *(const short8*)(L1 + pidx*66 + c8*8);
  }
}

// ---------- reconstruction conv: channel-split + LDS reduce
__global__ __launch_bounds__(256) void rec_kernel(
    const ush* __restrict__ fh, const ush* __restrict__ fl,
    const float* __restrict__ wT, const float* __restrict__ bias,
    void* __restrict__ out, int ni, const float* __restrict__ flag){
  __shared__ float red[256];
  int tid = threadIdx.x;
  int p = tid & 31, q = tid >> 5;
  int gx = blockIdx.x*32 + p;
  int gy = blockIdx.y;
  int b = blockIdx.z;
  float acc = 0.f;
  #pragma unroll
  for (int t=0;t<9;t++){
    int yy = gy + t/3 - 1, xx = gx + t%3 - 1;
    if (yy<0||yy>=HH||xx<0||xx>=WW) continue;
    long base = ((long)b*HW + yy*WW + xx)*64 + q*8;
    short8 h = *(const short8*)(fh + base);
    short8 lo = *(const short8*)(fl + base);
    #pragma unroll
    for (int cc=0;cc<8;cc++){
      float v = bfu2f((ush)h[cc]) + bfu2f((ush)lo[cc]);
      acc = fmaf(v, wT[(q*8+cc)*9 + t], acc);
    }
  }
  red[q*32+p] = acc;
  __syncthreads();
  if (tid < 32){
    float s = bias[0];
    #pragma unroll
    for (int k=0;k<8;k++) s += red[k*32+tid];
    long idx = ((long)b*5+ni)*HW + gy*WW + blockIdx.x*32 + tid;
    if (flag[0] > 0.5f) ((bf16*)out)[idx] = __float2bfloat16(s);
    else                ((float*)out)[idx] = s;
  }
}

extern "C" void kernel_launch(void* const* d_in, const int* in_sizes, int n_in,
                              void* d_out, int out_size, void* d_ws, size_t ws_size,
                              hipStream_t stream) {
  float* ws = (float*)d_ws;

  size_t off = 16;
  auto alloc = [&](size_t nel){ size_t o = off; off += (nel + 7) & ~(size_t)7; return o; };

  static const int IN_N[17] = {327680, 576, 64, 184320, 320, 184320, 320,
                               73728, 64, 147456, 256, 497664, 864, 147456,
                               256, 576, 1};
  size_t cin[17];
  for (int i=0;i<17;i++) cin[i] = alloc(IN_N[i]);

  size_t wt_init = alloc(640);
  size_t wdcn_pk[4]; for (int s=0;s<4;s++) wdcn_pk[s] = alloc(24576);
  size_t wt_rec = alloc(640);
  size_t pk_res1[5], pk_res2[5];
  for (int i=0;i<5;i++) pk_res1[i] = alloc(18432);
  for (int i=0;i<5;i++) pk_res2[i] = alloc(18432);
  size_t pk_bn[2]; for (int h=0;h<2;h++) pk_bn[h] = alloc(18432);
  size_t pk_off[4]; for (int s=0;s<4;s++) pk_off[s] = alloc(18432);
  size_t pk_com[4]; for (int s=0;s<4;s++) pk_com[s] = alloc(73728);

  size_t feat_h_o = alloc(10485760);
  size_t feat_l_o = alloc(10485760);
  size_t U = alloc(26738688);

  ush* feat_h = (ush*)(ws + feat_h_o);
  ush* feat_l = (ush*)(ws + feat_l_o);
  ush* feaA_h = (ush*)(ws + U);
  ush* feaA_l = (ush*)(ws + U + 2097152);
  ush* feaB_h = (ush*)(ws + U + 4194304);
  ush* feaB_l = (ush*)(ws + U + 6291456);
  ush* obuf_h = (ush*)(ws + U + 8388608);
  float* gpbuf = ws + U + 8388608;       // f32 gp aliases obuf (dead when gp live)
  float* ombuf = ws + U + 12582912;
  ush* hbuf_h = (ush*)(ws + U);          // res-phase alias (dead in neighbor loop)

  float* flag = ws;

  detect_dtype<<<dim3(1), dim3(256), 0, stream>>>((const ush*)d_in[0], flag);
  for (int i=0;i<17;i++){
    int n = IN_N[i];
    convert_in<<<dim3((n+255)/256), dim3(256), 0, stream>>>(d_in[i], ws+cin[i], n, flag);
  }
  const float* b_init = ws+cin[2];
  const float* res_b1 = ws+cin[4];
  const float* res_b2 = ws+cin[6];
  const float* b_bn   = ws+cin[8];
  const float* off_b  = ws+cin[10];
  const float* com_b  = ws+cin[12];
  const float* dcn_b  = ws+cin[14];
  const float* b_rec  = ws+cin[16];

  auto tr = [&](size_t src_o, size_t dst_o, int Co, int CiK){
    int total = Co*CiK;
    transpose_w<<<dim3((total+255)/256), dim3(256), 0, stream>>>(ws+src_o, ws+dst_o, Co, CiK);
  };
  tr(cin[1], wt_init, 64, 9);
  tr(cin[15], wt_rec, 1, 576);
  for (int s=0;s<4;s++)
    pack_dcn_w<<<dim3(192), dim3(256), 0, stream>>>(ws+cin[13]+(size_t)s*36864,
                                                    (ush*)(ws+wdcn_pk[s]));

  auto pack = [&](size_t src_o, size_t dst_o, int Cout, int Cin, int kh, int nOcB){
    int total = nOcB*36864;
    pack_w2<<<dim3((total+255)/256), dim3(256), 0, stream>>>(
        ws+src_o, (ush*)(ws+dst_o), Cout, Cin, kh, nOcB);
  };
  for (int i=0;i<5;i++) pack(cin[3]+(size_t)i*36864, pk_res1[i], 64, 64, 0, 1);
  for (int i=0;i<5;i++) pack(cin[5]+(size_t)i*36864, pk_res2[i], 64, 64, 0, 1);
  for (int h=0;h<2;h++) pack(cin[7], pk_bn[h], 64, 128, h, 1);
  for (int s=0;s<4;s++) pack(cin[9]+(size_t)s*36864,  pk_off[s], 64, 64, 0, 1);
  for (int s=0;s<4;s++) pack(cin[11]+(size_t)s*124416, pk_com[s], 216, 64, 0, 4);

  dim3 cblk(256);
  auto conv = [&](const ush* in_h, const ush* in_l, long in_ps,
                  const ush* in2_h, const ush* in2_l, long in2_ps,
                  size_t pk, const ush* pk2p,
                  const float* bias, int has_bias,
                  const ush* add_h, const ush* add_l, long add_ps, int add_cs,
                  ush* o_h, ush* o_l, long out_ps, int out_cs,
                  float* o_pf, int pf_C,
                  int Cout, int nOcB, int relu, int N, int nPl, int mtMode){
    if (nPl == 2 && mtMode == 2)
      conv_mfma<2,2,2><<<dim3(8,16,N*nOcB), cblk, 0, stream>>>(
          in_h, in_l, in_ps, in2_h, in2_l, in2_ps,
          (const ush*)(ws+pk), pk2p, bias, has_bias,
          add_h, add_l, add_ps, add_cs, o_h, o_l, out_ps, out_cs,
          o_pf, pf_C, Cout, nOcB, relu);
    else if (nPl == 2 && mtMode == 1)
      conv_mfma<2,2,1><<<dim3(8,32,N*nOcB), cblk, 0, stream>>>(
          in_h, in_l, in_ps, in2_h, in2_l, in2_ps,
          (const ush*)(ws+pk), pk2p, bias, has_bias,
          add_h, add_l, add_ps, add_cs, o_h, o_l, out_ps, out_cs,
          o_pf, pf_C, Cout, nOcB, relu);
    else if (nPl == 1 && mtMode == 1)
      conv_mfma<1,3,1><<<dim3(8,32,N*nOcB), cblk, 0, stream>>>(
          in_h, in_l, in_ps, in2_h, in2_l, in2_ps,
          (const ush*)(ws+pk), pk2p, bias, has_bias,
          add_h, add_l, add_ps, add_cs, o_h, o_l, out_ps, out_cs,
          o_pf, pf_C, Cout, nOcB, relu);
    else
      conv_mfma<1,3,2><<<dim3(8,16,N*nOcB), cblk, 0, stream>>>(
          in_h, in_l, in_ps, in2_h, in2_l, in2_ps,
          (const ush*)(ws+pk), pk2p, bias, has_bias,
          add_h, add_l, add_ps, add_cs, o_h, o_l, out_ps, out_cs,
          o_pf, pf_C, Cout, nOcB, relu);
  };

  // ---- feature extraction
  conv_init_kernel<<<dim3(8,8,20), cblk, 0, stream>>>(ws+cin[0], ws+wt_init, b_init,
                                                      feat_h, feat_l);
  for (int i=0;i<5;i++){
    // res1: h = relu(conv(feat)) -> hi-only intermediate; MT=1 for occupancy
    conv(feat_h, feat_l, HW, nullptr, nullptr, 0, pk_res1[i], nullptr,
         res_b1+(size_t)i*64, 1,
         nullptr, nullptr, 0, 0, hbuf_h, nullptr, HW, 64, nullptr, 0, 64, 1, 1, 20, 2, 1);
    // res2: feat += conv(h), single-plane input, MT=1
    conv(hbuf_h, hbuf_h, HW, nullptr, nullptr, 0, pk_res2[i], nullptr,
         res_b2+(size_t)i*64, 1,
         feat_h, feat_l, HW, 64, feat_h, feat_l, HW, 64, nullptr, 0, 64, 1, 0, 20, 1, 1);
  }
  // ---- per-neighbor alignment
  for (int i=0;i<5;i++){
    conv(feat_h + (size_t)2*HW*64, feat_l + (size_t)2*HW*64, 5L*HW,
         feat_h + (size_t)i*HW*64, feat_l + (size_t)i*HW*64, 5L*HW,
         pk_bn[0], (const ush*)(ws+pk_bn[1]), b_bn, 1,
         nullptr, nullptr, 0, 0, feaA_h, feaA_l, HW, 64, nullptr, 0, 64, 1, 0, 4, 2, 1);
    ush *fa_h = feaA_h, *fa_l = feaA_l, *fb_h = feaB_h, *fb_l = feaB_l;
    for (int s=0;s<4;s++){
      // off conv: single-plane input (offset branch), hi-only output
      conv(fa_h, fa_h, HW, nullptr, nullptr, 0, pk_off[s], nullptr,
           off_b+(size_t)s*64, 1,
           nullptr, nullptr, 0, 0, obuf_h, nullptr, HW, 64, nullptr, 0, 64, 1, 0, 4, 1, 1);
      conv(obuf_h, obuf_h, HW, nullptr, nullptr, 0, pk_com[s], nullptr,
           com_b+(size_t)s*216, 1,
           nullptr, nullptr, 0, 0, nullptr, nullptr, 0, 0, ombuf, 216, 216, 4, 0, 4, 1, 2);
      const ush *xs_h, *xs_l; long xps;
      if (s == 2){ xs_h = feat_h + (size_t)i*HW*64; xs_l = feat_l + (size_t)i*HW*64; xps = 5L*HW; }
      else       { xs_h = fa_h;                     xs_l = fa_l;                     xps = HW; }
      repack_gp<<<dim3(2048), cblk, 0, stream>>>(xs_h, xs_l, xps, gpbuf);
      dcn_mfma<<<dim3(2,128,4), cblk, 0, stream>>>(gpbuf, ombuf,
          (const ush*)(ws+wdcn_pk[s]), dcn_b+(size_t)s*64, fb_h, fb_l);
      ush* t;
      t = fa_h; fa_h = fb_h; fb_h = t;
      t = fa_l; fa_l = fb_l; fb_l = t;
    }
    rec_kernel<<<dim3(4,128,4), cblk, 0, stream>>>(fa_h, fa_l, ws+wt_rec, b_rec, d_out, i, flag);
  }
}

// Round 16
// 3257.315 us; speedup vs baseline: 2.4951x; 1.0548x over previous
//
#include <hip/hip_runtime.h>
#include <hip/hip_bf16.h>

typedef __hip_bfloat16 bf16;
typedef __attribute__((ext_vector_type(8))) short short8;
typedef __attribute__((ext_vector_type(4))) float floatx4;
typedef unsigned short ush;

#define HH 128
#define WW 128
#define HW 16384

__device__ __forceinline__ float b2f(bf16 v){ return __bfloat162float(v); }
__device__ __forceinline__ float bfu2f(ush u){
  union{unsigned int i; float f;} c; c.i = ((unsigned int)u)<<16; return c.f;
}
__device__ __forceinline__ ush f2bfu(float f){
  bf16 h = __float2bfloat16(f);
  return *(ush*)&h;
}

// ---------- dtype detector
__global__ void detect_dtype(const ush* __restrict__ x, float* __restrict__ flag){
  __shared__ int bad;
  if (threadIdx.x==0) bad = 0;
  __syncthreads();
  for (int j=threadIdx.x; j<4096; j+=256){
    float f = bfu2f(x[j]);
    if (!(fabsf(f) < 1e4f)) atomicOr(&bad, 1);
  }
  __syncthreads();
  if (threadIdx.x==0) flag[0] = bad ? 0.f : 1.f;
}

// ---------- input convert
__global__ void convert_in(const void* __restrict__ src, float* __restrict__ dst, int n,
                           const float* __restrict__ flag){
  int i = blockIdx.x*256 + threadIdx.x;
  if (i >= n) return;
  float v = (flag[0] > 0.5f) ? b2f(((const bf16*)src)[i]) : ((const float*)src)[i];
  dst[i] = v;
}

// ---------- weight transpose
__global__ void transpose_w(const float* __restrict__ src, float* __restrict__ dst, int Co, int CiK){
  int tid = blockIdx.x*256 + threadIdx.x;
  if (tid >= Co*CiK) return;
  int co = tid / CiK, r = tid - co*CiK;
  dst[(long)r*Co + co] = src[tid];
}

// ---------- weight pack v2: fragment-order
__global__ void pack_w2(const float* __restrict__ src, ush* __restrict__ dst,
                        int Cout, int Cin, int kh, int nOcB){
  int idx = blockIdx.x*256 + threadIdx.x;
  int total = nOcB*36864;
  if (idx >= total) return;
  int ocb = idx / 36864; int r = idx - ocb*36864;
  int c  = r & 7;
  int lx = (r>>3) & 15;
  int n  = (r>>7) & 3;
  int lk = (r>>9) & 3;
  int j  = r>>11;
  int t = j>>1, ch = j&1;
  int oc = n*16+lx;
  int k = ch*32 + lk*8 + c;
  int ocg = ocb*64 + oc, icg = kh*64 + k;
  float v = (ocg < Cout && icg < Cin) ? src[((long)ocg*Cin + icg)*9 + t] : 0.f;
  dst[idx] = f2bfu(v);
}

// ---------- DCN weight pack
__global__ void pack_dcn_w(const float* __restrict__ src, ush* __restrict__ dst){
  int idx = blockIdx.x*256 + threadIdx.x;
  if (idx >= 49152) return;
  int g = idx / 6144; int r = idx - g*6144;
  int oc = r / 96; int k = r - oc*96;
  float v = 0.f;
  if (k < 72){
    int tap = k >> 3, c = k & 7;
    v = src[((long)oc*64 + g*8 + c)*9 + tap];
  }
  dst[idx] = f2bfu(v);
}

// ---------- conv_init
__global__ __launch_bounds__(256) void conv_init_kernel(const float* __restrict__ x,
    const float* __restrict__ wT, const float* __restrict__ bias,
    ush* __restrict__ fh, ush* __restrict__ fl){
  __shared__ ush L[256*66];
  int tid = threadIdx.x;
  int tx = tid & 15, ty = tid >> 4;
  int gx = blockIdx.x*16+tx, gy = blockIdx.y*16+ty;
  int n = blockIdx.z;
  const float* xp = x + (long)n*HW;
  float v[9];
  #pragma unroll
  for (int dy=0;dy<3;dy++)
    #pragma unroll
    for (int dx=0;dx<3;dx++){
      int yy = gy+dy-1, xx = gx+dx-1;
      bool ok = (yy>=0)&&(yy<HH)&&(xx>=0)&&(xx<WW);
      v[dy*3+dx] = ok ? xp[yy*WW+xx] : 0.f;
    }
  float acc[64];
  #pragma unroll 1
  for (int oc=0; oc<64; oc++){
    float a = bias[oc];
    #pragma unroll
    for (int k=0;k<9;k++) a = fmaf(v[k], wT[k*64+oc], a);
    acc[oc] = fmaxf(a, 0.f);
  }
  #pragma unroll 1
  for (int pass=0; pass<2; pass++){
    #pragma unroll 1
    for (int oc=0; oc<64; oc++){
      float a = acc[oc];
      ush h = f2bfu(a);
      L[tid*66+oc] = pass ? f2bfu(a - bfu2f(h)) : h;
    }
    __syncthreads();
    ush* dst = pass ? fl : fh;
    for (int j=tid; j<2048; j+=256){
      int c8 = j&7, pidx = j>>3;
      int row = pidx>>4, col = pidx&15;
      long addr = ((long)n*HW + (blockIdx.y*16+row)*WW + blockIdx.x*16+col)*64 + c8*8;
      *(short8*)(dst+addr) = *(const short8*)(L + pidx*66 + c8*8);
    }
    __syncthreads();
  }
}

// ---------- MFMA implicit-GEMM 3x3 SAME conv (generic)
template<int NPL, int MINW, int MT>
__global__ __launch_bounds__(256, MINW) void conv_mfma(
    const ush* __restrict__ in_hi, const ush* __restrict__ in_lo, long in_ps,
    const ush* __restrict__ in2_hi, const ush* __restrict__ in2_lo, long in2_ps,
    const ush* __restrict__ wpack, const ush* __restrict__ wpack2,
    const float* __restrict__ bias, int has_bias,
    const ush* __restrict__ add_hi, const ush* __restrict__ add_lo,
    long add_ps, int add_cs,
    ush* __restrict__ out_hi, ush* __restrict__ out_lo,
    long out_ps, int out_cs,
    float* __restrict__ out_pf, int pf_C,
    int Cout, int nOcB, int relu)
{
  constexpr int ROWS = 4*MT + 2;
  constexpr int APX  = ROWS*18;
  constexpr int NPX  = 4*MT*16;
  constexpr int LDSN = (NPL*APX*64 > 2*NPX*66) ? NPL*APX*64 : 2*NPX*66;
  __shared__ ush A[LDSN];
  int tid = threadIdx.x;
  int z = blockIdx.z; int img = z / nOcB; int ocb = z - img*nOcB;
  int x0 = blockIdx.x*16 - 1, y0 = blockIdx.y*(4*MT) - 1;
  int w = tid>>6, l = tid&63, lx = l&15, lk = l>>4;
  floatx4 acc[MT][4];
  #pragma unroll
  for (int mt=0;mt<MT;mt++)
    #pragma unroll
    for (int n=0;n<4;n++) acc[mt][n] = (floatx4){0.f,0.f,0.f,0.f};

  auto phase = [&](const ush* ihb, const ush* ilb, const ush* wfb){
    __syncthreads();
    #pragma unroll
    for (int p=0;p<NPL;p++){
      const ush* src = p ? ilb : ihb;
      ush* dstp = A + p*APX*64;
      for (int j=tid; j<APX*8; j+=256){
        int pidx = j>>3, c8 = j&7;
        int row = pidx/18, col = pidx - row*18;
        int yy = y0+row, xx = x0+col;
        uint4 v = make_uint4(0u,0u,0u,0u);
        if ((unsigned)yy < 128u && (unsigned)xx < 128u)
          v = *(const uint4*)(src + ((long)(yy*WW+xx))*64 + c8*8);
        *(uint4*)(dstp + pidx*64 + ((c8 ^ (pidx&7))<<3)) = v;
      }
    }
    const ush* wfrag = wfb + lk*4*128 + lx*8;
    short8 bf[4][4];
    #pragma unroll
    for (int s=0;s<3;s++)
      #pragma unroll
      for (int n=0;n<4;n++)
        bf[s][n] = *(const short8*)(wfrag + (s*16 + n)*128);
    __syncthreads();
    #pragma unroll
    for (int j=0;j<18;j++){
      int t = j>>1, ch = j&1;
      if (j<15){
        #pragma unroll
        for (int n=0;n<4;n++)
          bf[(j+3)&3][n] = *(const short8*)(wfrag + ((j+3)*16 + n)*128);
      }
      int ky = t/3, kx = t - ky*3;
      int jc = ch*4 + lk;
      #pragma unroll
      for (int mt=0; mt<MT; mt++){
        int pidx = (w*MT+mt+ky)*18 + lx + kx;
        #pragma unroll
        for (int p=0;p<NPL;p++){
          short8 af = *(const short8*)(A + p*APX*64 + pidx*64 + ((jc ^ (pidx&7))<<3));
          #pragma unroll
          for (int n=0;n<4;n++)
            acc[mt][n] = __builtin_amdgcn_mfma_f32_16x16x32_bf16(af, bf[j&3][n], acc[mt][n], 0,0,0);
        }
      }
    }
  };
  phase(in_hi + (long)img*in_ps*64, in_lo + (long)img*in_ps*64,
        wpack + (long)ocb*36864);
  if (wpack2)
    phase(in2_hi + (long)img*in2_ps*64, in2_lo + (long)img*in2_ps*64,
          wpack2 + (long)ocb*36864);

  int ybase = blockIdx.y*(4*MT) + w*MT;
  int xbase = blockIdx.x*16 + lk*4;
  if (out_pf){
    #pragma unroll
    for (int mt=0;mt<MT;mt++){
      int y = ybase + mt;
      #pragma unroll
      for (int n=0;n<4;n++){
        int ocg = ocb*64 + n*16 + lx;
        if (ocg < Cout){
          float bv = has_bias ? bias[ocg] : 0.f;
          #pragma unroll
          for (int r=0;r<4;r++){
            int xg = xbase + r;
            out_pf[((long)img*pf_C + ocg)*HW + y*WW + xg] = acc[mt][n][r] + bv;
          }
        }
      }
    }
  } else {
    __syncthreads();
    ush* L0 = A;
    ush* L1 = A + NPX*66;
    #pragma unroll
    for (int mt=0;mt<MT;mt++){
      int y = ybase + mt;
      int rowl = w*MT + mt;
      #pragma unroll
      for (int n=0;n<4;n++){
        int ocg = n*16 + lx;
        float bv = has_bias ? bias[ocg] : 0.f;
        #pragma unroll
        for (int r=0;r<4;r++){
          int coll = lk*4 + r;
          float v = acc[mt][n][r] + bv;
          if (add_hi){
            long ap = ((long)img*add_ps + y*WW + blockIdx.x*16 + coll)*add_cs + ocg;
            v += bfu2f(add_hi[ap]) + bfu2f(add_lo[ap]);
          }
          if (relu) v = fmaxf(v, 0.f);
          ush h = f2bfu(v);
          L0[(rowl*16+coll)*66 + ocg] = h;
          if (out_lo) L1[(rowl*16+coll)*66 + ocg] = f2bfu(v - bfu2f(h));
        }
      }
    }
    __syncthreads();
    for (int j=tid; j<NPX*8; j+=256){
      int pidx = j>>3, c8 = j&7;
      int row = pidx>>4, col = pidx&15;
      long pp = (long)img*out_ps + (blockIdx.y*(4*MT)+row)*WW + blockIdx.x*16+col;
      *(short8*)(out_hi + pp*64 + c8*8) = *(const short8*)(L0 + pidx*66 + c8*8);
      if (out_lo)
        *(short8*)(out_lo + pp*64 + c8*8) = *(const short8*)(L1 + pidx*66 + c8*8);
    }
  }
}

// ---------- fused residual block: dst = src + conv2(relu(conv1(src_hi)))
// FIX vs r15: h halo pixels outside [0,128)^2 are ZERO (SAME-pad semantics),
// not recomputed conv values.
__global__ __launch_bounds__(256,4) void res_fused(
    const ush* __restrict__ src_h, const ush* __restrict__ src_l,
    const ush* __restrict__ w1, const float* __restrict__ b1,
    const ush* __restrict__ w2, const float* __restrict__ b2,
    ush* __restrict__ dst_h, ush* __restrict__ dst_l)
{
  __shared__ ush F[180*64];   // feat_hi tile: 9 rows x 20 cols, swizzled
  __shared__ ush Hs[112*64];  // h tile: 6 rows x 18 cols (108 used), swizzled
  int tid = threadIdx.x;
  int bx = blockIdx.x, by = blockIdx.y, img = blockIdx.z;
  int fy0 = by*4 - 2, fx0 = bx*16 - 2;
  int w = tid>>6, l = tid&63, lx = l&15, lk = l>>4;
  const ush* sh = src_h + (long)img*HW*64;
  for (int j=tid; j<1440; j+=256){
    int pidx = j>>3, c8 = j&7;
    int row = pidx/20, col = pidx - row*20;
    int yy = fy0+row, xx = fx0+col;
    uint4 v = make_uint4(0u,0u,0u,0u);
    if ((unsigned)yy<128u && (unsigned)xx<128u)
      v = *(const uint4*)(sh + ((long)(yy*WW+xx))*64 + c8*8);
    *(uint4*)(F + pidx*64 + ((c8 ^ (pidx&7))<<3)) = v;
  }
  const ush* wf1 = w1 + lk*4*128 + lx*8;
  int hrow[2], hcol[2], hvalid[2];
  #pragma unroll
  for (int mm=0;mm<2;mm++){
    int m = w + mm*4;
    hvalid[mm] = (m < 7);
    int hp = m*16 + lx;
    hrow[mm] = hp/18; hcol[mm] = hp - hrow[mm]*18;
  }
  floatx4 acc1[2][4];
  #pragma unroll
  for (int mm=0;mm<2;mm++)
    #pragma unroll
    for (int n=0;n<4;n++) acc1[mm][n] = (floatx4){0.f,0.f,0.f,0.f};
  short8 bf[4][4];
  #pragma unroll
  for (int s=0;s<3;s++)
    #pragma unroll
    for (int n=0;n<4;n++)
      bf[s][n] = *(const short8*)(wf1 + (s*16 + n)*128);
  __syncthreads();
  #pragma unroll
  for (int j=0;j<18;j++){
    int t = j>>1, ch = j&1;
    if (j<15){
      #pragma unroll
      for (int n=0;n<4;n++)
        bf[(j+3)&3][n] = *(const short8*)(wf1 + ((j+3)*16 + n)*128);
    }
    int ky = t/3, kx = t - ky*3;
    int jc = ch*4 + lk;
    #pragma unroll
    for (int mm=0;mm<2;mm++){
      if (!hvalid[mm]) continue;
      int pidx = (hrow[mm]+ky)*20 + hcol[mm] + kx;
      short8 af = *(const short8*)(F + pidx*64 + ((jc ^ (pidx&7))<<3));
      #pragma unroll
      for (int n=0;n<4;n++)
        acc1[mm][n] = __builtin_amdgcn_mfma_f32_16x16x32_bf16(af, bf[j&3][n], acc1[mm][n], 0,0,0);
    }
  }
  // write h (relu) into Hs; ZERO pixels whose feat coords are out of range
  #pragma unroll
  for (int mm=0;mm<2;mm++){
    if (!hvalid[mm]) continue;
    int m = w + mm*4;
    #pragma unroll
    for (int n=0;n<4;n++){
      int oc = n*16+lx;
      float bv = b1[oc];
      #pragma unroll
      for (int r=0;r<4;r++){
        int hp = m*16 + lk*4 + r;
        int hr = hp/18, hc = hp - hr*18;
        int fy = fy0 + 1 + hr, fx = fx0 + 1 + hc;
        bool inimg = ((unsigned)fy < 128u) && ((unsigned)fx < 128u);
        float v = inimg ? fmaxf(acc1[mm][n][r] + bv, 0.f) : 0.f;
        Hs[hp*64 + (((oc>>3) ^ (hp&7))<<3) + (oc&7)] = f2bfu(v);
      }
    }
  }
  __syncthreads();
  // conv2: 4 output rows (wave w -> row w), K=576 over h
  const ush* wf2 = w2 + lk*4*128 + lx*8;
  floatx4 acc2[4];
  #pragma unroll
  for (int n=0;n<4;n++) acc2[n] = (floatx4){0.f,0.f,0.f,0.f};
  #pragma unroll
  for (int s=0;s<3;s++)
    #pragma unroll
    for (int n=0;n<4;n++)
      bf[s][n] = *(const short8*)(wf2 + (s*16 + n)*128);
  #pragma unroll
  for (int j=0;j<18;j++){
    int t = j>>1, ch = j&1;
    if (j<15){
      #pragma unroll
      for (int n=0;n<4;n++)
        bf[(j+3)&3][n] = *(const short8*)(wf2 + ((j+3)*16 + n)*128);
    }
    int ky = t/3, kx = t - ky*3;
    int jc = ch*4 + lk;
    int pidx = (w+ky)*18 + lx + kx;
    short8 af = *(const short8*)(Hs + pidx*64 + ((jc ^ (pidx&7))<<3));
    #pragma unroll
    for (int n=0;n<4;n++)
      acc2[n] = __builtin_amdgcn_mfma_f32_16x16x32_bf16(af, bf[j&3][n], acc2[n], 0,0,0);
  }
  // residual add
  const ush* sl = src_l + (long)img*HW*64;
  int gy = by*4 + w;
  float vout[4][4];
  #pragma unroll
  for (int n=0;n<4;n++){
    int oc = n*16+lx;
    float bv = b2[oc];
    #pragma unroll
    for (int r=0;r<4;r++){
      int colp = lk*4 + r;
      int gx = bx*16 + colp;
      int pt = (w+2)*20 + colp + 2;
      float fh = bfu2f(F[pt*64 + (((oc>>3) ^ (pt&7))<<3) + (oc&7)]);
      float fl = bfu2f(sl[((long)(gy*WW+gx))*64 + oc]);
      vout[n][r] = acc2[n][r] + bv + fh + fl;
    }
  }
  __syncthreads();
  ush* L0 = F;
  ush* L1 = F + 64*66;
  #pragma unroll
  for (int n=0;n<4;n++){
    int oc = n*16+lx;
    #pragma unroll
    for (int r=0;r<4;r++){
      int px = w*16 + lk*4 + r;
      float v = vout[n][r];
      ush h = f2bfu(v);
      L0[px*66 + oc] = h;
      L1[px*66 + oc] = f2bfu(v - bfu2f(h));
    }
  }
  __syncthreads();
  for (int j=tid; j<512; j+=256){
    int pidx = j>>3, c8 = j&7;
    int row = pidx>>4, col = pidx&15;
    long pp = ((long)img*HW + (by*4+row)*WW + bx*16+col)*64 + c8*8;
    *(short8*)(dst_h + pp) = *(const short8*)(L0 + pidx*66 + c8*8);
    *(short8*)(dst_l + pp) = *(const short8*)(L1 + pidx*66 + c8*8);
  }
}

// ---------- repack NHWC hi/lo -> group-planar f32 [4][8][HW][8]
__global__ __launch_bounds__(256) void repack_gp(const ush* __restrict__ in_h,
    const ush* __restrict__ in_l, long in_ps, float* __restrict__ gp){
  long idx = (long)blockIdx.x*256 + threadIdx.x;
  int img = (int)(idx >> 17);
  int rem = (int)(idx & 131071);
  int pix = rem >> 3, c8 = rem & 7;
  long src = ((long)img*in_ps + pix)*64 + c8*8;
  short8 h = *(const short8*)(in_h+src);
  short8 lo = *(const short8*)(in_l+src);
  float* d = gp + (((long)(img*8+c8))*HW + pix)*8;
  #pragma unroll
  for (int c=0;c<8;c++) d[c] = bfu2f((ush)h[c]) + bfu2f((ush)lo[c]);
}

// ---------- MFMA modulated deformable conv; half-row blocks, 4-way tap split
__global__ __launch_bounds__(256) void dcn_mfma(
    const float* __restrict__ gp,
    const float* __restrict__ om,
    const ush* __restrict__ wpk,
    const float* __restrict__ bias,
    ush* __restrict__ out_hi, ush* __restrict__ out_lo)
{
  __shared__ ush S[13312];
  ush* Ah = S;
  ush* Bt = S + 6656;
  int tid = threadIdx.x;
  int half = blockIdx.x, gy = blockIdx.y, img = blockIdx.z;
  int xoff = half*64;
  {
    short8 z = {0,0,0,0,0,0,0,0};
    for (int j=tid; j<192; j+=256){
      int px = j/3, c = j - px*3;
      *(short8*)(Ah + px*104 + 72 + c*8) = z;
    }
  }
  int w = tid>>6, l = tid&63, lx = l&15, lk = l>>4;
  int px_s = tid & 63, q = tid >> 6;
  int t0 = (q==0)?0:(q*2+1), t1 = t0 + ((q==0)?3:2);
  const float* omb = om + (long)img*216*HW + gy*WW + xoff + px_s;
  floatx4 acc[4];
  #pragma unroll
  for (int n=0;n<4;n++) acc[n] = (floatx4){0.f,0.f,0.f,0.f};

  #pragma unroll 1
  for (int g=0; g<8; g++){
    __syncthreads();
    const ush* wsrc = wpk + g*6144;
    for (int j=tid; j<768; j+=256){
      int oc = j/12, kc = j - oc*12;
      *(short8*)(Bt + oc*104 + kc*8) = *(const short8*)(wsrc + oc*96 + kc*8);
    }
    const float* gpb = gp + ((long)(img*8+g))*HW*8;
    #pragma unroll 1
    for (int t=t0; t<t1; t++){
      int ch = g*9+t;
      float dy = omb[(long)ch*HW];
      float dx = omb[(long)(72+ch)*HW];
      float mv = omb[(long)(144+ch)*HW];
      float m = 1.f/(1.f+__expf(-mv));
      float py = (float)gy + (float)(t/3 - 1) + dy;
      float pxf = (float)(xoff + px_s) + (float)(t%3 - 1) + dx;
      float fy = floorf(py), fx = floorf(pxf);
      int y0 = (int)fy, x0 = (int)fx;
      float wy = py - fy, wx = pxf - fx;
      bool y0v = (y0>=0 && y0<HH), y1v = (y0+1>=0 && y0+1<HH);
      bool x0v = (x0>=0 && x0<WW), x1v = (x0+1>=0 && x0+1<WW);
      float w00 = (1.f-wy)*(1.f-wx)*m * ((y0v&&x0v)?1.f:0.f);
      float w01 = (1.f-wy)*wx*m      * ((y0v&&x1v)?1.f:0.f);
      float w10 = wy*(1.f-wx)*m      * ((y1v&&x0v)?1.f:0.f);
      float w11 = wy*wx*m            * ((y1v&&x1v)?1.f:0.f);
      int y0c = min(max(y0,0),HH-1), y1c = min(max(y0+1,0),HH-1);
      int x0c = min(max(x0,0),WW-1), x1c = min(max(x0+1,0),WW-1);
      const float* p00 = gpb + (((long)(y0c*WW+x0c))<<3);
      const float* p01 = gpb + (((long)(y0c*WW+x1c))<<3);
      const float* p10 = gpb + (((long)(y1c*WW+x0c))<<3);
      const float* p11 = gpb + (((long)(y1c*WW+x1c))<<3);
      float4 a00=*(const float4*)p00, b00=*(const float4*)(p00+4);
      float4 a01=*(const float4*)p01, b01=*(const float4*)(p01+4);
      float4 a10=*(const float4*)p10, b10=*(const float4*)(p10+4);
      float4 a11=*(const float4*)p11, b11=*(const float4*)(p11+4);
      float val[8];
      val[0]=w00*a00.x+w01*a01.x+w10*a10.x+w11*a11.x;
      val[1]=w00*a00.y+w01*a01.y+w10*a10.y+w11*a11.y;
      val[2]=w00*a00.z+w01*a01.z+w10*a10.z+w11*a11.z;
      val[3]=w00*a00.w+w01*a01.w+w10*a10.w+w11*a11.w;
      val[4]=w00*b00.x+w01*b01.x+w10*b10.x+w11*b11.x;
      val[5]=w00*b00.y+w01*b01.y+w10*b10.y+w11*b11.y;
      val[6]=w00*b00.z+w01*b01.z+w10*b10.z+w11*b11.z;
      val[7]=w00*b00.w+w01*b01.w+w10*b10.w+w11*b11.w;
      short8 vh;
      #pragma unroll
      for (int c=0;c<8;c++) vh[c] = (short)f2bfu(val[c]);
      *(short8*)(Ah + px_s*104 + t*8) = vh;
    }
    __syncthreads();
    #pragma unroll
    for (int ks=0; ks<3; ks++){
      short8 bfg[4];
      #pragma unroll
      for (int n=0;n<4;n++)
        bfg[n] = *(const short8*)(Bt + (n*16+lx)*104 + ks*32 + lk*8);
      int px = w*16 + lx;
      short8 ah = *(const short8*)(Ah + px*104 + ks*32 + lk*8);
      #pragma unroll
      for (int n=0;n<4;n++)
        acc[n] = __builtin_amdgcn_mfma_f32_16x16x32_bf16(ah, bfg[n], acc[n], 0,0,0);
    }
  }
  __syncthreads();
  ush* L0 = S;
  ush* L1 = S + 64*66;
  #pragma unroll
  for (int n=0;n<4;n++){
    int oc = n*16 + lx;
    float bv = bias[oc];
    #pragma unroll
    for (int r=0;r<4;r++){
      int pxl = w*16 + lk*4 + r;
      float v = acc[n][r] + bv;
      ush h = f2bfu(v);
      L0[pxl*66 + oc] = h;
      L1[pxl*66 + oc] = f2bfu(v - bfu2f(h));
    }
  }
  __syncthreads();
  long base = ((long)img*HW + gy*WW + xoff)*64;
  for (int j=tid; j<512; j+=256){
    int pidx = j>>3, c8 = j&7;
    *(short8*)(out_hi + base + pidx*64 + c8*8) = *(const short8*)(L0 + pidx*66 + c8*8);
    *(short8*)(out_lo + base + pidx*64 + c8*8) = *(const short8*)(L1 + pidx*66 + c8*8);
  }
}

// ---------- reconstruction conv
__global__ __launch_bounds__(256) void rec_kernel(
    const ush* __restrict__ fh, const ush* __restrict__ fl,
    const float* __restrict__ wT, const float* __restrict__ bias,
    void* __restrict__ out, int ni, const float* __restrict__ flag){
  __shared__ float red[256];
  int tid = threadIdx.x;
  int p = tid & 31, q = tid >> 5;
  int gx = blockIdx.x*32 + p;
  int gy = blockIdx.y;
  int b = blockIdx.z;
  float acc = 0.f;
  #pragma unroll
  for (int t=0;t<9;t++){
    int yy = gy + t/3 - 1, xx = gx + t%3 - 1;
    if (yy<0||yy>=HH||xx<0||xx>=WW) continue;
    long base = ((long)b*HW + yy*WW + xx)*64 + q*8;
    short8 h = *(const short8*)(fh + base);
    short8 lo = *(const short8*)(fl + base);
    #pragma unroll
    for (int cc=0;cc<8;cc++){
      float v = bfu2f((ush)h[cc]) + bfu2f((ush)lo[cc]);
      acc = fmaf(v, wT[(q*8+cc)*9 + t], acc);
    }
  }
  red[q*32+p] = acc;
  __syncthreads();
  if (tid < 32){
    float s = bias[0];
    #pragma unroll
    for (int k=0;k<8;k++) s += red[k*32+tid];
    long idx = ((long)b*5+ni)*HW + gy*WW + blockIdx.x*32 + tid;
    if (flag[0] > 0.5f) ((bf16*)out)[idx] = __float2bfloat16(s);
    else                ((float*)out)[idx] = s;
  }
}

extern "C" void kernel_launch(void* const* d_in, const int* in_sizes, int n_in,
                              void* d_out, int out_size, void* d_ws, size_t ws_size,
                              hipStream_t stream) {
  float* ws = (float*)d_ws;

  size_t off = 16;
  auto alloc = [&](size_t nel){ size_t o = off; off += (nel + 7) & ~(size_t)7; return o; };

  static const int IN_N[17] = {327680, 576, 64, 184320, 320, 184320, 320,
                               73728, 64, 147456, 256, 497664, 864, 147456,
                               256, 576, 1};
  size_t cin[17];
  for (int i=0;i<17;i++) cin[i] = alloc(IN_N[i]);

  size_t wt_init = alloc(640);
  size_t wdcn_pk[4]; for (int s=0;s<4;s++) wdcn_pk[s] = alloc(24576);
  size_t wt_rec = alloc(640);
  size_t pk_res1[5], pk_res2[5];
  for (int i=0;i<5;i++) pk_res1[i] = alloc(18432);
  for (int i=0;i<5;i++) pk_res2[i] = alloc(18432);
  size_t pk_bn[2]; for (int h=0;h<2;h++) pk_bn[h] = alloc(18432);
  size_t pk_off[4]; for (int s=0;s<4;s++) pk_off[s] = alloc(18432);
  size_t pk_com[4]; for (int s=0;s<4;s++) pk_com[s] = alloc(73728);

  size_t feat_h_o = alloc(10485760);
  size_t feat_l_o = alloc(10485760);
  size_t U = alloc(26738688);

  ush* feat_h = (ush*)(ws + feat_h_o);
  ush* feat_l = (ush*)(ws + feat_l_o);
  ush* alt_h  = (ush*)(ws + U);
  ush* alt_l  = (ush*)(ws + U + 10485760);
  ush* hbuf_h = (ush*)(ws + U + 10485760);
  ush* feaA_h = (ush*)(ws + U);
  ush* feaA_l = (ush*)(ws + U + 2097152);
  ush* feaB_h = (ush*)(ws + U + 4194304);
  ush* feaB_l = (ush*)(ws + U + 6291456);
  ush* obuf_h = (ush*)(ws + U + 8388608);
  float* gpbuf = ws + U + 8388608;
  float* ombuf = ws + U + 12582912;

  float* flag = ws;

  detect_dtype<<<dim3(1), dim3(256), 0, stream>>>((const ush*)d_in[0], flag);
  for (int i=0;i<17;i++){
    int n = IN_N[i];
    convert_in<<<dim3((n+255)/256), dim3(256), 0, stream>>>(d_in[i], ws+cin[i], n, flag);
  }
  const float* b_init = ws+cin[2];
  const float* res_b1 = ws+cin[4];
  const float* res_b2 = ws+cin[6];
  const float* b_bn   = ws+cin[8];
  const float* off_b  = ws+cin[10];
  const float* com_b  = ws+cin[12];
  const float* dcn_b  = ws+cin[14];
  const float* b_rec  = ws+cin[16];

  auto tr = [&](size_t src_o, size_t dst_o, int Co, int CiK){
    int total = Co*CiK;
    transpose_w<<<dim3((total+255)/256), dim3(256), 0, stream>>>(ws+src_o, ws+dst_o, Co, CiK);
  };
  tr(cin[1], wt_init, 64, 9);
  tr(cin[15], wt_rec, 1, 576);
  for (int s=0;s<4;s++)
    pack_dcn_w<<<dim3(192), dim3(256), 0, stream>>>(ws+cin[13]+(size_t)s*36864,
                                                    (ush*)(ws+wdcn_pk[s]));

  auto pack = [&](size_t src_o, size_t dst_o, int Cout, int Cin, int kh, int nOcB){
    int total = nOcB*36864;
    pack_w2<<<dim3((total+255)/256), dim3(256), 0, stream>>>(
        ws+src_o, (ush*)(ws+dst_o), Cout, Cin, kh, nOcB);
  };
  for (int i=0;i<5;i++) pack(cin[3]+(size_t)i*36864, pk_res1[i], 64, 64, 0, 1);
  for (int i=0;i<5;i++) pack(cin[5]+(size_t)i*36864, pk_res2[i], 64, 64, 0, 1);
  for (int h=0;h<2;h++) pack(cin[7], pk_bn[h], 64, 128, h, 1);
  for (int s=0;s<4;s++) pack(cin[9]+(size_t)s*36864,  pk_off[s], 64, 64, 0, 1);
  for (int s=0;s<4;s++) pack(cin[11]+(size_t)s*124416, pk_com[s], 216, 64, 0, 4);

  dim3 cblk(256);
  auto conv = [&](const ush* in_h, const ush* in_l, long in_ps,
                  const ush* in2_h, const ush* in2_l, long in2_ps,
                  size_t pk, const ush* pk2p,
                  const float* bias, int has_bias,
                  const ush* add_h, const ush* add_l, long add_ps, int add_cs,
                  ush* o_h, ush* o_l, long out_ps, int out_cs,
                  float* o_pf, int pf_C,
                  int Cout, int nOcB, int relu, int N, int nPl, int mtMode){
    if (nPl == 2 && mtMode == 2)
      conv_mfma<2,2,2><<<dim3(8,16,N*nOcB), cblk, 0, stream>>>(
          in_h, in_l, in_ps, in2_h, in2_l, in2_ps,
          (const ush*)(ws+pk), pk2p, bias, has_bias,
          add_h, add_l, add_ps, add_cs, o_h, o_l, out_ps, out_cs,
          o_pf, pf_C, Cout, nOcB, relu);
    else if (nPl == 2 && mtMode == 1)
      conv_mfma<2,2,1><<<dim3(8,32,N*nOcB), cblk, 0, stream>>>(
          in_h, in_l, in_ps, in2_h, in2_l, in2_ps,
          (const ush*)(ws+pk), pk2p, bias, has_bias,
          add_h, add_l, add_ps, add_cs, o_h, o_l, out_ps, out_cs,
          o_pf, pf_C, Cout, nOcB, relu);
    else if (nPl == 1 && mtMode == 1)
      conv_mfma<1,3,1><<<dim3(8,32,N*nOcB), cblk, 0, stream>>>(
          in_h, in_l, in_ps, in2_h, in2_l, in2_ps,
          (const ush*)(ws+pk), pk2p, bias, has_bias,
          add_h, add_l, add_ps, add_cs, o_h, o_l, out_ps, out_cs,
          o_pf, pf_C, Cout, nOcB, relu);
    else
      conv_mfma<1,3,2><<<dim3(8,16,N*nOcB), cblk, 0, stream>>>(
          in_h, in_l, in_ps, in2_h, in2_l, in2_ps,
          (const ush*)(ws+pk), pk2p, bias, has_bias,
          add_h, add_l, add_ps, add_cs, o_h, o_l, out_ps, out_cs,
          o_pf, pf_C, Cout, nOcB, relu);
  };

  // ---- feature extraction
  conv_init_kernel<<<dim3(8,8,20), cblk, 0, stream>>>(ws+cin[0], ws+wt_init, b_init,
                                                      feat_h, feat_l);
  // res block 0: unfused (parity)
  conv(feat_h, feat_l, HW, nullptr, nullptr, 0, pk_res1[0], nullptr,
       res_b1, 1,
       nullptr, nullptr, 0, 0, hbuf_h, nullptr, HW, 64, nullptr, 0, 64, 1, 1, 20, 2, 1);
  conv(hbuf_h, hbuf_h, HW, nullptr, nullptr, 0, pk_res2[0], nullptr,
       res_b2, 1,
       feat_h, feat_l, HW, 64, feat_h, feat_l, HW, 64, nullptr, 0, 64, 1, 0, 20, 1, 1);
  // res blocks 1..4: fused, ping-pong feat <-> alt (ends in feat)
  {
    ush *sh = feat_h, *sl = feat_l, *dh = alt_h, *dl = alt_l;
    for (int i=1;i<5;i++){
      res_fused<<<dim3(8,32,20), cblk, 0, stream>>>(
          sh, sl, (const ush*)(ws+pk_res1[i]), res_b1+(size_t)i*64,
          (const ush*)(ws+pk_res2[i]), res_b2+(size_t)i*64, dh, dl);
      ush* t;
      t = sh; sh = dh; dh = t;
      t = sl; sl = dl; dl = t;
    }
  }
  // ---- per-neighbor alignment
  for (int i=0;i<5;i++){
    conv(feat_h + (size_t)2*HW*64, feat_l + (size_t)2*HW*64, 5L*HW,
         feat_h + (size_t)i*HW*64, feat_l + (size_t)i*HW*64, 5L*HW,
         pk_bn[0], (const ush*)(ws+pk_bn[1]), b_bn, 1,
         nullptr, nullptr, 0, 0, feaA_h, feaA_l, HW, 64, nullptr, 0, 64, 1, 0, 4, 2, 1);
    ush *fa_h = feaA_h, *fa_l = feaA_l, *fb_h = feaB_h, *fb_l = feaB_l;
    for (int s=0;s<4;s++){
      conv(fa_h, fa_h, HW, nullptr, nullptr, 0, pk_off[s], nullptr,
           off_b+(size_t)s*64, 1,
           nullptr, nullptr, 0, 0, obuf_h, nullptr, HW, 64, nullptr, 0, 64, 1, 0, 4, 1, 1);
      conv(obuf_h, obuf_h, HW, nullptr, nullptr, 0, pk_com[s], nullptr,
           com_b+(size_t)s*216, 1,
           nullptr, nullptr, 0, 0, nullptr, nullptr, 0, 0, ombuf, 216, 216, 4, 0, 4, 1, 2);
      const ush *xs_h, *xs_l; long xps;
      if (s == 2){ xs_h = feat_h + (size_t)i*HW*64; xs_l = feat_l + (size_t)i*HW*64; xps = 5L*HW; }
      else       { xs_h = fa_h;                     xs_l = fa_l;                     xps = HW; }
      repack_gp<<<dim3(2048), cblk, 0, stream>>>(xs_h, xs_l, xps, gpbuf);
      dcn_mfma<<<dim3(2,128,4), cblk, 0, stream>>>(gpbuf, ombuf,
          (const ush*)(ws+wdcn_pk[s]), dcn_b+(size_t)s*64, fb_h, fb_l);
      ush* t;
      t = fa_h; fa_h = fb_h; fb_h = t;
      t = fa_l; fa_l = fb_l; fb_l = t;
    }
    rec_kernel<<<dim3(4,128,4), cblk, 0, stream>>>(fa_h, fa_l, ws+wt_rec, b_rec, d_out, i, flag);
  }
}

// Round 17
// 3002.228 us; speedup vs baseline: 2.7071x; 1.0850x over previous
//
#include <hip/hip_runtime.h>
#include <hip/hip_bf16.h>

typedef __hip_bfloat16 bf16;
typedef __attribute__((ext_vector_type(8))) short short8;
typedef __attribute__((ext_vector_type(4))) float floatx4;
typedef unsigned short ush;

#define HH 128
#define WW 128
#define HW 16384

__device__ __forceinline__ float b2f(bf16 v){ return __bfloat162float(v); }
__device__ __forceinline__ float bfu2f(ush u){
  union{unsigned int i; float f;} c; c.i = ((unsigned int)u)<<16; return c.f;
}
__device__ __forceinline__ ush f2bfu(float f){
  bf16 h = __float2bfloat16(f);
  return *(ush*)&h;
}

// ---------- dtype detector
__global__ void detect_dtype(const ush* __restrict__ x, float* __restrict__ flag){
  __shared__ int bad;
  if (threadIdx.x==0) bad = 0;
  __syncthreads();
  for (int j=threadIdx.x; j<4096; j+=256){
    float f = bfu2f(x[j]);
    if (!(fabsf(f) < 1e4f)) atomicOr(&bad, 1);
  }
  __syncthreads();
  if (threadIdx.x==0) flag[0] = bad ? 0.f : 1.f;
}

// ---------- input convert
__global__ void convert_in(const void* __restrict__ src, float* __restrict__ dst, int n,
                           const float* __restrict__ flag){
  int i = blockIdx.x*256 + threadIdx.x;
  if (i >= n) return;
  float v = (flag[0] > 0.5f) ? b2f(((const bf16*)src)[i]) : ((const float*)src)[i];
  dst[i] = v;
}

// ---------- weight transpose
__global__ void transpose_w(const float* __restrict__ src, float* __restrict__ dst, int Co, int CiK){
  int tid = blockIdx.x*256 + threadIdx.x;
  if (tid >= Co*CiK) return;
  int co = tid / CiK, r = tid - co*CiK;
  dst[(long)r*Co + co] = src[tid];
}

// ---------- weight pack v2: fragment-order
__global__ void pack_w2(const float* __restrict__ src, ush* __restrict__ dst,
                        int Cout, int Cin, int kh, int nOcB){
  int idx = blockIdx.x*256 + threadIdx.x;
  int total = nOcB*36864;
  if (idx >= total) return;
  int ocb = idx / 36864; int r = idx - ocb*36864;
  int c  = r & 7;
  int lx = (r>>3) & 15;
  int n  = (r>>7) & 3;
  int lk = (r>>9) & 3;
  int j  = r>>11;
  int t = j>>1, ch = j&1;
  int oc = n*16+lx;
  int k = ch*32 + lk*8 + c;
  int ocg = ocb*64 + oc, icg = kh*64 + k;
  float v = (ocg < Cout && icg < Cin) ? src[((long)ocg*Cin + icg)*9 + t] : 0.f;
  dst[idx] = f2bfu(v);
}

// ---------- DCN weight pack
__global__ void pack_dcn_w(const float* __restrict__ src, ush* __restrict__ dst){
  int idx = blockIdx.x*256 + threadIdx.x;
  if (idx >= 49152) return;
  int g = idx / 6144; int r = idx - g*6144;
  int oc = r / 96; int k = r - oc*96;
  float v = 0.f;
  if (k < 72){
    int tap = k >> 3, c = k & 7;
    v = src[((long)oc*64 + g*8 + c)*9 + tap];
  }
  dst[idx] = f2bfu(v);
}

// ---------- conv_init
__global__ __launch_bounds__(256) void conv_init_kernel(const float* __restrict__ x,
    const float* __restrict__ wT, const float* __restrict__ bias,
    ush* __restrict__ fh, ush* __restrict__ fl){
  __shared__ ush L[256*66];
  int tid = threadIdx.x;
  int tx = tid & 15, ty = tid >> 4;
  int gx = blockIdx.x*16+tx, gy = blockIdx.y*16+ty;
  int n = blockIdx.z;
  const float* xp = x + (long)n*HW;
  float v[9];
  #pragma unroll
  for (int dy=0;dy<3;dy++)
    #pragma unroll
    for (int dx=0;dx<3;dx++){
      int yy = gy+dy-1, xx = gx+dx-1;
      bool ok = (yy>=0)&&(yy<HH)&&(xx>=0)&&(xx<WW);
      v[dy*3+dx] = ok ? xp[yy*WW+xx] : 0.f;
    }
  float acc[64];
  #pragma unroll 1
  for (int oc=0; oc<64; oc++){
    float a = bias[oc];
    #pragma unroll
    for (int k=0;k<9;k++) a = fmaf(v[k], wT[k*64+oc], a);
    acc[oc] = fmaxf(a, 0.f);
  }
  #pragma unroll 1
  for (int pass=0; pass<2; pass++){
    #pragma unroll 1
    for (int oc=0; oc<64; oc++){
      float a = acc[oc];
      ush h = f2bfu(a);
      L[tid*66+oc] = pass ? f2bfu(a - bfu2f(h)) : h;
    }
    __syncthreads();
    ush* dst = pass ? fl : fh;
    for (int j=tid; j<2048; j+=256){
      int c8 = j&7, pidx = j>>3;
      int row = pidx>>4, col = pidx&15;
      long addr = ((long)n*HW + (blockIdx.y*16+row)*WW + blockIdx.x*16+col)*64 + c8*8;
      *(short8*)(dst+addr) = *(const short8*)(L + pidx*66 + c8*8);
    }
    __syncthreads();
  }
}

// ---------- MFMA implicit-GEMM 3x3 SAME conv (generic)
// out_pb: optional planar-bf16 output [img][pf_C][HW]
template<int NPL, int MINW, int MT>
__global__ __launch_bounds__(256, MINW) void conv_mfma(
    const ush* __restrict__ in_hi, const ush* __restrict__ in_lo, long in_ps,
    const ush* __restrict__ in2_hi, const ush* __restrict__ in2_lo, long in2_ps,
    const ush* __restrict__ wpack, const ush* __restrict__ wpack2,
    const float* __restrict__ bias, int has_bias,
    const ush* __restrict__ add_hi, const ush* __restrict__ add_lo,
    long add_ps, int add_cs,
    ush* __restrict__ out_hi, ush* __restrict__ out_lo,
    long out_ps, int out_cs,
    ush* __restrict__ out_pb, int pf_C,
    int Cout, int nOcB, int relu)
{
  constexpr int ROWS = 4*MT + 2;
  constexpr int APX  = ROWS*18;
  constexpr int NPX  = 4*MT*16;
  constexpr int LDSN = (NPL*APX*64 > 2*NPX*66) ? NPL*APX*64 : 2*NPX*66;
  __shared__ ush A[LDSN];
  int tid = threadIdx.x;
  int z = blockIdx.z; int img = z / nOcB; int ocb = z - img*nOcB;
  int x0 = blockIdx.x*16 - 1, y0 = blockIdx.y*(4*MT) - 1;
  int w = tid>>6, l = tid&63, lx = l&15, lk = l>>4;
  floatx4 acc[MT][4];
  #pragma unroll
  for (int mt=0;mt<MT;mt++)
    #pragma unroll
    for (int n=0;n<4;n++) acc[mt][n] = (floatx4){0.f,0.f,0.f,0.f};

  auto phase = [&](const ush* ihb, const ush* ilb, const ush* wfb){
    __syncthreads();
    #pragma unroll
    for (int p=0;p<NPL;p++){
      const ush* src = p ? ilb : ihb;
      ush* dstp = A + p*APX*64;
      for (int j=tid; j<APX*8; j+=256){
        int pidx = j>>3, c8 = j&7;
        int row = pidx/18, col = pidx - row*18;
        int yy = y0+row, xx = x0+col;
        uint4 v = make_uint4(0u,0u,0u,0u);
        if ((unsigned)yy < 128u && (unsigned)xx < 128u)
          v = *(const uint4*)(src + ((long)(yy*WW+xx))*64 + c8*8);
        *(uint4*)(dstp + pidx*64 + ((c8 ^ (pidx&7))<<3)) = v;
      }
    }
    const ush* wfrag = wfb + lk*4*128 + lx*8;
    short8 bf[4][4];
    #pragma unroll
    for (int s=0;s<3;s++)
      #pragma unroll
      for (int n=0;n<4;n++)
        bf[s][n] = *(const short8*)(wfrag + (s*16 + n)*128);
    __syncthreads();
    #pragma unroll
    for (int j=0;j<18;j++){
      int t = j>>1, ch = j&1;
      if (j<15){
        #pragma unroll
        for (int n=0;n<4;n++)
          bf[(j+3)&3][n] = *(const short8*)(wfrag + ((j+3)*16 + n)*128);
      }
      int ky = t/3, kx = t - ky*3;
      int jc = ch*4 + lk;
      #pragma unroll
      for (int mt=0; mt<MT; mt++){
        int pidx = (w*MT+mt+ky)*18 + lx + kx;
        #pragma unroll
        for (int p=0;p<NPL;p++){
          short8 af = *(const short8*)(A + p*APX*64 + pidx*64 + ((jc ^ (pidx&7))<<3));
          #pragma unroll
          for (int n=0;n<4;n++)
            acc[mt][n] = __builtin_amdgcn_mfma_f32_16x16x32_bf16(af, bf[j&3][n], acc[mt][n], 0,0,0);
        }
      }
    }
  };
  phase(in_hi + (long)img*in_ps*64, in_lo + (long)img*in_ps*64,
        wpack + (long)ocb*36864);
  if (wpack2)
    phase(in2_hi + (long)img*in2_ps*64, in2_lo + (long)img*in2_ps*64,
          wpack2 + (long)ocb*36864);

  int ybase = blockIdx.y*(4*MT) + w*MT;
  int xbase = blockIdx.x*16 + lk*4;
  if (out_pb){
    #pragma unroll
    for (int mt=0;mt<MT;mt++){
      int y = ybase + mt;
      #pragma unroll
      for (int n=0;n<4;n++){
        int ocg = ocb*64 + n*16 + lx;
        if (ocg < Cout){
          float bv = has_bias ? bias[ocg] : 0.f;
          #pragma unroll
          for (int r=0;r<4;r++){
            int xg = xbase + r;
            out_pb[((long)img*pf_C + ocg)*HW + y*WW + xg] = f2bfu(acc[mt][n][r] + bv);
          }
        }
      }
    }
  } else {
    __syncthreads();
    ush* L0 = A;
    ush* L1 = A + NPX*66;
    #pragma unroll
    for (int mt=0;mt<MT;mt++){
      int y = ybase + mt;
      int rowl = w*MT + mt;
      #pragma unroll
      for (int n=0;n<4;n++){
        int ocg = n*16 + lx;
        float bv = has_bias ? bias[ocg] : 0.f;
        #pragma unroll
        for (int r=0;r<4;r++){
          int coll = lk*4 + r;
          float v = acc[mt][n][r] + bv;
          if (add_hi){
            long ap = ((long)img*add_ps + y*WW + blockIdx.x*16 + coll)*add_cs + ocg;
            v += bfu2f(add_hi[ap]) + bfu2f(add_lo[ap]);
          }
          if (relu) v = fmaxf(v, 0.f);
          ush h = f2bfu(v);
          L0[(rowl*16+coll)*66 + ocg] = h;
          if (out_lo) L1[(rowl*16+coll)*66 + ocg] = f2bfu(v - bfu2f(h));
        }
      }
    }
    __syncthreads();
    for (int j=tid; j<NPX*8; j+=256){
      int pidx = j>>3, c8 = j&7;
      int row = pidx>>4, col = pidx&15;
      long pp = (long)img*out_ps + (blockIdx.y*(4*MT)+row)*WW + blockIdx.x*16+col;
      *(short8*)(out_hi + pp*64 + c8*8) = *(const short8*)(L0 + pidx*66 + c8*8);
      if (out_lo)
        *(short8*)(out_lo + pp*64 + c8*8) = *(const short8*)(L1 + pidx*66 + c8*8);
    }
  }
}

// ---------- fused residual block: dst = src + conv2(relu(conv1(src_hi)))
__global__ __launch_bounds__(256,4) void res_fused(
    const ush* __restrict__ src_h, const ush* __restrict__ src_l,
    const ush* __restrict__ w1, const float* __restrict__ b1,
    const ush* __restrict__ w2, const float* __restrict__ b2,
    ush* __restrict__ dst_h, ush* __restrict__ dst_l)
{
  __shared__ ush F[180*64];
  __shared__ ush Hs[112*64];
  int tid = threadIdx.x;
  int bx = blockIdx.x, by = blockIdx.y, img = blockIdx.z;
  int fy0 = by*4 - 2, fx0 = bx*16 - 2;
  int w = tid>>6, l = tid&63, lx = l&15, lk = l>>4;
  const ush* sh = src_h + (long)img*HW*64;
  for (int j=tid; j<1440; j+=256){
    int pidx = j>>3, c8 = j&7;
    int row = pidx/20, col = pidx - row*20;
    int yy = fy0+row, xx = fx0+col;
    uint4 v = make_uint4(0u,0u,0u,0u);
    if ((unsigned)yy<128u && (unsigned)xx<128u)
      v = *(const uint4*)(sh + ((long)(yy*WW+xx))*64 + c8*8);
    *(uint4*)(F + pidx*64 + ((c8 ^ (pidx&7))<<3)) = v;
  }
  const ush* wf1 = w1 + lk*4*128 + lx*8;
  int hrow[2], hcol[2], hvalid[2];
  #pragma unroll
  for (int mm=0;mm<2;mm++){
    int m = w + mm*4;
    hvalid[mm] = (m < 7);
    int hp = m*16 + lx;
    hrow[mm] = hp/18; hcol[mm] = hp - hrow[mm]*18;
  }
  floatx4 acc1[2][4];
  #pragma unroll
  for (int mm=0;mm<2;mm++)
    #pragma unroll
    for (int n=0;n<4;n++) acc1[mm][n] = (floatx4){0.f,0.f,0.f,0.f};
  short8 bf[4][4];
  #pragma unroll
  for (int s=0;s<3;s++)
    #pragma unroll
    for (int n=0;n<4;n++)
      bf[s][n] = *(const short8*)(wf1 + (s*16 + n)*128);
  __syncthreads();
  #pragma unroll
  for (int j=0;j<18;j++){
    int t = j>>1, ch = j&1;
    if (j<15){
      #pragma unroll
      for (int n=0;n<4;n++)
        bf[(j+3)&3][n] = *(const short8*)(wf1 + ((j+3)*16 + n)*128);
    }
    int ky = t/3, kx = t - ky*3;
    int jc = ch*4 + lk;
    #pragma unroll
    for (int mm=0;mm<2;mm++){
      if (!hvalid[mm]) continue;
      int pidx = (hrow[mm]+ky)*20 + hcol[mm] + kx;
      short8 af = *(const short8*)(F + pidx*64 + ((jc ^ (pidx&7))<<3));
      #pragma unroll
      for (int n=0;n<4;n++)
        acc1[mm][n] = __builtin_amdgcn_mfma_f32_16x16x32_bf16(af, bf[j&3][n], acc1[mm][n], 0,0,0);
    }
  }
  #pragma unroll
  for (int mm=0;mm<2;mm++){
    if (!hvalid[mm]) continue;
    int m = w + mm*4;
    #pragma unroll
    for (int n=0;n<4;n++){
      int oc = n*16+lx;
      float bv = b1[oc];
      #pragma unroll
      for (int r=0;r<4;r++){
        int hp = m*16 + lk*4 + r;
        int hr = hp/18, hc = hp - hr*18;
        int fy = fy0 + 1 + hr, fx = fx0 + 1 + hc;
        bool inimg = ((unsigned)fy < 128u) && ((unsigned)fx < 128u);
        float v = inimg ? fmaxf(acc1[mm][n][r] + bv, 0.f) : 0.f;
        Hs[hp*64 + (((oc>>3) ^ (hp&7))<<3) + (oc&7)] = f2bfu(v);
      }
    }
  }
  __syncthreads();
  const ush* wf2 = w2 + lk*4*128 + lx*8;
  floatx4 acc2[4];
  #pragma unroll
  for (int n=0;n<4;n++) acc2[n] = (floatx4){0.f,0.f,0.f,0.f};
  #pragma unroll
  for (int s=0;s<3;s++)
    #pragma unroll
    for (int n=0;n<4;n++)
      bf[s][n] = *(const short8*)(wf2 + (s*16 + n)*128);
  #pragma unroll
  for (int j=0;j<18;j++){
    int t = j>>1, ch = j&1;
    if (j<15){
      #pragma unroll
      for (int n=0;n<4;n++)
        bf[(j+3)&3][n] = *(const short8*)(wf2 + ((j+3)*16 + n)*128);
    }
    int ky = t/3, kx = t - ky*3;
    int jc = ch*4 + lk;
    int pidx = (w+ky)*18 + lx + kx;
    short8 af = *(const short8*)(Hs + pidx*64 + ((jc ^ (pidx&7))<<3));
    #pragma unroll
    for (int n=0;n<4;n++)
      acc2[n] = __builtin_amdgcn_mfma_f32_16x16x32_bf16(af, bf[j&3][n], acc2[n], 0,0,0);
  }
  const ush* sl = src_l + (long)img*HW*64;
  int gy = by*4 + w;
  float vout[4][4];
  #pragma unroll
  for (int n=0;n<4;n++){
    int oc = n*16+lx;
    float bv = b2[oc];
    #pragma unroll
    for (int r=0;r<4;r++){
      int colp = lk*4 + r;
      int gx = bx*16 + colp;
      int pt = (w+2)*20 + colp + 2;
      float fh = bfu2f(F[pt*64 + (((oc>>3) ^ (pt&7))<<3) + (oc&7)]);
      float fl = bfu2f(sl[((long)(gy*WW+gx))*64 + oc]);
      vout[n][r] = acc2[n][r] + bv + fh + fl;
    }
  }
  __syncthreads();
  ush* L0 = F;
  ush* L1 = F + 64*66;
  #pragma unroll
  for (int n=0;n<4;n++){
    int oc = n*16+lx;
    #pragma unroll
    for (int r=0;r<4;r++){
      int px = w*16 + lk*4 + r;
      float v = vout[n][r];
      ush h = f2bfu(v);
      L0[px*66 + oc] = h;
      L1[px*66 + oc] = f2bfu(v - bfu2f(h));
    }
  }
  __syncthreads();
  for (int j=tid; j<512; j+=256){
    int pidx = j>>3, c8 = j&7;
    int row = pidx>>4, col = pidx&15;
    long pp = ((long)img*HW + (by*4+row)*WW + bx*16+col)*64 + c8*8;
    *(short8*)(dst_h + pp) = *(const short8*)(L0 + pidx*66 + c8*8);
    *(short8*)(dst_l + pp) = *(const short8*)(L1 + pidx*66 + c8*8);
  }
}

// ---------- repack NHWC hi/lo -> group-planar bf16 [4][8][HW][8]
__global__ __launch_bounds__(256) void repack_gp(const ush* __restrict__ in_h,
    const ush* __restrict__ in_l, long in_ps, ush* __restrict__ gp){
  long idx = (long)blockIdx.x*256 + threadIdx.x;
  int img = (int)(idx >> 17);
  int rem = (int)(idx & 131071);
  int pix = rem >> 3, c8 = rem & 7;
  long src = ((long)img*in_ps + pix)*64 + c8*8;
  short8 h = *(const short8*)(in_h+src);
  short8 lo = *(const short8*)(in_l+src);
  short8 o;
  #pragma unroll
  for (int c=0;c<8;c++) o[c] = (short)f2bfu(bfu2f((ush)h[c]) + bfu2f((ush)lo[c]));
  *(short8*)(gp + (((long)(img*8+c8))*HW + pix)*8) = o;
}

// ---------- MFMA modulated deformable conv; bf16 gp + bf16 planar om
__global__ __launch_bounds__(256) void dcn_mfma(
    const ush* __restrict__ gp,
    const ush* __restrict__ om,
    const ush* __restrict__ wpk,
    const float* __restrict__ bias,
    ush* __restrict__ out_hi, ush* __restrict__ out_lo)
{
  __shared__ ush S[13312];
  ush* Ah = S;
  ush* Bt = S + 6656;
  int tid = threadIdx.x;
  int half = blockIdx.x, gy = blockIdx.y, img = blockIdx.z;
  int xoff = half*64;
  {
    short8 z = {0,0,0,0,0,0,0,0};
    for (int j=tid; j<192; j+=256){
      int px = j/3, c = j - px*3;
      *(short8*)(Ah + px*104 + 72 + c*8) = z;
    }
  }
  int w = tid>>6, l = tid&63, lx = l&15, lk = l>>4;
  int px_s = tid & 63, q = tid >> 6;
  int t0 = (q==0)?0:(q*2+1), t1 = t0 + ((q==0)?3:2);
  const ush* omb = om + (long)img*216*HW + gy*WW + xoff + px_s;
  floatx4 acc[4];
  #pragma unroll
  for (int n=0;n<4;n++) acc[n] = (floatx4){0.f,0.f,0.f,0.f};

  #pragma unroll 1
  for (int g=0; g<8; g++){
    __syncthreads();
    const ush* wsrc = wpk + g*6144;
    for (int j=tid; j<768; j+=256){
      int oc = j/12, kc = j - oc*12;
      *(short8*)(Bt + oc*104 + kc*8) = *(const short8*)(wsrc + oc*96 + kc*8);
    }
    const ush* gpb = gp + ((long)(img*8+g))*HW*8;
    #pragma unroll 1
    for (int t=t0; t<t1; t++){
      int ch = g*9+t;
      float dy = bfu2f(omb[(long)ch*HW]);
      float dx = bfu2f(omb[(long)(72+ch)*HW]);
      float mv = bfu2f(omb[(long)(144+ch)*HW]);
      float m = 1.f/(1.f+__expf(-mv));
      float py = (float)gy + (float)(t/3 - 1) + dy;
      float pxf = (float)(xoff + px_s) + (float)(t%3 - 1) + dx;
      float fy = floorf(py), fx = floorf(pxf);
      int y0 = (int)fy, x0 = (int)fx;
      float wy = py - fy, wx = pxf - fx;
      bool y0v = (y0>=0 && y0<HH), y1v = (y0+1>=0 && y0+1<HH);
      bool x0v = (x0>=0 && x0<WW), x1v = (x0+1>=0 && x0+1<WW);
      float w00 = (1.f-wy)*(1.f-wx)*m * ((y0v&&x0v)?1.f:0.f);
      float w01 = (1.f-wy)*wx*m      * ((y0v&&x1v)?1.f:0.f);
      float w10 = wy*(1.f-wx)*m      * ((y1v&&x0v)?1.f:0.f);
      float w11 = wy*wx*m            * ((y1v&&x1v)?1.f:0.f);
      int y0c = min(max(y0,0),HH-1), y1c = min(max(y0+1,0),HH-1);
      int x0c = min(max(x0,0),WW-1), x1c = min(max(x0+1,0),WW-1);
      short8 s00 = *(const short8*)(gpb + (((long)(y0c*WW+x0c))<<3));
      short8 s01 = *(const short8*)(gpb + (((long)(y0c*WW+x1c))<<3));
      short8 s10 = *(const short8*)(gpb + (((long)(y1c*WW+x0c))<<3));
      short8 s11 = *(const short8*)(gpb + (((long)(y1c*WW+x1c))<<3));
      short8 vh;
      #pragma unroll
      for (int c=0;c<8;c++){
        float val = w00*bfu2f((ush)s00[c]) + w01*bfu2f((ush)s01[c])
                  + w10*bfu2f((ush)s10[c]) + w11*bfu2f((ush)s11[c]);
        vh[c] = (short)f2bfu(val);
      }
      *(short8*)(Ah + px_s*104 + t*8) = vh;
    }
    __syncthreads();
    #pragma unroll
    for (int ks=0; ks<3; ks++){
      short8 bfg[4];
      #pragma unroll
      for (int n=0;n<4;n++)
        bfg[n] = *(const short8*)(Bt + (n*16+lx)*104 + ks*32 + lk*8);
      int px = w*16 + lx;
      short8 ah = *(const short8*)(Ah + px*104 + ks*32 + lk*8);
      #pragma unroll
      for (int n=0;n<4;n++)
        acc[n] = __builtin_amdgcn_mfma_f32_16x16x32_bf16(ah, bfg[n], acc[n], 0,0,0);
    }
  }
  __syncthreads();
  ush* L0 = S;
  ush* L1 = S + 64*66;
  #pragma unroll
  for (int n=0;n<4;n++){
    int oc = n*16 + lx;
    float bv = bias[oc];
    #pragma unroll
    for (int r=0;r<4;r++){
      int pxl = w*16 + lk*4 + r;
      float v = acc[n][r] + bv;
      ush h = f2bfu(v);
      L0[pxl*66 + oc] = h;
      L1[pxl*66 + oc] = f2bfu(v - bfu2f(h));
    }
  }
  __syncthreads();
  long base = ((long)img*HW + gy*WW + xoff)*64;
  for (int j=tid; j<512; j+=256){
    int pidx = j>>3, c8 = j&7;
    *(short8*)(out_hi + base + pidx*64 + c8*8) = *(const short8*)(L0 + pidx*66 + c8*8);
    *(short8*)(out_lo + base + pidx*64 + c8*8) = *(const short8*)(L1 + pidx*66 + c8*8);
  }
}

// ---------- reconstruction conv
__global__ __launch_bounds__(256) void rec_kernel(
    const ush* __restrict__ fh, const ush* __restrict__ fl,
    const float* __restrict__ wT, const float* __restrict__ bias,
    void* __restrict__ out, int ni, const float* __restrict__ flag){
  __shared__ float red[256];
  int tid = threadIdx.x;
  int p = tid & 31, q = tid >> 5;
  int gx = blockIdx.x*32 + p;
  int gy = blockIdx.y;
  int b = blockIdx.z;
  float acc = 0.f;
  #pragma unroll
  for (int t=0;t<9;t++){
    int yy = gy + t/3 - 1, xx = gx + t%3 - 1;
    if (yy<0||yy>=HH||xx<0||xx>=WW) continue;
    long base = ((long)b*HW + yy*WW + xx)*64 + q*8;
    short8 h = *(const short8*)(fh + base);
    short8 lo = *(const short8*)(fl + base);
    #pragma unroll
    for (int cc=0;cc<8;cc++){
      float v = bfu2f((ush)h[cc]) + bfu2f((ush)lo[cc]);
      acc = fmaf(v, wT[(q*8+cc)*9 + t], acc);
    }
  }
  red[q*32+p] = acc;
  __syncthreads();
  if (tid < 32){
    float s = bias[0];
    #pragma unroll
    for (int k=0;k<8;k++) s += red[k*32+tid];
    long idx = ((long)b*5+ni)*HW + gy*WW + blockIdx.x*32 + tid;
    if (flag[0] > 0.5f) ((bf16*)out)[idx] = __float2bfloat16(s);
    else                ((float*)out)[idx] = s;
  }
}

extern "C" void kernel_launch(void* const* d_in, const int* in_sizes, int n_in,
                              void* d_out, int out_size, void* d_ws, size_t ws_size,
                              hipStream_t stream) {
  float* ws = (float*)d_ws;

  size_t off = 16;
  auto alloc = [&](size_t nel){ size_t o = off; off += (nel + 7) & ~(size_t)7; return o; };

  static const int IN_N[17] = {327680, 576, 64, 184320, 320, 184320, 320,
                               73728, 64, 147456, 256, 497664, 864, 147456,
                               256, 576, 1};
  size_t cin[17];
  for (int i=0;i<17;i++) cin[i] = alloc(IN_N[i]);

  size_t wt_init = alloc(640);
  size_t wdcn_pk[4]; for (int s=0;s<4;s++) wdcn_pk[s] = alloc(24576);
  size_t wt_rec = alloc(640);
  size_t pk_res1[5], pk_res2[5];
  for (int i=0;i<5;i++) pk_res1[i] = alloc(18432);
  for (int i=0;i<5;i++) pk_res2[i] = alloc(18432);
  size_t pk_bn[2]; for (int h=0;h<2;h++) pk_bn[h] = alloc(18432);
  size_t pk_off[4]; for (int s=0;s<4;s++) pk_off[s] = alloc(18432);
  size_t pk_com[4]; for (int s=0;s<4;s++) pk_com[s] = alloc(73728);

  size_t feat_h_o = alloc(10485760);
  size_t feat_l_o = alloc(10485760);
  size_t U = alloc(26738688);

  ush* feat_h = (ush*)(ws + feat_h_o);
  ush* feat_l = (ush*)(ws + feat_l_o);
  ush* alt_h  = (ush*)(ws + U);
  ush* alt_l  = (ush*)(ws + U + 10485760);
  ush* hbuf_h = (ush*)(ws + U + 10485760);
  ush* feaA_h = (ush*)(ws + U);
  ush* feaA_l = (ush*)(ws + U + 2097152);
  ush* feaB_h = (ush*)(ws + U + 4194304);
  ush* feaB_l = (ush*)(ws + U + 6291456);
  ush* obuf_h = (ush*)(ws + U + 8388608);
  ush* gpbuf  = (ush*)(ws + U + 10485760);   // bf16 gp [4][8][HW][8] = 8.4 MB
  ush* ombuf  = (ush*)(ws + U + 12582912);   // bf16 planar om [4][216][HW] = 28.3 MB

  float* flag = ws;

  detect_dtype<<<dim3(1), dim3(256), 0, stream>>>((const ush*)d_in[0], flag);
  for (int i=0;i<17;i++){
    int n = IN_N[i];
    convert_in<<<dim3((n+255)/256), dim3(256), 0, stream>>>(d_in[i], ws+cin[i], n, flag);
  }
  const float* b_init = ws+cin[2];
  const float* res_b1 = ws+cin[4];
  const float* res_b2 = ws+cin[6];
  const float* b_bn   = ws+cin[8];
  const float* off_b  = ws+cin[10];
  const float* com_b  = ws+cin[12];
  const float* dcn_b  = ws+cin[14];
  const float* b_rec  = ws+cin[16];

  auto tr = [&](size_t src_o, size_t dst_o, int Co, int CiK){
    int total = Co*CiK;
    transpose_w<<<dim3((total+255)/256), dim3(256), 0, stream>>>(ws+src_o, ws+dst_o, Co, CiK);
  };
  tr(cin[1], wt_init, 64, 9);
  tr(cin[15], wt_rec, 1, 576);
  for (int s=0;s<4;s++)
    pack_dcn_w<<<dim3(192), dim3(256), 0, stream>>>(ws+cin[13]+(size_t)s*36864,
                                                    (ush*)(ws+wdcn_pk[s]));

  auto pack = [&](size_t src_o, size_t dst_o, int Cout, int Cin, int kh, int nOcB){
    int total = nOcB*36864;
    pack_w2<<<dim3((total+255)/256), dim3(256), 0, stream>>>(
        ws+src_o, (ush*)(ws+dst_o), Cout, Cin, kh, nOcB);
  };
  for (int i=0;i<5;i++) pack(cin[3]+(size_t)i*36864, pk_res1[i], 64, 64, 0, 1);
  for (int i=0;i<5;i++) pack(cin[5]+(size_t)i*36864, pk_res2[i], 64, 64, 0, 1);
  for (int h=0;h<2;h++) pack(cin[7], pk_bn[h], 64, 128, h, 1);
  for (int s=0;s<4;s++) pack(cin[9]+(size_t)s*36864,  pk_off[s], 64, 64, 0, 1);
  for (int s=0;s<4;s++) pack(cin[11]+(size_t)s*124416, pk_com[s], 216, 64, 0, 4);

  dim3 cblk(256);
  auto conv = [&](const ush* in_h, const ush* in_l, long in_ps,
                  const ush* in2_h, const ush* in2_l, long in2_ps,
                  size_t pk, const ush* pk2p,
                  const float* bias, int has_bias,
                  const ush* add_h, const ush* add_l, long add_ps, int add_cs,
                  ush* o_h, ush* o_l, long out_ps, int out_cs,
                  ush* o_pb, int pf_C,
                  int Cout, int nOcB, int relu, int N, int nPl, int mtMode){
    if (nPl == 2 && mtMode == 2)
      conv_mfma<2,2,2><<<dim3(8,16,N*nOcB), cblk, 0, stream>>>(
          in_h, in_l, in_ps, in2_h, in2_l, in2_ps,
          (const ush*)(ws+pk), pk2p, bias, has_bias,
          add_h, add_l, add_ps, add_cs, o_h, o_l, out_ps, out_cs,
          o_pb, pf_C, Cout, nOcB, relu);
    else if (nPl == 2 && mtMode == 1)
      conv_mfma<2,2,1><<<dim3(8,32,N*nOcB), cblk, 0, stream>>>(
          in_h, in_l, in_ps, in2_h, in2_l, in2_ps,
          (const ush*)(ws+pk), pk2p, bias, has_bias,
          add_h, add_l, add_ps, add_cs, o_h, o_l, out_ps, out_cs,
          o_pb, pf_C, Cout, nOcB, relu);
    else if (nPl == 1 && mtMode == 1)
      conv_mfma<1,3,1><<<dim3(8,32,N*nOcB), cblk, 0, stream>>>(
          in_h, in_l, in_ps, in2_h, in2_l, in2_ps,
          (const ush*)(ws+pk), pk2p, bias, has_bias,
          add_h, add_l, add_ps, add_cs, o_h, o_l, out_ps, out_cs,
          o_pb, pf_C, Cout, nOcB, relu);
    else
      conv_mfma<1,3,2><<<dim3(8,16,N*nOcB), cblk, 0, stream>>>(
          in_h, in_l, in_ps, in2_h, in2_l, in2_ps,
          (const ush*)(ws+pk), pk2p, bias, has_bias,
          add_h, add_l, add_ps, add_cs, o_h, o_l, out_ps, out_cs,
          o_pb, pf_C, Cout, nOcB, relu);
  };

  // ---- feature extraction
  conv_init_kernel<<<dim3(8,8,20), cblk, 0, stream>>>(ws+cin[0], ws+wt_init, b_init,
                                                      feat_h, feat_l);
  // res block 0: unfused (parity)
  conv(feat_h, feat_l, HW, nullptr, nullptr, 0, pk_res1[0], nullptr,
       res_b1, 1,
       nullptr, nullptr, 0, 0, hbuf_h, nullptr, HW, 64, nullptr, 0, 64, 1, 1, 20, 2, 1);
  conv(hbuf_h, hbuf_h, HW, nullptr, nullptr, 0, pk_res2[0], nullptr,
       res_b2, 1,
       feat_h, feat_l, HW, 64, feat_h, feat_l, HW, 64, nullptr, 0, 64, 1, 0, 20, 1, 1);
  // res blocks 1..4: fused, ping-pong feat <-> alt (ends in feat)
  {
    ush *sh = feat_h, *sl = feat_l, *dh = alt_h, *dl = alt_l;
    for (int i=1;i<5;i++){
      res_fused<<<dim3(8,32,20), cblk, 0, stream>>>(
          sh, sl, (const ush*)(ws+pk_res1[i]), res_b1+(size_t)i*64,
          (const ush*)(ws+pk_res2[i]), res_b2+(size_t)i*64, dh, dl);
      ush* t;
      t = sh; sh = dh; dh = t;
      t = sl; sl = dl; dl = t;
    }
  }
  // ---- per-neighbor alignment
  for (int i=0;i<5;i++){
    conv(feat_h + (size_t)2*HW*64, feat_l + (size_t)2*HW*64, 5L*HW,
         feat_h + (size_t)i*HW*64, feat_l + (size_t)i*HW*64, 5L*HW,
         pk_bn[0], (const ush*)(ws+pk_bn[1]), b_bn, 1,
         nullptr, nullptr, 0, 0, feaA_h, feaA_l, HW, 64, nullptr, 0, 64, 1, 0, 4, 2, 1);
    ush *fa_h = feaA_h, *fa_l = feaA_l, *fb_h = feaB_h, *fb_l = feaB_l;
    for (int s=0;s<4;s++){
      conv(fa_h, fa_h, HW, nullptr, nullptr, 0, pk_off[s], nullptr,
           off_b+(size_t)s*64, 1,
           nullptr, nullptr, 0, 0, obuf_h, nullptr, HW, 64, nullptr, 0, 64, 1, 0, 4, 1, 1);
      conv(obuf_h, obuf_h, HW, nullptr, nullptr, 0, pk_com[s], nullptr,
           com_b+(size_t)s*216, 1,
           nullptr, nullptr, 0, 0, nullptr, nullptr, 0, 0, ombuf, 216, 216, 4, 0, 4, 1, 2);
      const ush *xs_h, *xs_l; long xps;
      if (s == 2){ xs_h = feat_h + (size_t)i*HW*64; xs_l = feat_l + (size_t)i*HW*64; xps = 5L*HW; }
      else       { xs_h = fa_h;                     xs_l = fa_l;                     xps = HW; }
      repack_gp<<<dim3(2048), cblk, 0, stream>>>(xs_h, xs_l, xps, gpbuf);
      dcn_mfma<<<dim3(2,128,4), cblk, 0, stream>>>(gpbuf, ombuf,
          (const ush*)(ws+wdcn_pk[s]), dcn_b+(size_t)s*64, fb_h, fb_l);
      ush* t;
      t = fa_h; fa_h = fb_h; fb_h = t;
      t = fa_l; fa_l = fb_l; fb_l = t;
    }
    rec_kernel<<<dim3(4,128,4), cblk, 0, stream>>>(fa_h, fa_l, ws+wt_rec, b_rec, d_out, i, flag);
  }
}

// Round 18
// 2930.697 us; speedup vs baseline: 2.7732x; 1.0244x over previous
//
#include <hip/hip_runtime.h>
#include <hip/hip_bf16.h>

typedef __hip_bfloat16 bf16;
typedef __attribute__((ext_vector_type(8))) short short8;
typedef __attribute__((ext_vector_type(4))) float floatx4;
typedef unsigned short ush;

#define HH 128
#define WW 128
#define HW 16384

__device__ __forceinline__ float b2f(bf16 v){ return __bfloat162float(v); }
__device__ __forceinline__ float bfu2f(ush u){
  union{unsigned int i; float f;} c; c.i = ((unsigned int)u)<<16; return c.f;
}
__device__ __forceinline__ ush f2bfu(float f){
  bf16 h = __float2bfloat16(f);
  return *(ush*)&h;
}

// ---------- dtype detector
__global__ void detect_dtype(const ush* __restrict__ x, float* __restrict__ flag){
  __shared__ int bad;
  if (threadIdx.x==0) bad = 0;
  __syncthreads();
  for (int j=threadIdx.x; j<4096; j+=256){
    float f = bfu2f(x[j]);
    if (!(fabsf(f) < 1e4f)) atomicOr(&bad, 1);
  }
  __syncthreads();
  if (threadIdx.x==0) flag[0] = bad ? 0.f : 1.f;
}

// ---------- batched input convert (17 inputs, one dispatch)
struct CvtArgs { const void* src[17]; int dst[17]; };
__global__ void convert_all(CvtArgs a, float* __restrict__ ws, const float* __restrict__ flag){
  static const int N[17] = {327680, 576, 64, 184320, 320, 184320, 320,
                            73728, 64, 147456, 256, 497664, 864, 147456,
                            256, 576, 1};
  int i = blockIdx.y;
  int idx = blockIdx.x*256 + threadIdx.x;
  if (idx >= N[i]) return;
  float v = (flag[0] > 0.5f) ? b2f(((const bf16*)a.src[i])[idx])
                             : ((const float*)a.src[i])[idx];
  ws[a.dst[i] + idx] = v;
}

// ---------- weight transpose
__global__ void transpose_w(const float* __restrict__ src, float* __restrict__ dst, int Co, int CiK){
  int tid = blockIdx.x*256 + threadIdx.x;
  if (tid >= Co*CiK) return;
  int co = tid / CiK, r = tid - co*CiK;
  dst[(long)r*Co + co] = src[tid];
}

// ---------- batched fragment-order weight pack (20 jobs, one dispatch)
struct PackArgs { int src[20]; int dst[20]; short Cout[20]; short Cin[20];
                  short kh[20]; short nOcB[20]; };
__global__ void pack_all(PackArgs a, const float* __restrict__ ws, ush* __restrict__ wsu){
  int jb = blockIdx.y;
  int idx = blockIdx.x*256 + threadIdx.x;
  int nOcB = a.nOcB[jb];
  int total = nOcB*36864;
  if (idx >= total) return;
  const float* src = ws + a.src[jb];
  ush* dst = wsu + 2*(size_t)a.dst[jb];
  int Cout = a.Cout[jb], Cin = a.Cin[jb], kh = a.kh[jb];
  int ocb = idx / 36864; int r = idx - ocb*36864;
  int c  = r & 7;
  int lx = (r>>3) & 15;
  int n  = (r>>7) & 3;
  int lk = (r>>9) & 3;
  int j  = r>>11;
  int t = j>>1, ch = j&1;
  int oc = n*16+lx;
  int k = ch*32 + lk*8 + c;
  int ocg = ocb*64 + oc, icg = kh*64 + k;
  float v = (ocg < Cout && icg < Cin) ? src[((long)ocg*Cin + icg)*9 + t] : 0.f;
  dst[idx] = f2bfu(v);
}

// ---------- DCN weight pack (4 stages via z)
__global__ void pack_dcn_w(const float* __restrict__ src0, ush* __restrict__ dst0){
  int s = blockIdx.y;
  const float* src = src0 + (long)s*36864;
  ush* dst = dst0 + (long)s*49152;
  int idx = blockIdx.x*256 + threadIdx.x;
  if (idx >= 49152) return;
  int g = idx / 6144; int r = idx - g*6144;
  int oc = r / 96; int k = r - oc*96;
  float v = 0.f;
  if (k < 72){
    int tap = k >> 3, c = k & 7;
    v = src[((long)oc*64 + g*8 + c)*9 + tap];
  }
  dst[idx] = f2bfu(v);
}

// ---------- conv_init
__global__ __launch_bounds__(256) void conv_init_kernel(const float* __restrict__ x,
    const float* __restrict__ wT, const float* __restrict__ bias,
    ush* __restrict__ fh, ush* __restrict__ fl){
  __shared__ ush L[256*66];
  int tid = threadIdx.x;
  int tx = tid & 15, ty = tid >> 4;
  int gx = blockIdx.x*16+tx, gy = blockIdx.y*16+ty;
  int n = blockIdx.z;
  const float* xp = x + (long)n*HW;
  float v[9];
  #pragma unroll
  for (int dy=0;dy<3;dy++)
    #pragma unroll
    for (int dx=0;dx<3;dx++){
      int yy = gy+dy-1, xx = gx+dx-1;
      bool ok = (yy>=0)&&(yy<HH)&&(xx>=0)&&(xx<WW);
      v[dy*3+dx] = ok ? xp[yy*WW+xx] : 0.f;
    }
  float acc[64];
  #pragma unroll 1
  for (int oc=0; oc<64; oc++){
    float a = bias[oc];
    #pragma unroll
    for (int k=0;k<9;k++) a = fmaf(v[k], wT[k*64+oc], a);
    acc[oc] = fmaxf(a, 0.f);
  }
  #pragma unroll 1
  for (int pass=0; pass<2; pass++){
    #pragma unroll 1
    for (int oc=0; oc<64; oc++){
      float a = acc[oc];
      ush h = f2bfu(a);
      L[tid*66+oc] = pass ? f2bfu(a - bfu2f(h)) : h;
    }
    __syncthreads();
    ush* dst = pass ? fl : fh;
    for (int j=tid; j<2048; j+=256){
      int c8 = j&7, pidx = j>>3;
      int row = pidx>>4, col = pidx&15;
      long addr = ((long)n*HW + (blockIdx.y*16+row)*WW + blockIdx.x*16+col)*64 + c8*8;
      *(short8*)(dst+addr) = *(const short8*)(L + pidx*66 + c8*8);
    }
    __syncthreads();
  }
}

// ---------- MFMA implicit-GEMM 3x3 SAME conv (generic)
// out_pb: planar-bf16 output; gp_out: optional group-planar bf16 dual-write
template<int NPL, int MINW, int MT>
__global__ __launch_bounds__(256, MINW) void conv_mfma(
    const ush* __restrict__ in_hi, const ush* __restrict__ in_lo, long in_ps,
    const ush* __restrict__ in2_hi, const ush* __restrict__ in2_lo, long in2_ps,
    const ush* __restrict__ wpack, const ush* __restrict__ wpack2,
    const float* __restrict__ bias, int has_bias,
    const ush* __restrict__ add_hi, const ush* __restrict__ add_lo,
    long add_ps, int add_cs,
    ush* __restrict__ out_hi, ush* __restrict__ out_lo,
    long out_ps, int out_cs,
    ush* __restrict__ out_pb, int pf_C,
    ush* __restrict__ gp_out,
    int Cout, int nOcB, int relu)
{
  constexpr int ROWS = 4*MT + 2;
  constexpr int APX  = ROWS*18;
  constexpr int NPX  = 4*MT*16;
  constexpr int LDSN = (NPL*APX*64 > 2*NPX*66) ? NPL*APX*64 : 2*NPX*66;
  __shared__ ush A[LDSN];
  int tid = threadIdx.x;
  int z = blockIdx.z; int img = z / nOcB; int ocb = z - img*nOcB;
  int x0 = blockIdx.x*16 - 1, y0 = blockIdx.y*(4*MT) - 1;
  int w = tid>>6, l = tid&63, lx = l&15, lk = l>>4;
  floatx4 acc[MT][4];
  #pragma unroll
  for (int mt=0;mt<MT;mt++)
    #pragma unroll
    for (int n=0;n<4;n++) acc[mt][n] = (floatx4){0.f,0.f,0.f,0.f};

  auto phase = [&](const ush* ihb, const ush* ilb, const ush* wfb){
    __syncthreads();
    #pragma unroll
    for (int p=0;p<NPL;p++){
      const ush* src = p ? ilb : ihb;
      ush* dstp = A + p*APX*64;
      for (int j=tid; j<APX*8; j+=256){
        int pidx = j>>3, c8 = j&7;
        int row = pidx/18, col = pidx - row*18;
        int yy = y0+row, xx = x0+col;
        uint4 v = make_uint4(0u,0u,0u,0u);
        if ((unsigned)yy < 128u && (unsigned)xx < 128u)
          v = *(const uint4*)(src + ((long)(yy*WW+xx))*64 + c8*8);
        *(uint4*)(dstp + pidx*64 + ((c8 ^ (pidx&7))<<3)) = v;
      }
    }
    const ush* wfrag = wfb + lk*4*128 + lx*8;
    short8 bf[4][4];
    #pragma unroll
    for (int s=0;s<3;s++)
      #pragma unroll
      for (int n=0;n<4;n++)
        bf[s][n] = *(const short8*)(wfrag + (s*16 + n)*128);
    __syncthreads();
    #pragma unroll
    for (int j=0;j<18;j++){
      int t = j>>1, ch = j&1;
      if (j<15){
        #pragma unroll
        for (int n=0;n<4;n++)
          bf[(j+3)&3][n] = *(const short8*)(wfrag + ((j+3)*16 + n)*128);
      }
      int ky = t/3, kx = t - ky*3;
      int jc = ch*4 + lk;
      #pragma unroll
      for (int mt=0; mt<MT; mt++){
        int pidx = (w*MT+mt+ky)*18 + lx + kx;
        #pragma unroll
        for (int p=0;p<NPL;p++){
          short8 af = *(const short8*)(A + p*APX*64 + pidx*64 + ((jc ^ (pidx&7))<<3));
          #pragma unroll
          for (int n=0;n<4;n++)
            acc[mt][n] = __builtin_amdgcn_mfma_f32_16x16x32_bf16(af, bf[j&3][n], acc[mt][n], 0,0,0);
        }
      }
    }
  };
  phase(in_hi + (long)img*in_ps*64, in_lo + (long)img*in_ps*64,
        wpack + (long)ocb*36864);
  if (wpack2)
    phase(in2_hi + (long)img*in2_ps*64, in2_lo + (long)img*in2_ps*64,
          wpack2 + (long)ocb*36864);

  int ybase = blockIdx.y*(4*MT) + w*MT;
  int xbase = blockIdx.x*16 + lk*4;
  if (out_pb){
    #pragma unroll
    for (int mt=0;mt<MT;mt++){
      int y = ybase + mt;
      #pragma unroll
      for (int n=0;n<4;n++){
        int ocg = ocb*64 + n*16 + lx;
        if (ocg < Cout){
          float bv = has_bias ? bias[ocg] : 0.f;
          #pragma unroll
          for (int r=0;r<4;r++){
            int xg = xbase + r;
            out_pb[((long)img*pf_C + ocg)*HW + y*WW + xg] = f2bfu(acc[mt][n][r] + bv);
          }
        }
      }
    }
  } else {
    __syncthreads();
    ush* L0 = A;
    ush* L1 = A + NPX*66;
    #pragma unroll
    for (int mt=0;mt<MT;mt++){
      int y = ybase + mt;
      int rowl = w*MT + mt;
      #pragma unroll
      for (int n=0;n<4;n++){
        int ocg = n*16 + lx;
        float bv = has_bias ? bias[ocg] : 0.f;
        #pragma unroll
        for (int r=0;r<4;r++){
          int coll = lk*4 + r;
          float v = acc[mt][n][r] + bv;
          if (add_hi){
            long ap = ((long)img*add_ps + y*WW + blockIdx.x*16 + coll)*add_cs + ocg;
            v += bfu2f(add_hi[ap]) + bfu2f(add_lo[ap]);
          }
          if (relu) v = fmaxf(v, 0.f);
          ush h = f2bfu(v);
          L0[(rowl*16+coll)*66 + ocg] = h;
          if (out_lo) L1[(rowl*16+coll)*66 + ocg] = f2bfu(v - bfu2f(h));
        }
      }
    }
    __syncthreads();
    for (int j=tid; j<NPX*8; j+=256){
      int pidx = j>>3, c8 = j&7;
      int row = pidx>>4, col = pidx&15;
      long pix = (blockIdx.y*(4*MT)+row)*WW + blockIdx.x*16+col;
      long pp = (long)img*out_ps + pix;
      short8 h8 = *(const short8*)(L0 + pidx*66 + c8*8);
      *(short8*)(out_hi + pp*64 + c8*8) = h8;
      if (out_lo){
        short8 l8 = *(const short8*)(L1 + pidx*66 + c8*8);
        *(short8*)(out_lo + pp*64 + c8*8) = l8;
        if (gp_out){
          short8 g;
          #pragma unroll
          for (int c=0;c<8;c++)
            g[c] = (short)f2bfu(bfu2f((ush)h8[c]) + bfu2f((ush)l8[c]));
          *(short8*)(gp_out + (((long)(img*8+c8))*HW + pix)*8) = g;
        }
      }
    }
  }
}

// ---------- fused residual block
__global__ __launch_bounds__(256,4) void res_fused(
    const ush* __restrict__ src_h, const ush* __restrict__ src_l,
    const ush* __restrict__ w1, const float* __restrict__ b1,
    const ush* __restrict__ w2, const float* __restrict__ b2,
    ush* __restrict__ dst_h, ush* __restrict__ dst_l)
{
  __shared__ ush F[180*64];
  __shared__ ush Hs[112*64];
  int tid = threadIdx.x;
  int bx = blockIdx.x, by = blockIdx.y, img = blockIdx.z;
  int fy0 = by*4 - 2, fx0 = bx*16 - 2;
  int w = tid>>6, l = tid&63, lx = l&15, lk = l>>4;
  const ush* sh = src_h + (long)img*HW*64;
  for (int j=tid; j<1440; j+=256){
    int pidx = j>>3, c8 = j&7;
    int row = pidx/20, col = pidx - row*20;
    int yy = fy0+row, xx = fx0+col;
    uint4 v = make_uint4(0u,0u,0u,0u);
    if ((unsigned)yy<128u && (unsigned)xx<128u)
      v = *(const uint4*)(sh + ((long)(yy*WW+xx))*64 + c8*8);
    *(uint4*)(F + pidx*64 + ((c8 ^ (pidx&7))<<3)) = v;
  }
  const ush* wf1 = w1 + lk*4*128 + lx*8;
  int hrow[2], hcol[2], hvalid[2];
  #pragma unroll
  for (int mm=0;mm<2;mm++){
    int m = w + mm*4;
    hvalid[mm] = (m < 7);
    int hp = m*16 + lx;
    hrow[mm] = hp/18; hcol[mm] = hp - hrow[mm]*18;
  }
  floatx4 acc1[2][4];
  #pragma unroll
  for (int mm=0;mm<2;mm++)
    #pragma unroll
    for (int n=0;n<4;n++) acc1[mm][n] = (floatx4){0.f,0.f,0.f,0.f};
  short8 bf[4][4];
  #pragma unroll
  for (int s=0;s<3;s++)
    #pragma unroll
    for (int n=0;n<4;n++)
      bf[s][n] = *(const short8*)(wf1 + (s*16 + n)*128);
  __syncthreads();
  #pragma unroll
  for (int j=0;j<18;j++){
    int t = j>>1, ch = j&1;
    if (j<15){
      #pragma unroll
      for (int n=0;n<4;n++)
        bf[(j+3)&3][n] = *(const short8*)(wf1 + ((j+3)*16 + n)*128);
    }
    int ky = t/3, kx = t - ky*3;
    int jc = ch*4 + lk;
    #pragma unroll
    for (int mm=0;mm<2;mm++){
      if (!hvalid[mm]) continue;
      int pidx = (hrow[mm]+ky)*20 + hcol[mm] + kx;
      short8 af = *(const short8*)(F + pidx*64 + ((jc ^ (pidx&7))<<3));
      #pragma unroll
      for (int n=0;n<4;n++)
        acc1[mm][n] = __builtin_amdgcn_mfma_f32_16x16x32_bf16(af, bf[j&3][n], acc1[mm][n], 0,0,0);
    }
  }
  #pragma unroll
  for (int mm=0;mm<2;mm++){
    if (!hvalid[mm]) continue;
    int m = w + mm*4;
    #pragma unroll
    for (int n=0;n<4;n++){
      int oc = n*16+lx;
      float bv = b1[oc];
      #pragma unroll
      for (int r=0;r<4;r++){
        int hp = m*16 + lk*4 + r;
        int hr = hp/18, hc = hp - hr*18;
        int fy = fy0 + 1 + hr, fx = fx0 + 1 + hc;
        bool inimg = ((unsigned)fy < 128u) && ((unsigned)fx < 128u);
        float v = inimg ? fmaxf(acc1[mm][n][r] + bv, 0.f) : 0.f;
        Hs[hp*64 + (((oc>>3) ^ (hp&7))<<3) + (oc&7)] = f2bfu(v);
      }
    }
  }
  __syncthreads();
  const ush* wf2 = w2 + lk*4*128 + lx*8;
  floatx4 acc2[4];
  #pragma unroll
  for (int n=0;n<4;n++) acc2[n] = (floatx4){0.f,0.f,0.f,0.f};
  #pragma unroll
  for (int s=0;s<3;s++)
    #pragma unroll
    for (int n=0;n<4;n++)
      bf[s][n] = *(const short8*)(wf2 + (s*16 + n)*128);
  #pragma unroll
  for (int j=0;j<18;j++){
    int t = j>>1, ch = j&1;
    if (j<15){
      #pragma unroll
      for (int n=0;n<4;n++)
        bf[(j+3)&3][n] = *(const short8*)(wf2 + ((j+3)*16 + n)*128);
    }
    int ky = t/3, kx = t - ky*3;
    int jc = ch*4 + lk;
    int pidx = (w+ky)*18 + lx + kx;
    short8 af = *(const short8*)(Hs + pidx*64 + ((jc ^ (pidx&7))<<3));
    #pragma unroll
    for (int n=0;n<4;n++)
      acc2[n] = __builtin_amdgcn_mfma_f32_16x16x32_bf16(af, bf[j&3][n], acc2[n], 0,0,0);
  }
  const ush* sl = src_l + (long)img*HW*64;
  int gy = by*4 + w;
  float vout[4][4];
  #pragma unroll
  for (int n=0;n<4;n++){
    int oc = n*16+lx;
    float bv = b2[oc];
    #pragma unroll
    for (int r=0;r<4;r++){
      int colp = lk*4 + r;
      int gx = bx*16 + colp;
      int pt = (w+2)*20 + colp + 2;
      float fh = bfu2f(F[pt*64 + (((oc>>3) ^ (pt&7))<<3) + (oc&7)]);
      float fl = bfu2f(sl[((long)(gy*WW+gx))*64 + oc]);
      vout[n][r] = acc2[n][r] + bv + fh + fl;
    }
  }
  __syncthreads();
  ush* L0 = F;
  ush* L1 = F + 64*66;
  #pragma unroll
  for (int n=0;n<4;n++){
    int oc = n*16+lx;
    #pragma unroll
    for (int r=0;r<4;r++){
      int px = w*16 + lk*4 + r;
      float v = vout[n][r];
      ush h = f2bfu(v);
      L0[px*66 + oc] = h;
      L1[px*66 + oc] = f2bfu(v - bfu2f(h));
    }
  }
  __syncthreads();
  for (int j=tid; j<512; j+=256){
    int pidx = j>>3, c8 = j&7;
    int row = pidx>>4, col = pidx&15;
    long pp = ((long)img*HW + (by*4+row)*WW + bx*16+col)*64 + c8*8;
    *(short8*)(dst_h + pp) = *(const short8*)(L0 + pidx*66 + c8*8);
    *(short8*)(dst_l + pp) = *(const short8*)(L1 + pidx*66 + c8*8);
  }
}

// ---------- repack NHWC hi/lo -> group-planar bf16 (feat source only)
__global__ __launch_bounds__(256) void repack_gp(const ush* __restrict__ in_h,
    const ush* __restrict__ in_l, long in_ps, ush* __restrict__ gp){
  long idx = (long)blockIdx.x*256 + threadIdx.x;
  int img = (int)(idx >> 17);
  int rem = (int)(idx & 131071);
  int pix = rem >> 3, c8 = rem & 7;
  long src = ((long)img*in_ps + pix)*64 + c8*8;
  short8 h = *(const short8*)(in_h+src);
  short8 lo = *(const short8*)(in_l+src);
  short8 o;
  #pragma unroll
  for (int c=0;c<8;c++) o[c] = (short)f2bfu(bfu2f((ush)h[c]) + bfu2f((ush)lo[c]));
  *(short8*)(gp + (((long)(img*8+c8))*HW + pix)*8) = o;
}

// ---------- MFMA modulated deformable conv; bf16 gp + bf16 planar om;
// optional gp dual-write for the next stage
__global__ __launch_bounds__(256) void dcn_mfma(
    const ush* __restrict__ gp,
    const ush* __restrict__ om,
    const ush* __restrict__ wpk,
    const float* __restrict__ bias,
    ush* __restrict__ out_hi, ush* __restrict__ out_lo,
    ush* __restrict__ gp_out)
{
  __shared__ ush S[13312];
  ush* Ah = S;
  ush* Bt = S + 6656;
  int tid = threadIdx.x;
  int half = blockIdx.x, gy = blockIdx.y, img = blockIdx.z;
  int xoff = half*64;
  {
    short8 z = {0,0,0,0,0,0,0,0};
    for (int j=tid; j<192; j+=256){
      int px = j/3, c = j - px*3;
      *(short8*)(Ah + px*104 + 72 + c*8) = z;
    }
  }
  int w = tid>>6, l = tid&63, lx = l&15, lk = l>>4;
  int px_s = tid & 63, q = tid >> 6;
  int t0 = (q==0)?0:(q*2+1), t1 = t0 + ((q==0)?3:2);
  const ush* omb = om + (long)img*216*HW + gy*WW + xoff + px_s;
  floatx4 acc[4];
  #pragma unroll
  for (int n=0;n<4;n++) acc[n] = (floatx4){0.f,0.f,0.f,0.f};

  #pragma unroll 1
  for (int g=0; g<8; g++){
    __syncthreads();
    const ush* wsrc = wpk + g*6144;
    for (int j=tid; j<768; j+=256){
      int oc = j/12, kc = j - oc*12;
      *(short8*)(Bt + oc*104 + kc*8) = *(const short8*)(wsrc + oc*96 + kc*8);
    }
    const ush* gpb = gp + ((long)(img*8+g))*HW*8;
    #pragma unroll 1
    for (int t=t0; t<t1; t++){
      int ch = g*9+t;
      float dy = bfu2f(omb[(long)ch*HW]);
      float dx = bfu2f(omb[(long)(72+ch)*HW]);
      float mv = bfu2f(omb[(long)(144+ch)*HW]);
      float m = 1.f/(1.f+__expf(-mv));
      float py = (float)gy + (float)(t/3 - 1) + dy;
      float pxf = (float)(xoff + px_s) + (float)(t%3 - 1) + dx;
      float fy = floorf(py), fx = floorf(pxf);
      int y0 = (int)fy, x0 = (int)fx;
      float wy = py - fy, wx = pxf - fx;
      bool y0v = (y0>=0 && y0<HH), y1v = (y0+1>=0 && y0+1<HH);
      bool x0v = (x0>=0 && x0<WW), x1v = (x0+1>=0 && x0+1<WW);
      float w00 = (1.f-wy)*(1.f-wx)*m * ((y0v&&x0v)?1.f:0.f);
      float w01 = (1.f-wy)*wx*m      * ((y0v&&x1v)?1.f:0.f);
      float w10 = wy*(1.f-wx)*m      * ((y1v&&x0v)?1.f:0.f);
      float w11 = wy*wx*m            * ((y1v&&x1v)?1.f:0.f);
      int y0c = min(max(y0,0),HH-1), y1c = min(max(y0+1,0),HH-1);
      int x0c = min(max(x0,0),WW-1), x1c = min(max(x0+1,0),WW-1);
      short8 s00 = *(const short8*)(gpb + (((long)(y0c*WW+x0c))<<3));
      short8 s01 = *(const short8*)(gpb + (((long)(y0c*WW+x1c))<<3));
      short8 s10 = *(const short8*)(gpb + (((long)(y1c*WW+x0c))<<3));
      short8 s11 = *(const short8*)(gpb + (((long)(y1c*WW+x1c))<<3));
      short8 vh;
      #pragma unroll
      for (int c=0;c<8;c++){
        float val = w00*bfu2f((ush)s00[c]) + w01*bfu2f((ush)s01[c])
                  + w10*bfu2f((ush)s10[c]) + w11*bfu2f((ush)s11[c]);
        vh[c] = (short)f2bfu(val);
      }
      *(short8*)(Ah + px_s*104 + t*8) = vh;
    }
    __syncthreads();
    #pragma unroll
    for (int ks=0; ks<3; ks++){
      short8 bfg[4];
      #pragma unroll
      for (int n=0;n<4;n++)
        bfg[n] = *(const short8*)(Bt + (n*16+lx)*104 + ks*32 + lk*8);
      int px = w*16 + lx;
      short8 ah = *(const short8*)(Ah + px*104 + ks*32 + lk*8);
      #pragma unroll
      for (int n=0;n<4;n++)
        acc[n] = __builtin_amdgcn_mfma_f32_16x16x32_bf16(ah, bfg[n], acc[n], 0,0,0);
    }
  }
  __syncthreads();
  ush* L0 = S;
  ush* L1 = S + 64*66;
  #pragma unroll
  for (int n=0;n<4;n++){
    int oc = n*16 + lx;
    float bv = bias[oc];
    #pragma unroll
    for (int r=0;r<4;r++){
      int pxl = w*16 + lk*4 + r;
      float v = acc[n][r] + bv;
      ush h = f2bfu(v);
      L0[pxl*66 + oc] = h;
      L1[pxl*66 + oc] = f2bfu(v - bfu2f(h));
    }
  }
  __syncthreads();
  long base = ((long)img*HW + gy*WW + xoff)*64;
  for (int j=tid; j<512; j+=256){
    int pidx = j>>3, c8 = j&7;
    short8 h8 = *(const short8*)(L0 + pidx*66 + c8*8);
    short8 l8 = *(const short8*)(L1 + pidx*66 + c8*8);
    *(short8*)(out_hi + base + pidx*64 + c8*8) = h8;
    *(short8*)(out_lo + base + pidx*64 + c8*8) = l8;
    if (gp_out){
      short8 g8;
      #pragma unroll
      for (int c=0;c<8;c++)
        g8[c] = (short)f2bfu(bfu2f((ush)h8[c]) + bfu2f((ush)l8[c]));
      *(short8*)(gp_out + (((long)(img*8+c8))*HW + gy*WW + xoff + pidx)*8) = g8;
    }
  }
}

// ---------- reconstruction conv
__global__ __launch_bounds__(256) void rec_kernel(
    const ush* __restrict__ fh, const ush* __restrict__ fl,
    const float* __restrict__ wT, const float* __restrict__ bias,
    void* __restrict__ out, int ni, const float* __restrict__ flag){
  __shared__ float red[256];
  int tid = threadIdx.x;
  int p = tid & 31, q = tid >> 5;
  int gx = blockIdx.x*32 + p;
  int gy = blockIdx.y;
  int b = blockIdx.z;
  float acc = 0.f;
  #pragma unroll
  for (int t=0;t<9;t++){
    int yy = gy + t/3 - 1, xx = gx + t%3 - 1;
    if (yy<0||yy>=HH||xx<0||xx>=WW) continue;
    long base = ((long)b*HW + yy*WW + xx)*64 + q*8;
    short8 h = *(const short8*)(fh + base);
    short8 lo = *(const short8*)(fl + base);
    #pragma unroll
    for (int cc=0;cc<8;cc++){
      float v = bfu2f((ush)h[cc]) + bfu2f((ush)lo[cc]);
      acc = fmaf(v, wT[(q*8+cc)*9 + t], acc);
    }
  }
  red[q*32+p] = acc;
  __syncthreads();
  if (tid < 32){
    float s = bias[0];
    #pragma unroll
    for (int k=0;k<8;k++) s += red[k*32+tid];
    long idx = ((long)b*5+ni)*HW + gy*WW + blockIdx.x*32 + tid;
    if (flag[0] > 0.5f) ((bf16*)out)[idx] = __float2bfloat16(s);
    else                ((float*)out)[idx] = s;
  }
}

extern "C" void kernel_launch(void* const* d_in, const int* in_sizes, int n_in,
                              void* d_out, int out_size, void* d_ws, size_t ws_size,
                              hipStream_t stream) {
  float* ws = (float*)d_ws;

  size_t off = 16;
  auto alloc = [&](size_t nel){ size_t o = off; off += (nel + 7) & ~(size_t)7; return o; };

  static const int IN_N[17] = {327680, 576, 64, 184320, 320, 184320, 320,
                               73728, 64, 147456, 256, 497664, 864, 147456,
                               256, 576, 1};
  size_t cin[17];
  for (int i=0;i<17;i++) cin[i] = alloc(IN_N[i]);

  size_t wt_init = alloc(640);
  size_t wdcn_pk[4]; for (int s=0;s<4;s++) wdcn_pk[s] = alloc(24576);
  size_t wt_rec = alloc(640);
  size_t pk_res1[5], pk_res2[5];
  for (int i=0;i<5;i++) pk_res1[i] = alloc(18432);
  for (int i=0;i<5;i++) pk_res2[i] = alloc(18432);
  size_t pk_bn[2]; for (int h=0;h<2;h++) pk_bn[h] = alloc(18432);
  size_t pk_off[4]; for (int s=0;s<4;s++) pk_off[s] = alloc(18432);
  size_t pk_com[4]; for (int s=0;s<4;s++) pk_com[s] = alloc(73728);

  size_t feat_h_o = alloc(10485760);
  size_t feat_l_o = alloc(10485760);
  size_t U = alloc(26738688);

  ush* feat_h = (ush*)(ws + feat_h_o);
  ush* feat_l = (ush*)(ws + feat_l_o);
  ush* alt_h  = (ush*)(ws + U);
  ush* alt_l  = (ush*)(ws + U + 10485760);
  ush* hbuf_h = (ush*)(ws + U + 10485760);
  ush* feaA_h = (ush*)(ws + U);
  ush* feaA_l = (ush*)(ws + U + 2097152);
  ush* feaB_h = (ush*)(ws + U + 4194304);
  ush* feaB_l = (ush*)(ws + U + 6291456);
  ush* obuf_h = (ush*)(ws + U + 8388608);
  ush* gpA    = (ush*)(ws + U + 10485760);   // bf16 gp ping [4][8][HW][8]
  ush* ombuf  = (ush*)(ws + U + 12582912);   // bf16 planar om [4][216][HW]
  ush* gpB    = (ush*)(ws + U + 19660800);   // bf16 gp pong

  float* flag = ws;

  detect_dtype<<<dim3(1), dim3(256), 0, stream>>>((const ush*)d_in[0], flag);
  {
    CvtArgs ca;
    for (int i=0;i<17;i++){ ca.src[i] = d_in[i]; ca.dst[i] = (int)cin[i]; }
    convert_all<<<dim3(1945,17), dim3(256), 0, stream>>>(ca, ws, flag);
  }
  const float* b_init = ws+cin[2];
  const float* res_b1 = ws+cin[4];
  const float* res_b2 = ws+cin[6];
  const float* b_bn   = ws+cin[8];
  const float* off_b  = ws+cin[10];
  const float* com_b  = ws+cin[12];
  const float* dcn_b  = ws+cin[14];
  const float* b_rec  = ws+cin[16];

  transpose_w<<<dim3(3), dim3(256), 0, stream>>>(ws+cin[1], ws+wt_init, 64, 9);
  transpose_w<<<dim3(3), dim3(256), 0, stream>>>(ws+cin[15], ws+wt_rec, 1, 576);
  pack_dcn_w<<<dim3(192,4), dim3(256), 0, stream>>>(ws+cin[13], (ush*)(ws+wdcn_pk[0]));
  {
    PackArgs pa;
    int j = 0;
    for (int i=0;i<5;i++){ pa.src[j]=(int)(cin[3]+(size_t)i*36864); pa.dst[j]=(int)pk_res1[i];
      pa.Cout[j]=64; pa.Cin[j]=64; pa.kh[j]=0; pa.nOcB[j]=1; j++; }
    for (int i=0;i<5;i++){ pa.src[j]=(int)(cin[5]+(size_t)i*36864); pa.dst[j]=(int)pk_res2[i];
      pa.Cout[j]=64; pa.Cin[j]=64; pa.kh[j]=0; pa.nOcB[j]=1; j++; }
    for (int h=0;h<2;h++){ pa.src[j]=(int)cin[7]; pa.dst[j]=(int)pk_bn[h];
      pa.Cout[j]=64; pa.Cin[j]=128; pa.kh[j]=(short)h; pa.nOcB[j]=1; j++; }
    for (int s=0;s<4;s++){ pa.src[j]=(int)(cin[9]+(size_t)s*36864); pa.dst[j]=(int)pk_off[s];
      pa.Cout[j]=64; pa.Cin[j]=64; pa.kh[j]=0; pa.nOcB[j]=1; j++; }
    for (int s=0;s<4;s++){ pa.src[j]=(int)(cin[11]+(size_t)s*124416); pa.dst[j]=(int)pk_com[s];
      pa.Cout[j]=216; pa.Cin[j]=64; pa.kh[j]=0; pa.nOcB[j]=4; j++; }
    pack_all<<<dim3(576,20), dim3(256), 0, stream>>>(pa, ws, (ush*)ws);
  }

  dim3 cblk(256);
  auto conv = [&](const ush* in_h, const ush* in_l, long in_ps,
                  const ush* in2_h, const ush* in2_l, long in2_ps,
                  size_t pk, const ush* pk2p,
                  const float* bias, int has_bias,
                  const ush* add_h, const ush* add_l, long add_ps, int add_cs,
                  ush* o_h, ush* o_l, long out_ps, int out_cs,
                  ush* o_pb, int pf_C, ush* gp_o,
                  int Cout, int nOcB, int relu, int N, int nPl, int mtMode){
    if (nPl == 2 && mtMode == 2)
      conv_mfma<2,2,2><<<dim3(8,16,N*nOcB), cblk, 0, stream>>>(
          in_h, in_l, in_ps, in2_h, in2_l, in2_ps,
          (const ush*)(ws+pk), pk2p, bias, has_bias,
          add_h, add_l, add_ps, add_cs, o_h, o_l, out_ps, out_cs,
          o_pb, pf_C, gp_o, Cout, nOcB, relu);
    else if (nPl == 2 && mtMode == 1)
      conv_mfma<2,2,1><<<dim3(8,32,N*nOcB), cblk, 0, stream>>>(
          in_h, in_l, in_ps, in2_h, in2_l, in2_ps,
          (const ush*)(ws+pk), pk2p, bias, has_bias,
          add_h, add_l, add_ps, add_cs, o_h, o_l, out_ps, out_cs,
          o_pb, pf_C, gp_o, Cout, nOcB, relu);
    else if (nPl == 1 && mtMode == 1)
      conv_mfma<1,3,1><<<dim3(8,32,N*nOcB), cblk, 0, stream>>>(
          in_h, in_l, in_ps, in2_h, in2_l, in2_ps,
          (const ush*)(ws+pk), pk2p, bias, has_bias,
          add_h, add_l, add_ps, add_cs, o_h, o_l, out_ps, out_cs,
          o_pb, pf_C, gp_o, Cout, nOcB, relu);
    else
      conv_mfma<1,3,2><<<dim3(8,16,N*nOcB), cblk, 0, stream>>>(
          in_h, in_l, in_ps, in2_h, in2_l, in2_ps,
          (const ush*)(ws+pk), pk2p, bias, has_bias,
          add_h, add_l, add_ps, add_cs, o_h, o_l, out_ps, out_cs,
          o_pb, pf_C, gp_o, Cout, nOcB, relu);
  };

  // ---- feature extraction
  conv_init_kernel<<<dim3(8,8,20), cblk, 0, stream>>>(ws+cin[0], ws+wt_init, b_init,
                                                      feat_h, feat_l);
  conv(feat_h, feat_l, HW, nullptr, nullptr, 0, pk_res1[0], nullptr,
       res_b1, 1,
       nullptr, nullptr, 0, 0, hbuf_h, nullptr, HW, 64, nullptr, 0, nullptr, 64, 1, 1, 20, 2, 1);
  conv(hbuf_h, hbuf_h, HW, nullptr, nullptr, 0, pk_res2[0], nullptr,
       res_b2, 1,
       feat_h, feat_l, HW, 64, feat_h, feat_l, HW, 64, nullptr, 0, nullptr, 64, 1, 0, 20, 1, 1);
  {
    ush *sh = feat_h, *sl = feat_l, *dh = alt_h, *dl = alt_l;
    for (int i=1;i<5;i++){
      res_fused<<<dim3(8,32,20), cblk, 0, stream>>>(
          sh, sl, (const ush*)(ws+pk_res1[i]), res_b1+(size_t)i*64,
          (const ush*)(ws+pk_res2[i]), res_b2+(size_t)i*64, dh, dl);
      ush* t;
      t = sh; sh = dh; dh = t;
      t = sl; sl = dl; dl = t;
    }
  }
  // ---- per-neighbor alignment
  for (int i=0;i<5;i++){
    // bn conv writes fea + gpA (sampling source for s=0)
    conv(feat_h + (size_t)2*HW*64, feat_l + (size_t)2*HW*64, 5L*HW,
         feat_h + (size_t)i*HW*64, feat_l + (size_t)i*HW*64, 5L*HW,
         pk_bn[0], (const ush*)(ws+pk_bn[1]), b_bn, 1,
         nullptr, nullptr, 0, 0, feaA_h, feaA_l, HW, 64, nullptr, 0, gpA, 64, 1, 0, 4, 2, 1);
    ush *fa_h = feaA_h, *fa_l = feaA_l, *fb_h = feaB_h, *fb_l = feaB_l;
    for (int s=0;s<4;s++){
      conv(fa_h, fa_h, HW, nullptr, nullptr, 0, pk_off[s], nullptr,
           off_b+(size_t)s*64, 1,
           nullptr, nullptr, 0, 0, obuf_h, nullptr, HW, 64, nullptr, 0, nullptr, 64, 1, 0, 4, 1, 1);
      conv(obuf_h, obuf_h, HW, nullptr, nullptr, 0, pk_com[s], nullptr,
           com_b+(size_t)s*216, 1,
           nullptr, nullptr, 0, 0, nullptr, nullptr, 0, 0, ombuf, 216, nullptr, 216, 4, 0, 4, 1, 2);
      if (s == 2)
        repack_gp<<<dim3(2048), cblk, 0, stream>>>(feat_h + (size_t)i*HW*64,
            feat_l + (size_t)i*HW*64, 5L*HW, gpA);
      const ush* gp_src = (s==0) ? gpA : (s==1) ? gpB : (s==2) ? gpA : gpB;
      ush* gp_dst = (s==0 || s==2) ? gpB : nullptr;
      dcn_mfma<<<dim3(2,128,4), cblk, 0, stream>>>(gp_src, ombuf,
          (const ush*)(ws+wdcn_pk[s]), dcn_b+(size_t)s*64, fb_h, fb_l, gp_dst);
      ush* t;
      t = fa_h; fa_h = fb_h; fb_h = t;
      t = fa_l; fa_l = fb_l; fb_l = t;
    }
    rec_kernel<<<dim3(4,128,4), cblk, 0, stream>>>(fa_h, fa_l, ws+wt_rec, b_rec, d_out, i, flag);
  }
}